// Round 8
// baseline (1036.131 us; speedup 1.0000x reference)
//
#include <hip/hip_runtime.h>

typedef __attribute__((ext_vector_type(8))) short short8;
typedef __attribute__((ext_vector_type(4))) short short4v;
typedef __attribute__((ext_vector_type(4))) float floatx4;

__device__ __forceinline__ float b2f(short b) {
  union { unsigned u; float f; } v; v.u = ((unsigned)(unsigned short)b) << 16; return v.f;
}
__device__ __forceinline__ short f2b(float f) {
  union { float f; unsigned u; } v; v.f = f;
  return (short)((v.u + 0x7fffu + ((v.u >> 16) & 1u)) >> 16);
}
__device__ __forceinline__ float loadf(const void* p, size_t i, bool f32) {
  return f32 ? ((const float*)p)[i] : b2f(((const short*)p)[i]);
}
__device__ __forceinline__ short8 load8(const void* p, size_t i, bool f32) {
  if (f32) {
    const float* fp = (const float*)p + i;
    float4 a = *(const float4*)fp;
    float4 b = *(const float4*)(fp + 4);
    short8 r;
    r[0] = f2b(a.x); r[1] = f2b(a.y); r[2] = f2b(a.z); r[3] = f2b(a.w);
    r[4] = f2b(b.x); r[5] = f2b(b.y); r[6] = f2b(b.z); r[7] = f2b(b.w);
    return r;
  }
  return *(const short8*)((const short*)p + i);
}

// async global->LDS, 16B per lane. LDS dest = wave-uniform base + lane*16.
__device__ __forceinline__ void gload16(const short* g, short* l) {
  __builtin_amdgcn_global_load_lds(
      (const __attribute__((address_space(1))) unsigned int*)g,
      (__attribute__((address_space(3))) unsigned int*)l, 16, 0, 0);
}

// ---------- dtype detector: fp32 data read as shorts has random exponent fields
__global__ void detect_dtype(const unsigned short* __restrict__ w, int* __restrict__ flag) {
  __shared__ int cnt;
  if (threadIdx.x == 0) cnt = 0;
  __syncthreads();
  int bad = 0;
  for (int i = threadIdx.x; i < 4096; i += 256) {
    int e = (w[i] >> 7) & 0xFF;
    if (e >= 0xC8) bad++;  // |x| >= 2^73: impossible for real bf16 weights
  }
  atomicAdd(&cnt, bad);
  __syncthreads();
  if (threadIdx.x == 0) *flag = (cnt > 64) ? 1 : 0;
}

// ---------- one-time dtype normalization: src (fp32 or bf16, per dflag) -> bf16
__global__ __launch_bounds__(256)
void cvt_bf16(const void* __restrict__ src, short* __restrict__ dst, long n8,
              const int* __restrict__ dflag) {
  const bool f32 = (*dflag != 0);
  long stride = (long)gridDim.x * 256;
  for (long i = (long)blockIdx.x * 256 + threadIdx.x; i < n8; i += stride) {
    long e = i * 8;
    if (f32) {
      const float* fp = (const float*)src + e;
      float4 a = *(const float4*)fp;
      float4 b = *(const float4*)(fp + 4);
      short8 r;
      r[0] = f2b(a.x); r[1] = f2b(a.y); r[2] = f2b(a.z); r[3] = f2b(a.w);
      r[4] = f2b(b.x); r[5] = f2b(b.y); r[6] = f2b(b.z); r[7] = f2b(b.w);
      *(short8*)(dst + e) = r;
    } else {
      *(short8*)(dst + e) = *(const short8*)((const short*)src + e);
    }
  }
}

// ---------- one-time transposing conversion: src [K][N] (dtype per dflag) -> dst [N][K] bf16.
__global__ __launch_bounds__(256)
void cvt_t(const void* __restrict__ src, short* __restrict__ dst,
           int K, int N, const int* __restrict__ dflag) {
  __shared__ int tile[64][65];
  const bool f32 = (*dflag != 0);
  const int n0 = blockIdx.x << 6, k0 = blockIdx.y << 6;
  const int tx = threadIdx.x & 63, ty = threadIdx.x >> 6;
#pragma unroll
  for (int i = 0; i < 16; ++i) {
    int kl = i * 4 + ty;
    short v;
    if (f32) v = f2b(((const float*)src)[(size_t)(k0 + kl) * N + n0 + tx]);
    else     v = ((const short*)src)[(size_t)(k0 + kl) * N + n0 + tx];
    tile[tx][kl] = v;   // transposed store, lanes hit distinct banks (stride 65)
  }
  __syncthreads();
#pragma unroll
  for (int i = 0; i < 16; ++i) {
    int nl = i * 4 + ty;
    dst[(size_t)(n0 + nl) * K + k0 + tx] = (short)tile[nl][tx];
  }
}

// ---------- OLD GEMM (fallback when workspace too small for bf16 pool) ----------
__global__ __launch_bounds__(256, 2)
void gemm_bt(const void* __restrict__ A, int a_row0,
             const void* __restrict__ B, const void* __restrict__ bias,
             void* __restrict__ C, int c_row0, int N, int K,
             const int* __restrict__ dflag, int aIn, int cOut) {
  __shared__ short As[128 * 32];
  __shared__ short Bs[128 * 32];
  const bool f32 = (*dflag != 0);
  const bool a32 = aIn && f32;
  const bool c32 = cOut && f32;
  const int tid = threadIdx.x;
  const int lane = tid & 63, w = tid >> 6;
  const int wm = w & 1, wn = w >> 1;
  const int qg = lane >> 4, l16 = lane & 15;
  const int m0 = blockIdx.y << 7, n0 = blockIdx.x << 7;

  const int arow = tid >> 2, ak = (tid & 3) << 3;
  const int brow = tid >> 4, bc = (tid & 15) << 3;
  const int rot = tid & 15;

  floatx4 acc[4][4];
#pragma unroll
  for (int i = 0; i < 4; ++i)
#pragma unroll
    for (int j = 0; j < 4; ++j) acc[i][j] = (floatx4){0.f, 0.f, 0.f, 0.f};

  for (int k0 = 0; k0 < K; k0 += 32) {
    __syncthreads();
#pragma unroll
    for (int j = 0; j < 2; ++j) {
      short8 av = load8(A, (size_t)(a_row0 + m0 + j * 64 + arow) * K + (k0 + ak), a32);
      *(short8*)(As + (j * 64 + arow) * 32 + ak) = av;
      int kr = j * 16 + brow;
      short8 bv = load8(B, (size_t)(k0 + kr) * N + (n0 + bc), f32);
      int kq = kr >> 3, kj = kr & 7;
#pragma unroll
      for (int s = 0; s < 8; ++s) {
        int u = (s + rot) & 7;
        int n = bc + u;
        Bs[(n << 5) + ((kq ^ (n & 3)) << 3) + kj] = bv[u];
      }
    }
    __syncthreads();
    short8 a[4];
#pragma unroll
    for (int mi = 0; mi < 4; ++mi)
      a[mi] = *(const short8*)(As + (wm * 64 + mi * 16 + l16) * 32 + qg * 8);
#pragma unroll
    for (int ni = 0; ni < 4; ++ni) {
      int n = wn * 64 + ni * 16 + l16;
      short8 b = *(const short8*)(Bs + (n << 5) + ((qg ^ (n & 3)) << 3));
#pragma unroll
      for (int mi = 0; mi < 4; ++mi)
        acc[mi][ni] = __builtin_amdgcn_mfma_f32_16x16x32_bf16(a[mi], b, acc[mi][ni], 0, 0, 0);
    }
  }
#pragma unroll
  for (int ni = 0; ni < 4; ++ni) {
    int col = n0 + wn * 64 + ni * 16 + l16;
    float bv = bias ? loadf(bias, col, f32) : 0.0f;
#pragma unroll
    for (int mi = 0; mi < 4; ++mi) {
      int row = m0 + wm * 64 + mi * 16 + qg * 4;
#pragma unroll
      for (int r = 0; r < 4; ++r) {
        size_t idx = (size_t)(c_row0 + row + r) * N + col;
        float val = acc[mi][ni][r] + bv;
        if (c32) ((float*)C)[idx] = val;
        else     ((short*)C)[idx] = f2b(val);
      }
    }
  }
}

// ---------- GEMM v5: m97-exact single-buffered structure.
// bf16 A [M][K] + pre-transposed bf16 B^T [N][K], both via global_load_lds.
// 16 KB LDS -> up to 10 blocks/CU co-resident; other blocks' MFMA covers this
// block's vmcnt(0) drain (the m97 mechanism: implicit wave-level overlap beats
// explicit double-buffer, per m99/m100). R7 evidence: dbuf 2-blocks/CU variant
// stuck at 574 TF / 24% MfmaUtil / 30% occupancy; conflicts NOT the lever
// (m98: m97 hits 912 TF with the same ~1.5e7 SQ_LDS_BANK_CONFLICT).
__global__ __launch_bounds__(256, 4)
void gemm_bf2(const short* __restrict__ A, int a_row0,
              const short* __restrict__ BT, const void* __restrict__ bias,
              void* __restrict__ C, int c_row0, int N, int K,
              const int* __restrict__ dflag, int cOut) {
  __shared__ short As[128 * 32];
  __shared__ short Bs[128 * 32];
  const bool f32 = (*dflag != 0);
  const bool c32 = cOut && f32;
  const int tid = threadIdx.x;
  const int lane = tid & 63, w = tid >> 6;
  const int wm = w & 1, wn = w >> 1;
  const int qg = lane >> 4, l16 = lane & 15;
  const int m0 = blockIdx.y << 7, n0 = blockIdx.x << 7;
  const int garow = lane >> 2;   // row within 16-row gload group
  const int gcir = lane & 3;     // 16B chunk within row
  const int nk = K >> 5;
  const int swz = (gcir ^ (garow & 3) ^ (garow >> 2)) << 3;   // shorts
  const short* Abase = A + (size_t)(a_row0 + m0 + w * 32 + garow) * K + swz;
  const short* Bbase = BT + (size_t)(n0 + w * 32 + garow) * K + swz;
  const int rswz = (l16 & 3) ^ (l16 >> 2);

  floatx4 acc[4][4];
#pragma unroll
  for (int i = 0; i < 4; ++i)
#pragma unroll
    for (int j = 0; j < 4; ++j) acc[i][j] = (floatx4){0.f, 0.f, 0.f, 0.f};

  for (int t = 0; t < nk; ++t) {
    const int k0 = t << 5;
    // all waves' LDS reads of the previous tile complete
    asm volatile("s_waitcnt lgkmcnt(0)" ::: "memory");
    __builtin_amdgcn_s_barrier();
#pragma unroll
    for (int j = 0; j < 2; ++j) {
      gload16(Abase + (size_t)j * 16 * K + k0, &As[(w * 2 + j) << 9]);
      gload16(Bbase + (size_t)j * 16 * K + k0, &Bs[(w * 2 + j) << 9]);
    }
    asm volatile("s_waitcnt vmcnt(0)" ::: "memory");
    __builtin_amdgcn_s_barrier();
    short8 a[4], b[4];
#pragma unroll
    for (int mi = 0; mi < 4; ++mi) {
      int ra = wm * 64 + mi * 16 + l16;
      a[mi] = *(const short8*)(&As[(ra << 5) + ((qg ^ rswz) << 3)]);
    }
#pragma unroll
    for (int ni = 0; ni < 4; ++ni) {
      int n = wn * 64 + ni * 16 + l16;
      b[ni] = *(const short8*)(&Bs[(n << 5) + ((qg ^ rswz) << 3)]);
    }
    __builtin_amdgcn_s_setprio(1);
#pragma unroll
    for (int ni = 0; ni < 4; ++ni)
#pragma unroll
      for (int mi = 0; mi < 4; ++mi)
        acc[mi][ni] = __builtin_amdgcn_mfma_f32_16x16x32_bf16(a[mi], b[ni], acc[mi][ni], 0, 0, 0);
    __builtin_amdgcn_s_setprio(0);
  }
  // epilogue
#pragma unroll
  for (int ni = 0; ni < 4; ++ni) {
    int col = n0 + wn * 64 + ni * 16 + l16;
    float bvv = bias ? loadf(bias, col, f32) : 0.0f;
#pragma unroll
    for (int mi = 0; mi < 4; ++mi) {
      int row = m0 + wm * 64 + mi * 16 + qg * 4;
#pragma unroll
      for (int r = 0; r < 4; ++r) {
        size_t idx = (size_t)(c_row0 + row + r) * N + col;
        float val = acc[mi][ni][r] + bvv;
        if (c32) ((float*)C)[idx] = val;
        else     ((short*)C)[idx] = f2b(val);
      }
    }
  }
}

// ---------- RMSNorm + RoPE v2 (unchanged from R7): one wave per head.
__global__ __launch_bounds__(512)
void norm_rope(short* __restrict__ qkv, const int* __restrict__ ids,
               const void* __restrict__ nqw, const void* __restrict__ nkw,
               const void* __restrict__ naqw, const void* __restrict__ nakw,
               const int* __restrict__ dflag) {
  const bool f32 = (*dflag != 0);
  const int t = blockIdx.x, wv = threadIdx.x >> 6, lane = threadIdx.x & 63;
  const bool txt = t < 512;
  int p = lane, axis; float expo;
  if (p < 8)       { axis = 0; expo = (float)(2 * p) * (1.0f / 16.0f); }
  else if (p < 36) { axis = 1; expo = (float)(2 * (p - 8)) * (1.0f / 56.0f); }
  else             { axis = 2; expo = (float)(2 * (p - 36)) * (1.0f / 56.0f); }
  float freq = __expf(-expo * 9.210340371976184f);  // 10000^-expo
  float ang = (float)ids[t * 3 + axis] * freq;
  float s, c; sincosf(ang, &s, &c);
  const void* qw = txt ? naqw : nqw;
  const void* kw = txt ? nakw : nkw;
  float w0q = loadf(qw, 2 * lane, f32), w1q = loadf(qw, 2 * lane + 1, f32);
  float w0k = loadf(kw, 2 * lane, f32), w1k = loadf(kw, 2 * lane + 1, f32);
#pragma unroll
  for (int i = 0; i < 3; ++i) {
    int h = wv + 8 * i;
    short* qp = qkv + (size_t)t * 9216 + h * 128 + 2 * lane;
    short* kp = qp + 3072;
    union { unsigned u; short sh[2]; } qv, kv;
    qv.u = *(const unsigned*)qp;
    kv.u = *(const unsigned*)kp;
    float q0 = b2f(qv.sh[0]), q1 = b2f(qv.sh[1]);
    float k0 = b2f(kv.sh[0]), k1 = b2f(kv.sh[1]);
    float sq = q0 * q0 + q1 * q1, sk = k0 * k0 + k1 * k1;
#pragma unroll
    for (int o = 1; o < 64; o <<= 1) { sq += __shfl_xor(sq, o); sk += __shfl_xor(sk, o); }
    float rq = rsqrtf(sq * (1.0f / 128.0f) + 1e-5f);
    float rk = rsqrtf(sk * (1.0f / 128.0f) + 1e-5f);
    float qn0 = q0 * rq * w0q, qn1 = q1 * rq * w1q;
    float kn0 = k0 * rk * w0k, kn1 = k1 * rk * w1k;
    float qo0 = qn0 * c - qn1 * s, qo1 = qn1 * c + qn0 * s;
    float ko0 = kn0 * c - kn1 * s, ko1 = kn1 * c + kn0 * s;
    union { unsigned u; short sh[2]; } qo, ko;
    qo.sh[0] = f2b(qo0 * 0.08838834764831845f);
    qo.sh[1] = f2b(qo1 * 0.08838834764831845f);
    ko.sh[0] = f2b(ko0); ko.sh[1] = f2b(ko1);
    *(unsigned*)qp = qo.u;
    *(unsigned*)kp = ko.u;
  }
}

// ---------- flash attention v6.
// v6: V^T commit packed as ds_write_b64. V loads re-mapped so thread (sc,
// srow5, half) holds tokens {half*64 + j*16 + srow5 : j=0..3}; their t' =
// 8*srow5 + 4*half + j are consecutive -> per d one b64 write (8 total vs 32
// scalar b16). V^T chunk swizzle gains ^((d>>3)&7) so write banks spread over
// sc (write lanes vary sc, not d&7); PV read updated to match. k-order
// agreement with P is preserved (both place key token t at t'=8*(t&15)+(t>>4)).
__global__ __launch_bounds__(512, 2)
void attn_fa(const short* __restrict__ qkv, short* __restrict__ attn) {
  __shared__ short QPs[256 * 128];      // 64 KB
  __shared__ short KVs[2][128 * 128];   // 2 x 32 KB
  const int wgid = blockIdx.x;
  const int xcd = wgid & 7, slot = wgid >> 3;   // 30 slots/XCD
  const int h = xcd * 3 + slot / 10;            // 3 heads per XCD (L2-resident K/V)
  const int qt = slot % 10;
  const int tid = threadIdx.x, lane = tid & 63, w = tid >> 6;  // 8 waves
  const int qg = lane >> 4, l16 = lane & 15;
  const int lr = lane >> 4, lc = lane & 15;
  const int q0 = qt << 8;
  const int sc = tid & 15;
  const int srow5 = (tid >> 4) & 15, half = tid >> 8;

  const short* Qg  = qkv + (size_t)q0 * 9216 + h * 128;
  const short* Kg0 = qkv + 3072 + h * 128;
  const short* Vg0 = qkv + 6144 + h * 128;

  short8 vr[4];
#pragma unroll
  for (int j = 0; j < 8; ++j) {
    int row = j * 32 + w * 4 + lr;
    gload16(Qg + (size_t)row * 9216 + ((lc ^ (row & 7)) << 3),
            QPs + (j * 32 + w * 4) * 128);
  }
#pragma unroll
  for (int j = 0; j < 4; ++j) {
    int row = j * 32 + w * 4 + lr;
    gload16(Kg0 + (size_t)row * 9216 + ((lc ^ (row & 7)) << 3),
            &KVs[0][(j * 32 + w * 4) * 128]);
  }
#pragma unroll
  for (int j = 0; j < 4; ++j) {
    int row = half * 64 + j * 16 + srow5;
    vr[j] = *(const short8*)(Vg0 + (size_t)row * 9216 + sc * 8);
  }
  asm volatile("s_waitcnt vmcnt(8) lgkmcnt(0)" ::: "memory");
  __builtin_amdgcn_s_barrier();
  short8 aq[2][4];
#pragma unroll
  for (int mi = 0; mi < 2; ++mi)
#pragma unroll
    for (int kc = 0; kc < 4; ++kc) {
      int row = w * 32 + mi * 16 + l16;
      aq[mi][kc] = *(const short8*)(QPs + row * 128 + (((kc * 4 + qg) ^ (row & 7)) << 3));
    }

  floatx4 acc_o[2][8];
#pragma unroll
  for (int mi = 0; mi < 2; ++mi)
#pragma unroll
    for (int nd = 0; nd < 8; ++nd) acc_o[mi][nd] = (floatx4){0.f, 0.f, 0.f, 0.f};
  float m_i[2][4], l_i[2][4];
#pragma unroll
  for (int mi = 0; mi < 2; ++mi)
#pragma unroll
    for (int r = 0; r < 4; ++r) { m_i[mi][r] = -1e30f; l_i[mi][r] = 0.0f; }

  for (int kt = 0; kt < 20; ++kt) {
    const int c = kt & 1;
    asm volatile("s_waitcnt vmcnt(4) lgkmcnt(0)" ::: "memory");
    __builtin_amdgcn_s_barrier();
    if (kt < 19) {
      const short* Kg = qkv + ((size_t)(kt + 1) * 128) * 9216 + 3072 + h * 128;
#pragma unroll
      for (int j = 0; j < 4; ++j) {
        int row = j * 32 + w * 4 + lr;
        gload16(Kg + (size_t)row * 9216 + ((lc ^ (row & 7)) << 3),
                &KVs[1 - c][(j * 32 + w * 4) * 128]);
      }
    }
    // ---- QK^T from KVs[c]
    floatx4 acc_s[2][8];
#pragma unroll
    for (int mi = 0; mi < 2; ++mi)
#pragma unroll
      for (int ni = 0; ni < 8; ++ni) acc_s[mi][ni] = (floatx4){0.f, 0.f, 0.f, 0.f};
    __builtin_amdgcn_s_setprio(1);
#pragma unroll
    for (int kc = 0; kc < 4; ++kc) {
#pragma unroll
      for (int ni = 0; ni < 8; ++ni) {
        int row = ni * 16 + l16;
        short8 b = *(const short8*)(&KVs[c][row * 128 + (((kc * 4 + qg) ^ (row & 7)) << 3)]);
        acc_s[0][ni] = __builtin_amdgcn_mfma_f32_16x16x32_bf16(aq[0][kc], b, acc_s[0][ni], 0, 0, 0);
        acc_s[1][ni] = __builtin_amdgcn_mfma_f32_16x16x32_bf16(aq[1][kc], b, acc_s[1][ni], 0, 0, 0);
      }
    }
    __builtin_amdgcn_s_setprio(0);
    // ---- online softmax (wave-private rows)
    float alpha[2][4];
#pragma unroll
    for (int mi = 0; mi < 2; ++mi) {
#pragma unroll
      for (int r = 0; r < 4; ++r) {
        float mx = acc_s[mi][0][r];
#pragma unroll
        for (int ni = 1; ni < 8; ++ni) mx = fmaxf(mx, acc_s[mi][ni][r]);
        mx = fmaxf(mx, __shfl_xor(mx, 1));
        mx = fmaxf(mx, __shfl_xor(mx, 2));
        mx = fmaxf(mx, __shfl_xor(mx, 4));
        mx = fmaxf(mx, __shfl_xor(mx, 8));
        float mn = fmaxf(m_i[mi][r], mx);
        alpha[mi][r] = __expf(m_i[mi][r] - mn);
        m_i[mi][r] = mn;
      }
    }
#pragma unroll
    for (int mi = 0; mi < 2; ++mi) {
      float rs[4] = {0.f, 0.f, 0.f, 0.f};
#pragma unroll
      for (int r = 0; r < 4; ++r) {
        short8 p8;
#pragma unroll
        for (int ni = 0; ni < 8; ++ni) {
          float pv = __expf(acc_s[mi][ni][r] - m_i[mi][r]);
          rs[r] += pv;
          p8[ni] = f2b(pv);
        }
        int row = w * 32 + mi * 16 + qg * 4 + r;  // wave-private P row
        *(short8*)(QPs + row * 128 + ((l16 ^ (row & 15)) << 3)) = p8;
      }
#pragma unroll
      for (int r = 0; r < 4; ++r) {
        float t = rs[r];
        t += __shfl_xor(t, 1); t += __shfl_xor(t, 2);
        t += __shfl_xor(t, 4); t += __shfl_xor(t, 8);
        l_i[mi][r] = alpha[mi][r] * l_i[mi][r] + t;
      }
#pragma unroll
      for (int nd = 0; nd < 8; ++nd)
#pragma unroll
        for (int r = 0; r < 4; ++r) acc_o[mi][nd][r] *= alpha[mi][r];
    }
    asm volatile("s_waitcnt lgkmcnt(0)" ::: "memory");
    __builtin_amdgcn_s_barrier();
    // ---- commit V^T(kt) into KVs[c]: token r -> col t' = 8*(r&15) + (r>>4).
    // Thread holds tokens half*64+j*16+srow5 (j=0..3) -> t' = 8*srow5+4*half+j
    // consecutive; per d one b64 at chunk (srow5 ^ (d&7) ^ ((d>>3)&7)).
#pragma unroll
    for (int u = 0; u < 8; ++u) {
      int d = sc * 8 + u;
      short4v pk = { vr[0][u], vr[1][u], vr[2][u], vr[3][u] };
      *(short4v*)(&KVs[c][d * 128 + (((srow5 ^ u ^ (sc & 7))) << 3) + half * 4]) = pk;
    }
    if (kt < 19) {
      const short* Vg = qkv + ((size_t)(kt + 1) * 128) * 9216 + 6144 + h * 128;
#pragma unroll
      for (int j = 0; j < 4; ++j) {
        int row = half * 64 + j * 16 + srow5;
        vr[j] = *(const short8*)(Vg + (size_t)row * 9216 + sc * 8);
      }
    }
    asm volatile("s_waitcnt lgkmcnt(0)" ::: "memory");
    __builtin_amdgcn_s_barrier();
    // ---- PV: A = P (chunk c at c^(row&15)), B = V^T (chunk c at
    // c^(d&7)^((d>>3)&7)) — k-orders match by construction.
    __builtin_amdgcn_s_setprio(1);
#pragma unroll
    for (int kc = 0; kc < 4; ++kc) {
      int prow0 = w * 32 + l16;
      short8 ap0 = *(const short8*)(QPs + prow0 * 128 + (((kc * 4 + qg) ^ (prow0 & 15)) << 3));
      int prow1 = prow0 + 16;
      short8 ap1 = *(const short8*)(QPs + prow1 * 128 + (((kc * 4 + qg) ^ (prow1 & 15)) << 3));
#pragma unroll
      for (int nd = 0; nd < 8; ++nd) {
        int row = nd * 16 + l16;
        int chn = (kc * 4 + qg) ^ (row & 7) ^ ((row >> 3) & 7);
        short8 b = *(const short8*)(&KVs[c][row * 128 + (chn << 3)]);
        acc_o[0][nd] = __builtin_amdgcn_mfma_f32_16x16x32_bf16(ap0, b, acc_o[0][nd], 0, 0, 0);
        acc_o[1][nd] = __builtin_amdgcn_mfma_f32_16x16x32_bf16(ap1, b, acc_o[1][nd], 0, 0, 0);
      }
    }
    __builtin_amdgcn_s_setprio(0);
  }
  // ---- epilogue: normalize, transpose through QPs, coalesced b128 stores
#pragma unroll
  for (int mi = 0; mi < 2; ++mi) {
    float inv[4];
#pragma unroll
    for (int r = 0; r < 4; ++r) inv[r] = 1.0f / l_i[mi][r];
#pragma unroll
    for (int nd = 0; nd < 8; ++nd) {
#pragma unroll
      for (int r = 0; r < 4; ++r) {
        int row = w * 32 + mi * 16 + qg * 4 + r;
        QPs[row * 128 + nd * 16 + l16] = f2b(acc_o[mi][nd][r] * inv[r]);
      }
    }
  }
  asm volatile("s_waitcnt lgkmcnt(0)" ::: "memory");
#pragma unroll
  for (int j = 0; j < 8; ++j) {
    int rrow = w * 32 + j * 4 + qg;   // 4 rows x 16 col-chunks per iteration
    short8 vv = *(const short8*)(QPs + rrow * 128 + l16 * 8);
    *(short8*)(attn + (size_t)(q0 + rrow) * 3072 + h * 128 + l16 * 8) = vv;
  }
}

extern "C" void kernel_launch(void* const* d_in, const int* in_sizes, int n_in,
                              void* d_out, int out_size, void* d_ws, size_t ws_size,
                              hipStream_t stream) {
  (void)in_sizes; (void)n_in; (void)out_size;
  const void* hidden    = d_in[0];
  const void* enc       = d_in[1];
  const int*  ids       = (const int*)d_in[2];
  const void* w_qkv     = d_in[3];
  const void* w_add_qkv = d_in[4];
  const void* b_add_qkv = d_in[5];
  const void* w_out     = d_in[6];
  const void* b_out     = d_in[7];
  const void* w_add_out = d_in[8];
  const void* b_add_out = d_in[9];
  const void* nqw  = d_in[10];
  const void* nkw  = d_in[11];
  const void* naqw = d_in[12];
  const void* nakw = d_in[13];

  int*   dflag = (int*)d_ws;
  short* qkv   = (short*)((char*)d_ws + 256);   // [2560][9216] bf16
  short* attnB = qkv + (size_t)2560 * 9216;     // [2560][3072] bf16

  // bf16 pool: hidden, enc (row-major) + w_qkv^T, w_add_qkv^T, w_out^T, w_add_out^T
  short* pool  = attnB + (size_t)2560 * 3072;
  const long n_hid  = 2048L * 3072;
  const long n_enc  = 512L * 3072;
  const long n_wqkv = 3072L * 9216;
  const long n_wout = 3072L * 3072;
  short* hb   = pool;
  short* eb   = hb + n_hid;
  short* wqb  = eb + n_enc;        // w_qkv^T    [9216][3072]
  short* waqb = wqb + n_wqkv;      // w_add_qkv^T[9216][3072]
  short* wob  = waqb + n_wqkv;     // w_out^T    [3072][3072]
  short* waob = wob + n_wout;      // w_add_out^T[3072][3072]
  const size_t REQ = 256 + 2 * ((size_t)2560 * 9216 + (size_t)2560 * 3072 +
                                n_hid + n_enc + 2 * n_wqkv + 2 * n_wout);

  detect_dtype<<<1, 256, 0, stream>>>((const unsigned short*)w_qkv, dflag);

  if (ws_size >= REQ) {
    cvt_bf16<<<1024, 256, 0, stream>>>(hidden, hb, n_hid / 8, dflag);
    cvt_bf16<<<256, 256, 0, stream>>>(enc, eb, n_enc / 8, dflag);
    cvt_t<<<dim3(144, 48), 256, 0, stream>>>(w_qkv,     wqb,  3072, 9216, dflag);
    cvt_t<<<dim3(144, 48), 256, 0, stream>>>(w_add_qkv, waqb, 3072, 9216, dflag);
    cvt_t<<<dim3(48, 48), 256, 0, stream>>>(w_out,     wob,  3072, 3072, dflag);
    cvt_t<<<dim3(48, 48), 256, 0, stream>>>(w_add_out, waob, 3072, 3072, dflag);

    gemm_bf2<<<dim3(72, 4), 256, 0, stream>>>(eb, 0, waqb, b_add_qkv, qkv, 0, 9216, 3072, dflag, 0);
    gemm_bf2<<<dim3(72, 16), 256, 0, stream>>>(hb, 0, wqb, nullptr, qkv, 512, 9216, 3072, dflag, 0);
    norm_rope<<<dim3(2560), 512, 0, stream>>>(qkv, ids, nqw, nkw, naqw, nakw, dflag);
    attn_fa<<<dim3(240), 512, 0, stream>>>(qkv, attnB);
    gemm_bf2<<<dim3(24, 16), 256, 0, stream>>>(attnB, 512, wob, b_out, d_out, 0, 3072, 3072, dflag, 1);
    gemm_bf2<<<dim3(24, 4), 256, 0, stream>>>(attnB, 0, waob, b_add_out, d_out, 2048, 3072, 3072, dflag, 1);
  } else {
    gemm_bt<<<dim3(72, 4), 256, 0, stream>>>(enc, 0, w_add_qkv, b_add_qkv, qkv, 0, 9216, 3072, dflag, 1, 0);
    gemm_bt<<<dim3(72, 16), 256, 0, stream>>>(hidden, 0, w_qkv, nullptr, qkv, 512, 9216, 3072, dflag, 1, 0);
    norm_rope<<<dim3(2560), 512, 0, stream>>>(qkv, ids, nqw, nkw, naqw, nakw, dflag);
    attn_fa<<<dim3(240), 512, 0, stream>>>(qkv, attnB);
    gemm_bt<<<dim3(24, 16), 256, 0, stream>>>(attnB, 512, w_out, b_out, d_out, 0, 3072, 3072, dflag, 0, 1);
    gemm_bt<<<dim3(24, 4), 256, 0, stream>>>(attnB, 0, w_add_out, b_add_out, d_out, 2048, 3072, 3072, dflag, 0, 1);
  }
}

// Round 9
// 1021.278 us; speedup vs baseline: 1.0145x; 1.0145x over previous
//
#include <hip/hip_runtime.h>

typedef __attribute__((ext_vector_type(8))) short short8;
typedef __attribute__((ext_vector_type(4))) short short4v;
typedef __attribute__((ext_vector_type(4))) float floatx4;

__device__ __forceinline__ float b2f(short b) {
  union { unsigned u; float f; } v; v.u = ((unsigned)(unsigned short)b) << 16; return v.f;
}
__device__ __forceinline__ short f2b(float f) {
  union { float f; unsigned u; } v; v.f = f;
  return (short)((v.u + 0x7fffu + ((v.u >> 16) & 1u)) >> 16);
}
__device__ __forceinline__ float loadf(const void* p, size_t i, bool f32) {
  return f32 ? ((const float*)p)[i] : b2f(((const short*)p)[i]);
}
__device__ __forceinline__ short8 load8(const void* p, size_t i, bool f32) {
  if (f32) {
    const float* fp = (const float*)p + i;
    float4 a = *(const float4*)fp;
    float4 b = *(const float4*)(fp + 4);
    short8 r;
    r[0] = f2b(a.x); r[1] = f2b(a.y); r[2] = f2b(a.z); r[3] = f2b(a.w);
    r[4] = f2b(b.x); r[5] = f2b(b.y); r[6] = f2b(b.z); r[7] = f2b(b.w);
    return r;
  }
  return *(const short8*)((const short*)p + i);
}

// async global->LDS, 16B per lane. LDS dest = wave-uniform base + lane*16.
__device__ __forceinline__ void gload16(const short* g, short* l) {
  __builtin_amdgcn_global_load_lds(
      (const __attribute__((address_space(1))) unsigned int*)g,
      (__attribute__((address_space(3))) unsigned int*)l, 16, 0, 0);
}

// ---------- dtype detector: fp32 data read as shorts has random exponent fields
__global__ void detect_dtype(const unsigned short* __restrict__ w, int* __restrict__ flag) {
  __shared__ int cnt;
  if (threadIdx.x == 0) cnt = 0;
  __syncthreads();
  int bad = 0;
  for (int i = threadIdx.x; i < 4096; i += 256) {
    int e = (w[i] >> 7) & 0xFF;
    if (e >= 0xC8) bad++;  // |x| >= 2^73: impossible for real bf16 weights
  }
  atomicAdd(&cnt, bad);
  __syncthreads();
  if (threadIdx.x == 0) *flag = (cnt > 64) ? 1 : 0;
}

// ---------- one-time dtype normalization: src (fp32 or bf16, per dflag) -> bf16
__global__ __launch_bounds__(256)
void cvt_bf16(const void* __restrict__ src, short* __restrict__ dst, long n8,
              const int* __restrict__ dflag) {
  const bool f32 = (*dflag != 0);
  long stride = (long)gridDim.x * 256;
  for (long i = (long)blockIdx.x * 256 + threadIdx.x; i < n8; i += stride) {
    long e = i * 8;
    if (f32) {
      const float* fp = (const float*)src + e;
      float4 a = *(const float4*)fp;
      float4 b = *(const float4*)(fp + 4);
      short8 r;
      r[0] = f2b(a.x); r[1] = f2b(a.y); r[2] = f2b(a.z); r[3] = f2b(a.w);
      r[4] = f2b(b.x); r[5] = f2b(b.y); r[6] = f2b(b.z); r[7] = f2b(b.w);
      *(short8*)(dst + e) = r;
    } else {
      *(short8*)(dst + e) = *(const short8*)((const short*)src + e);
    }
  }
}

// ---------- one-time transposing conversion: src [K][N] (dtype per dflag) -> dst [N][K] bf16.
__global__ __launch_bounds__(256)
void cvt_t(const void* __restrict__ src, short* __restrict__ dst,
           int K, int N, const int* __restrict__ dflag) {
  __shared__ int tile[64][65];
  const bool f32 = (*dflag != 0);
  const int n0 = blockIdx.x << 6, k0 = blockIdx.y << 6;
  const int tx = threadIdx.x & 63, ty = threadIdx.x >> 6;
#pragma unroll
  for (int i = 0; i < 16; ++i) {
    int kl = i * 4 + ty;
    short v;
    if (f32) v = f2b(((const float*)src)[(size_t)(k0 + kl) * N + n0 + tx]);
    else     v = ((const short*)src)[(size_t)(k0 + kl) * N + n0 + tx];
    tile[tx][kl] = v;   // transposed store, lanes hit distinct banks (stride 65)
  }
  __syncthreads();
#pragma unroll
  for (int i = 0; i < 16; ++i) {
    int nl = i * 4 + ty;
    dst[(size_t)(n0 + nl) * K + k0 + tx] = (short)tile[nl][tx];
  }
}

// ---------- OLD GEMM (fallback when workspace too small for bf16 pool) ----------
__global__ __launch_bounds__(256, 2)
void gemm_bt(const void* __restrict__ A, int a_row0,
             const void* __restrict__ B, const void* __restrict__ bias,
             void* __restrict__ C, int c_row0, int N, int K,
             const int* __restrict__ dflag, int aIn, int cOut) {
  __shared__ short As[128 * 32];
  __shared__ short Bs[128 * 32];
  const bool f32 = (*dflag != 0);
  const bool a32 = aIn && f32;
  const bool c32 = cOut && f32;
  const int tid = threadIdx.x;
  const int lane = tid & 63, w = tid >> 6;
  const int wm = w & 1, wn = w >> 1;
  const int qg = lane >> 4, l16 = lane & 15;
  const int m0 = blockIdx.y << 7, n0 = blockIdx.x << 7;

  const int arow = tid >> 2, ak = (tid & 3) << 3;
  const int brow = tid >> 4, bc = (tid & 15) << 3;
  const int rot = tid & 15;

  floatx4 acc[4][4];
#pragma unroll
  for (int i = 0; i < 4; ++i)
#pragma unroll
    for (int j = 0; j < 4; ++j) acc[i][j] = (floatx4){0.f, 0.f, 0.f, 0.f};

  for (int k0 = 0; k0 < K; k0 += 32) {
    __syncthreads();
#pragma unroll
    for (int j = 0; j < 2; ++j) {
      short8 av = load8(A, (size_t)(a_row0 + m0 + j * 64 + arow) * K + (k0 + ak), a32);
      *(short8*)(As + (j * 64 + arow) * 32 + ak) = av;
      int kr = j * 16 + brow;
      short8 bv = load8(B, (size_t)(k0 + kr) * N + (n0 + bc), f32);
      int kq = kr >> 3, kj = kr & 7;
#pragma unroll
      for (int s = 0; s < 8; ++s) {
        int u = (s + rot) & 7;
        int n = bc + u;
        Bs[(n << 5) + ((kq ^ (n & 3)) << 3) + kj] = bv[u];
      }
    }
    __syncthreads();
    short8 a[4];
#pragma unroll
    for (int mi = 0; mi < 4; ++mi)
      a[mi] = *(const short8*)(As + (wm * 64 + mi * 16 + l16) * 32 + qg * 8);
#pragma unroll
    for (int ni = 0; ni < 4; ++ni) {
      int n = wn * 64 + ni * 16 + l16;
      short8 b = *(const short8*)(Bs + (n << 5) + ((qg ^ (n & 3)) << 3));
#pragma unroll
      for (int mi = 0; mi < 4; ++mi)
        acc[mi][ni] = __builtin_amdgcn_mfma_f32_16x16x32_bf16(a[mi], b, acc[mi][ni], 0, 0, 0);
    }
  }
#pragma unroll
  for (int ni = 0; ni < 4; ++ni) {
    int col = n0 + wn * 64 + ni * 16 + l16;
    float bv = bias ? loadf(bias, col, f32) : 0.0f;
#pragma unroll
    for (int mi = 0; mi < 4; ++mi) {
      int row = m0 + wm * 64 + mi * 16 + qg * 4;
#pragma unroll
      for (int r = 0; r < 4; ++r) {
        size_t idx = (size_t)(c_row0 + row + r) * N + col;
        float val = acc[mi][ni][r] + bv;
        if (c32) ((float*)C)[idx] = val;
        else     ((short*)C)[idx] = f2b(val);
      }
    }
  }
}

// ---------- GEMM v6: depth-2 pipelined staging with counted vmcnt (T3/T4).
// bf16 A [M][K] + pre-transposed bf16 B^T [N][K], both via global_load_lds.
// 3 buffer pairs (48 KB LDS, 3 blocks/CU). At iter t: issue tile t+2's loads,
// wait vmcnt(8) (tiles t+1,t+2 stay IN FLIGHT across barriers - never drain 0),
// barrier, compute tile t, lgkm-only barrier. Load->use distance = 2 K-steps.
// R8 evidence: single-buffer == dbuf == 204us (1130 cyc/K-step vs ~320 needed)
// -> the stall is ~900cyc load latency that depth-1 prefetch cannot hide.
__global__ __launch_bounds__(256, 3)
void gemm_bf2(const short* __restrict__ A, int a_row0,
              const short* __restrict__ BT, const void* __restrict__ bias,
              void* __restrict__ C, int c_row0, int N, int K,
              const int* __restrict__ dflag, int cOut) {
  __shared__ short As[3][128 * 32];
  __shared__ short Bs[3][128 * 32];
  const bool f32 = (*dflag != 0);
  const bool c32 = cOut && f32;
  const int tid = threadIdx.x;
  const int lane = tid & 63, w = tid >> 6;
  const int wm = w & 1, wn = w >> 1;
  const int qg = lane >> 4, l16 = lane & 15;
  const int m0 = blockIdx.y << 7, n0 = blockIdx.x << 7;
  const int garow = lane >> 2;   // row within 16-row gload group
  const int gcir = lane & 3;     // 16B chunk within row
  const int nk = K >> 5;
  const int swz = (gcir ^ (garow & 3) ^ (garow >> 2)) << 3;   // shorts
  const short* Abase = A + (size_t)(a_row0 + m0 + w * 32 + garow) * K + swz;
  const short* Bbase = BT + (size_t)(n0 + w * 32 + garow) * K + swz;
  const int rswz = (l16 & 3) ^ (l16 >> 2);

  floatx4 acc[4][4];
#pragma unroll
  for (int i = 0; i < 4; ++i)
#pragma unroll
    for (int j = 0; j < 4; ++j) acc[i][j] = (floatx4){0.f, 0.f, 0.f, 0.f};

  auto STAGE = [&](int buf, int k0) {
#pragma unroll
    for (int j = 0; j < 2; ++j) {
      gload16(Abase + (size_t)j * 16 * K + k0, &As[buf][(w * 2 + j) << 9]);
      gload16(Bbase + (size_t)j * 16 * K + k0, &Bs[buf][(w * 2 + j) << 9]);
    }
  };

  // prologue: tiles 0 and 1 in flight (8 loads/thread)
  STAGE(0, 0);
  if (nk > 1) STAGE(1, 32);

  int cb = 0;  // buffer holding tile t
  for (int t = 0; t < nk; ++t) {
    if (t + 2 < nk) {
      // (t+2)%3 == (t-1)%3: that buffer's reads were drained by the barrier
      // at the end of iteration t-1.
      int sb = (cb == 0) ? 2 : cb - 1;
      STAGE(sb, (t + 2) << 5);
      asm volatile("s_waitcnt vmcnt(8)" ::: "memory");   // tile t done; t+1,t+2 in flight
    } else if (t + 1 < nk) {
      asm volatile("s_waitcnt vmcnt(4)" ::: "memory");
    } else {
      asm volatile("s_waitcnt vmcnt(0)" ::: "memory");
    }
    __builtin_amdgcn_s_barrier();   // all waves' tile-t loads complete
    short8 a[4], b[4];
#pragma unroll
    for (int mi = 0; mi < 4; ++mi) {
      int ra = wm * 64 + mi * 16 + l16;
      a[mi] = *(const short8*)(&As[cb][(ra << 5) + ((qg ^ rswz) << 3)]);
    }
#pragma unroll
    for (int ni = 0; ni < 4; ++ni) {
      int n = wn * 64 + ni * 16 + l16;
      b[ni] = *(const short8*)(&Bs[cb][(n << 5) + ((qg ^ rswz) << 3)]);
    }
    __builtin_amdgcn_s_setprio(1);
#pragma unroll
    for (int ni = 0; ni < 4; ++ni)
#pragma unroll
      for (int mi = 0; mi < 4; ++mi)
        acc[mi][ni] = __builtin_amdgcn_mfma_f32_16x16x32_bf16(a[mi], b[ni], acc[mi][ni], 0, 0, 0);
    __builtin_amdgcn_s_setprio(0);
    asm volatile("s_waitcnt lgkmcnt(0)" ::: "memory");
    __builtin_amdgcn_s_barrier();   // tile-t reads drained (its buffer is reused at t+3)
    cb = (cb == 2) ? 0 : cb + 1;
  }
  // epilogue
#pragma unroll
  for (int ni = 0; ni < 4; ++ni) {
    int col = n0 + wn * 64 + ni * 16 + l16;
    float bvv = bias ? loadf(bias, col, f32) : 0.0f;
#pragma unroll
    for (int mi = 0; mi < 4; ++mi) {
      int row = m0 + wm * 64 + mi * 16 + qg * 4;
#pragma unroll
      for (int r = 0; r < 4; ++r) {
        size_t idx = (size_t)(c_row0 + row + r) * N + col;
        float val = acc[mi][ni][r] + bvv;
        if (c32) ((float*)C)[idx] = val;
        else     ((short*)C)[idx] = f2b(val);
      }
    }
  }
}

// ---------- RMSNorm + RoPE v2 (unchanged): one wave per head.
__global__ __launch_bounds__(512)
void norm_rope(short* __restrict__ qkv, const int* __restrict__ ids,
               const void* __restrict__ nqw, const void* __restrict__ nkw,
               const void* __restrict__ naqw, const void* __restrict__ nakw,
               const int* __restrict__ dflag) {
  const bool f32 = (*dflag != 0);
  const int t = blockIdx.x, wv = threadIdx.x >> 6, lane = threadIdx.x & 63;
  const bool txt = t < 512;
  int p = lane, axis; float expo;
  if (p < 8)       { axis = 0; expo = (float)(2 * p) * (1.0f / 16.0f); }
  else if (p < 36) { axis = 1; expo = (float)(2 * (p - 8)) * (1.0f / 56.0f); }
  else             { axis = 2; expo = (float)(2 * (p - 36)) * (1.0f / 56.0f); }
  float freq = __expf(-expo * 9.210340371976184f);  // 10000^-expo
  float ang = (float)ids[t * 3 + axis] * freq;
  float s, c; sincosf(ang, &s, &c);
  const void* qw = txt ? naqw : nqw;
  const void* kw = txt ? nakw : nkw;
  float w0q = loadf(qw, 2 * lane, f32), w1q = loadf(qw, 2 * lane + 1, f32);
  float w0k = loadf(kw, 2 * lane, f32), w1k = loadf(kw, 2 * lane + 1, f32);
#pragma unroll
  for (int i = 0; i < 3; ++i) {
    int h = wv + 8 * i;
    short* qp = qkv + (size_t)t * 9216 + h * 128 + 2 * lane;
    short* kp = qp + 3072;
    union { unsigned u; short sh[2]; } qv, kv;
    qv.u = *(const unsigned*)qp;
    kv.u = *(const unsigned*)kp;
    float q0 = b2f(qv.sh[0]), q1 = b2f(qv.sh[1]);
    float k0 = b2f(kv.sh[0]), k1 = b2f(kv.sh[1]);
    float sq = q0 * q0 + q1 * q1, sk = k0 * k0 + k1 * k1;
#pragma unroll
    for (int o = 1; o < 64; o <<= 1) { sq += __shfl_xor(sq, o); sk += __shfl_xor(sk, o); }
    float rq = rsqrtf(sq * (1.0f / 128.0f) + 1e-5f);
    float rk = rsqrtf(sk * (1.0f / 128.0f) + 1e-5f);
    float qn0 = q0 * rq * w0q, qn1 = q1 * rq * w1q;
    float kn0 = k0 * rk * w0k, kn1 = k1 * rk * w1k;
    float qo0 = qn0 * c - qn1 * s, qo1 = qn1 * c + qn0 * s;
    float ko0 = kn0 * c - kn1 * s, ko1 = kn1 * c + kn0 * s;
    union { unsigned u; short sh[2]; } qo, ko;
    qo.sh[0] = f2b(qo0 * 0.08838834764831845f);
    qo.sh[1] = f2b(qo1 * 0.08838834764831845f);
    ko.sh[0] = f2b(ko0); ko.sh[1] = f2b(ko1);
    *(unsigned*)qp = qo.u;
    *(unsigned*)kp = ko.u;
  }
}

// ---------- flash attention v6 (unchanged from R8).
__global__ __launch_bounds__(512, 2)
void attn_fa(const short* __restrict__ qkv, short* __restrict__ attn) {
  __shared__ short QPs[256 * 128];      // 64 KB
  __shared__ short KVs[2][128 * 128];   // 2 x 32 KB
  const int wgid = blockIdx.x;
  const int xcd = wgid & 7, slot = wgid >> 3;   // 30 slots/XCD
  const int h = xcd * 3 + slot / 10;            // 3 heads per XCD (L2-resident K/V)
  const int qt = slot % 10;
  const int tid = threadIdx.x, lane = tid & 63, w = tid >> 6;  // 8 waves
  const int qg = lane >> 4, l16 = lane & 15;
  const int lr = lane >> 4, lc = lane & 15;
  const int q0 = qt << 8;
  const int sc = tid & 15;
  const int srow5 = (tid >> 4) & 15, half = tid >> 8;

  const short* Qg  = qkv + (size_t)q0 * 9216 + h * 128;
  const short* Kg0 = qkv + 3072 + h * 128;
  const short* Vg0 = qkv + 6144 + h * 128;

  short8 vr[4];
#pragma unroll
  for (int j = 0; j < 8; ++j) {
    int row = j * 32 + w * 4 + lr;
    gload16(Qg + (size_t)row * 9216 + ((lc ^ (row & 7)) << 3),
            QPs + (j * 32 + w * 4) * 128);
  }
#pragma unroll
  for (int j = 0; j < 4; ++j) {
    int row = j * 32 + w * 4 + lr;
    gload16(Kg0 + (size_t)row * 9216 + ((lc ^ (row & 7)) << 3),
            &KVs[0][(j * 32 + w * 4) * 128]);
  }
#pragma unroll
  for (int j = 0; j < 4; ++j) {
    int row = half * 64 + j * 16 + srow5;
    vr[j] = *(const short8*)(Vg0 + (size_t)row * 9216 + sc * 8);
  }
  asm volatile("s_waitcnt vmcnt(8) lgkmcnt(0)" ::: "memory");
  __builtin_amdgcn_s_barrier();
  short8 aq[2][4];
#pragma unroll
  for (int mi = 0; mi < 2; ++mi)
#pragma unroll
    for (int kc = 0; kc < 4; ++kc) {
      int row = w * 32 + mi * 16 + l16;
      aq[mi][kc] = *(const short8*)(QPs + row * 128 + (((kc * 4 + qg) ^ (row & 7)) << 3));
    }

  floatx4 acc_o[2][8];
#pragma unroll
  for (int mi = 0; mi < 2; ++mi)
#pragma unroll
    for (int nd = 0; nd < 8; ++nd) acc_o[mi][nd] = (floatx4){0.f, 0.f, 0.f, 0.f};
  float m_i[2][4], l_i[2][4];
#pragma unroll
  for (int mi = 0; mi < 2; ++mi)
#pragma unroll
    for (int r = 0; r < 4; ++r) { m_i[mi][r] = -1e30f; l_i[mi][r] = 0.0f; }

  for (int kt = 0; kt < 20; ++kt) {
    const int c = kt & 1;
    asm volatile("s_waitcnt vmcnt(4) lgkmcnt(0)" ::: "memory");
    __builtin_amdgcn_s_barrier();
    if (kt < 19) {
      const short* Kg = qkv + ((size_t)(kt + 1) * 128) * 9216 + 3072 + h * 128;
#pragma unroll
      for (int j = 0; j < 4; ++j) {
        int row = j * 32 + w * 4 + lr;
        gload16(Kg + (size_t)row * 9216 + ((lc ^ (row & 7)) << 3),
                &KVs[1 - c][(j * 32 + w * 4) * 128]);
      }
    }
    // ---- QK^T from KVs[c]
    floatx4 acc_s[2][8];
#pragma unroll
    for (int mi = 0; mi < 2; ++mi)
#pragma unroll
      for (int ni = 0; ni < 8; ++ni) acc_s[mi][ni] = (floatx4){0.f, 0.f, 0.f, 0.f};
    __builtin_amdgcn_s_setprio(1);
#pragma unroll
    for (int kc = 0; kc < 4; ++kc) {
#pragma unroll
      for (int ni = 0; ni < 8; ++ni) {
        int row = ni * 16 + l16;
        short8 b = *(const short8*)(&KVs[c][row * 128 + (((kc * 4 + qg) ^ (row & 7)) << 3)]);
        acc_s[0][ni] = __builtin_amdgcn_mfma_f32_16x16x32_bf16(aq[0][kc], b, acc_s[0][ni], 0, 0, 0);
        acc_s[1][ni] = __builtin_amdgcn_mfma_f32_16x16x32_bf16(aq[1][kc], b, acc_s[1][ni], 0, 0, 0);
      }
    }
    __builtin_amdgcn_s_setprio(0);
    // ---- online softmax (wave-private rows)
    float alpha[2][4];
#pragma unroll
    for (int mi = 0; mi < 2; ++mi) {
#pragma unroll
      for (int r = 0; r < 4; ++r) {
        float mx = acc_s[mi][0][r];
#pragma unroll
        for (int ni = 1; ni < 8; ++ni) mx = fmaxf(mx, acc_s[mi][ni][r]);
        mx = fmaxf(mx, __shfl_xor(mx, 1));
        mx = fmaxf(mx, __shfl_xor(mx, 2));
        mx = fmaxf(mx, __shfl_xor(mx, 4));
        mx = fmaxf(mx, __shfl_xor(mx, 8));
        float mn = fmaxf(m_i[mi][r], mx);
        alpha[mi][r] = __expf(m_i[mi][r] - mn);
        m_i[mi][r] = mn;
      }
    }
#pragma unroll
    for (int mi = 0; mi < 2; ++mi) {
      float rs[4] = {0.f, 0.f, 0.f, 0.f};
#pragma unroll
      for (int r = 0; r < 4; ++r) {
        short8 p8;
#pragma unroll
        for (int ni = 0; ni < 8; ++ni) {
          float pv = __expf(acc_s[mi][ni][r] - m_i[mi][r]);
          rs[r] += pv;
          p8[ni] = f2b(pv);
        }
        int row = w * 32 + mi * 16 + qg * 4 + r;  // wave-private P row
        *(short8*)(QPs + row * 128 + ((l16 ^ (row & 15)) << 3)) = p8;
      }
#pragma unroll
      for (int r = 0; r < 4; ++r) {
        float t = rs[r];
        t += __shfl_xor(t, 1); t += __shfl_xor(t, 2);
        t += __shfl_xor(t, 4); t += __shfl_xor(t, 8);
        l_i[mi][r] = alpha[mi][r] * l_i[mi][r] + t;
      }
#pragma unroll
      for (int nd = 0; nd < 8; ++nd)
#pragma unroll
        for (int r = 0; r < 4; ++r) acc_o[mi][nd][r] *= alpha[mi][r];
    }
    asm volatile("s_waitcnt lgkmcnt(0)" ::: "memory");
    __builtin_amdgcn_s_barrier();
    // ---- commit V^T(kt) into KVs[c]: token r -> col t' = 8*(r&15) + (r>>4).
#pragma unroll
    for (int u = 0; u < 8; ++u) {
      int d = sc * 8 + u;
      short4v pk = { vr[0][u], vr[1][u], vr[2][u], vr[3][u] };
      *(short4v*)(&KVs[c][d * 128 + (((srow5 ^ u ^ (sc & 7))) << 3) + half * 4]) = pk;
    }
    if (kt < 19) {
      const short* Vg = qkv + ((size_t)(kt + 1) * 128) * 9216 + 6144 + h * 128;
#pragma unroll
      for (int j = 0; j < 4; ++j) {
        int row = half * 64 + j * 16 + srow5;
        vr[j] = *(const short8*)(Vg + (size_t)row * 9216 + sc * 8);
      }
    }
    asm volatile("s_waitcnt lgkmcnt(0)" ::: "memory");
    __builtin_amdgcn_s_barrier();
    // ---- PV
    __builtin_amdgcn_s_setprio(1);
#pragma unroll
    for (int kc = 0; kc < 4; ++kc) {
      int prow0 = w * 32 + l16;
      short8 ap0 = *(const short8*)(QPs + prow0 * 128 + (((kc * 4 + qg) ^ (prow0 & 15)) << 3));
      int prow1 = prow0 + 16;
      short8 ap1 = *(const short8*)(QPs + prow1 * 128 + (((kc * 4 + qg) ^ (prow1 & 15)) << 3));
#pragma unroll
      for (int nd = 0; nd < 8; ++nd) {
        int row = nd * 16 + l16;
        int chn = (kc * 4 + qg) ^ (row & 7) ^ ((row >> 3) & 7);
        short8 b = *(const short8*)(&KVs[c][row * 128 + (chn << 3)]);
        acc_o[0][nd] = __builtin_amdgcn_mfma_f32_16x16x32_bf16(ap0, b, acc_o[0][nd], 0, 0, 0);
        acc_o[1][nd] = __builtin_amdgcn_mfma_f32_16x16x32_bf16(ap1, b, acc_o[1][nd], 0, 0, 0);
      }
    }
    __builtin_amdgcn_s_setprio(0);
  }
  // ---- epilogue: normalize, transpose through QPs, coalesced b128 stores
#pragma unroll
  for (int mi = 0; mi < 2; ++mi) {
    float inv[4];
#pragma unroll
    for (int r = 0; r < 4; ++r) inv[r] = 1.0f / l_i[mi][r];
#pragma unroll
    for (int nd = 0; nd < 8; ++nd) {
#pragma unroll
      for (int r = 0; r < 4; ++r) {
        int row = w * 32 + mi * 16 + qg * 4 + r;
        QPs[row * 128 + nd * 16 + l16] = f2b(acc_o[mi][nd][r] * inv[r]);
      }
    }
  }
  asm volatile("s_waitcnt lgkmcnt(0)" ::: "memory");
#pragma unroll
  for (int j = 0; j < 8; ++j) {
    int rrow = w * 32 + j * 4 + qg;   // 4 rows x 16 col-chunks per iteration
    short8 vv = *(const short8*)(QPs + rrow * 128 + l16 * 8);
    *(short8*)(attn + (size_t)(q0 + rrow) * 3072 + h * 128 + l16 * 8) = vv;
  }
}

extern "C" void kernel_launch(void* const* d_in, const int* in_sizes, int n_in,
                              void* d_out, int out_size, void* d_ws, size_t ws_size,
                              hipStream_t stream) {
  (void)in_sizes; (void)n_in; (void)out_size;
  const void* hidden    = d_in[0];
  const void* enc       = d_in[1];
  const int*  ids       = (const int*)d_in[2];
  const void* w_qkv     = d_in[3];
  const void* w_add_qkv = d_in[4];
  const void* b_add_qkv = d_in[5];
  const void* w_out     = d_in[6];
  const void* b_out     = d_in[7];
  const void* w_add_out = d_in[8];
  const void* b_add_out = d_in[9];
  const void* nqw  = d_in[10];
  const void* nkw  = d_in[11];
  const void* naqw = d_in[12];
  const void* nakw = d_in[13];

  int*   dflag = (int*)d_ws;
  short* qkv   = (short*)((char*)d_ws + 256);   // [2560][9216] bf16
  short* attnB = qkv + (size_t)2560 * 9216;     // [2560][3072] bf16

  // bf16 pool: hidden, enc (row-major) + w_qkv^T, w_add_qkv^T, w_out^T, w_add_out^T
  short* pool  = attnB + (size_t)2560 * 3072;
  const long n_hid  = 2048L * 3072;
  const long n_enc  = 512L * 3072;
  const long n_wqkv = 3072L * 9216;
  const long n_wout = 3072L * 3072;
  short* hb   = pool;
  short* eb   = hb + n_hid;
  short* wqb  = eb + n_enc;        // w_qkv^T    [9216][3072]
  short* waqb = wqb + n_wqkv;      // w_add_qkv^T[9216][3072]
  short* wob  = waqb + n_wqkv;     // w_out^T    [3072][3072]
  short* waob = wob + n_wout;      // w_add_out^T[3072][3072]
  const size_t REQ = 256 + 2 * ((size_t)2560 * 9216 + (size_t)2560 * 3072 +
                                n_hid + n_enc + 2 * n_wqkv + 2 * n_wout);

  detect_dtype<<<1, 256, 0, stream>>>((const unsigned short*)w_qkv, dflag);

  if (ws_size >= REQ) {
    cvt_bf16<<<1024, 256, 0, stream>>>(hidden, hb, n_hid / 8, dflag);
    cvt_bf16<<<256, 256, 0, stream>>>(enc, eb, n_enc / 8, dflag);
    cvt_t<<<dim3(144, 48), 256, 0, stream>>>(w_qkv,     wqb,  3072, 9216, dflag);
    cvt_t<<<dim3(144, 48), 256, 0, stream>>>(w_add_qkv, waqb, 3072, 9216, dflag);
    cvt_t<<<dim3(48, 48), 256, 0, stream>>>(w_out,     wob,  3072, 3072, dflag);
    cvt_t<<<dim3(48, 48), 256, 0, stream>>>(w_add_out, waob, 3072, 3072, dflag);

    gemm_bf2<<<dim3(72, 4), 256, 0, stream>>>(eb, 0, waqb, b_add_qkv, qkv, 0, 9216, 3072, dflag, 0);
    gemm_bf2<<<dim3(72, 16), 256, 0, stream>>>(hb, 0, wqb, nullptr, qkv, 512, 9216, 3072, dflag, 0);
    norm_rope<<<dim3(2560), 512, 0, stream>>>(qkv, ids, nqw, nkw, naqw, nakw, dflag);
    attn_fa<<<dim3(240), 512, 0, stream>>>(qkv, attnB);
    gemm_bf2<<<dim3(24, 16), 256, 0, stream>>>(attnB, 512, wob, b_out, d_out, 0, 3072, 3072, dflag, 1);
    gemm_bf2<<<dim3(24, 4), 256, 0, stream>>>(attnB, 0, waob, b_add_out, d_out, 2048, 3072, 3072, dflag, 1);
  } else {
    gemm_bt<<<dim3(72, 4), 256, 0, stream>>>(enc, 0, w_add_qkv, b_add_qkv, qkv, 0, 9216, 3072, dflag, 1, 0);
    gemm_bt<<<dim3(72, 16), 256, 0, stream>>>(hidden, 0, w_qkv, nullptr, qkv, 512, 9216, 3072, dflag, 1, 0);
    norm_rope<<<dim3(2560), 512, 0, stream>>>(qkv, ids, nqw, nkw, naqw, nakw, dflag);
    attn_fa<<<dim3(240), 512, 0, stream>>>(qkv, attnB);
    gemm_bt<<<dim3(24, 16), 256, 0, stream>>>(attnB, 512, w_out, b_out, d_out, 0, 3072, 3072, dflag, 0, 1);
    gemm_bt<<<dim3(24, 4), 256, 0, stream>>>(attnB, 0, w_add_out, b_add_out, d_out, 2048, 3072, 3072, dflag, 0, 1);
  }
}

// Round 10
// 985.808 us; speedup vs baseline: 1.0510x; 1.0360x over previous
//
#include <hip/hip_runtime.h>

typedef __attribute__((ext_vector_type(8))) short short8;
typedef __attribute__((ext_vector_type(4))) short short4v;
typedef __attribute__((ext_vector_type(4))) float floatx4;

__device__ __forceinline__ float b2f(short b) {
  union { unsigned u; float f; } v; v.u = ((unsigned)(unsigned short)b) << 16; return v.f;
}
__device__ __forceinline__ short f2b(float f) {
  union { float f; unsigned u; } v; v.f = f;
  return (short)((v.u + 0x7fffu + ((v.u >> 16) & 1u)) >> 16);
}
// packed f32x2 -> bf16x2 (RNE), single VOP3 instr
__device__ __forceinline__ unsigned cvtpk(float lo, float hi) {
  unsigned r;
  asm("v_cvt_pk_bf16_f32 %0, %1, %2" : "=v"(r) : "v"(lo), "v"(hi));
  return r;
}
__device__ __forceinline__ float loadf(const void* p, size_t i, bool f32) {
  return f32 ? ((const float*)p)[i] : b2f(((const short*)p)[i]);
}
__device__ __forceinline__ short8 load8(const void* p, size_t i, bool f32) {
  if (f32) {
    const float* fp = (const float*)p + i;
    float4 a = *(const float4*)fp;
    float4 b = *(const float4*)(fp + 4);
    short8 r;
    r[0] = f2b(a.x); r[1] = f2b(a.y); r[2] = f2b(a.z); r[3] = f2b(a.w);
    r[4] = f2b(b.x); r[5] = f2b(b.y); r[6] = f2b(b.z); r[7] = f2b(b.w);
    return r;
  }
  return *(const short8*)((const short*)p + i);
}

// async global->LDS, 16B per lane. LDS dest = wave-uniform base + lane*16.
__device__ __forceinline__ void gload16(const short* g, short* l) {
  __builtin_amdgcn_global_load_lds(
      (const __attribute__((address_space(1))) unsigned int*)g,
      (__attribute__((address_space(3))) unsigned int*)l, 16, 0, 0);
}

// ---------- dtype detector: fp32 data read as shorts has random exponent fields
__global__ void detect_dtype(const unsigned short* __restrict__ w, int* __restrict__ flag) {
  __shared__ int cnt;
  if (threadIdx.x == 0) cnt = 0;
  __syncthreads();
  int bad = 0;
  for (int i = threadIdx.x; i < 4096; i += 256) {
    int e = (w[i] >> 7) & 0xFF;
    if (e >= 0xC8) bad++;  // |x| >= 2^73: impossible for real bf16 weights
  }
  atomicAdd(&cnt, bad);
  __syncthreads();
  if (threadIdx.x == 0) *flag = (cnt > 64) ? 1 : 0;
}

// ---------- one-time dtype normalization: src (fp32 or bf16, per dflag) -> bf16
__global__ __launch_bounds__(256)
void cvt_bf16(const void* __restrict__ src, short* __restrict__ dst, long n8,
              const int* __restrict__ dflag) {
  const bool f32 = (*dflag != 0);
  long stride = (long)gridDim.x * 256;
  for (long i = (long)blockIdx.x * 256 + threadIdx.x; i < n8; i += stride) {
    long e = i * 8;
    if (f32) {
      const float* fp = (const float*)src + e;
      float4 a = *(const float4*)fp;
      float4 b = *(const float4*)(fp + 4);
      short8 r;
      r[0] = f2b(a.x); r[1] = f2b(a.y); r[2] = f2b(a.z); r[3] = f2b(a.w);
      r[4] = f2b(b.x); r[5] = f2b(b.y); r[6] = f2b(b.z); r[7] = f2b(b.w);
      *(short8*)(dst + e) = r;
    } else {
      *(short8*)(dst + e) = *(const short8*)((const short*)src + e);
    }
  }
}

// ---------- cvt_t v2: src [K][N] (dtype per dflag) -> dst [N][K] bf16.
// R9 post-mortem: old version read fp32 at 4 B/lane and wrote bf16 with 16
// scalar 2-byte global stores/thread (~1.5 TB/s; ~280 us across 4 calls).
// v2: 4x float4 (or short4) reads, 64x64 LDS transpose tile (72-short rows),
// 2x short8 writes per thread (32 B, 128 B contiguous per 4 lanes).
__global__ __launch_bounds__(256)
void cvt_t(const void* __restrict__ src, short* __restrict__ dst,
           int K, int N, const int* __restrict__ dflag) {
  __shared__ short st[64][72];   // [n][k], 72-short pitch spreads banks
  const bool f32 = (*dflag != 0);
  const int n0 = blockIdx.x << 6, k0 = blockIdx.y << 6;
  const int c4 = threadIdx.x & 15;   // n-chunk of 4
  const int rq = threadIdx.x >> 4;   // 0..15
#pragma unroll
  for (int r = 0; r < 4; ++r) {
    int k = r * 16 + rq;
    int n = c4 * 4;
    short v0, v1, v2, v3;
    if (f32) {
      const float* sp = (const float*)src + (size_t)(k0 + k) * N + n0 + n;
      float4 f = *(const float4*)sp;
      v0 = f2b(f.x); v1 = f2b(f.y); v2 = f2b(f.z); v3 = f2b(f.w);
    } else {
      const short* sp = (const short*)src + (size_t)(k0 + k) * N + n0 + n;
      short4v s = *(const short4v*)sp;
      v0 = s[0]; v1 = s[1]; v2 = s[2]; v3 = s[3];
    }
    st[n + 0][k] = v0; st[n + 1][k] = v1; st[n + 2][k] = v2; st[n + 3][k] = v3;
  }
  __syncthreads();
  const int n = threadIdx.x >> 2;           // 0..63
  const int kc = (threadIdx.x & 3) << 4;    // 0,16,32,48
  short8 a = *(const short8*)(&st[n][kc]);
  short8 b = *(const short8*)(&st[n][kc + 8]);
  short* dp = dst + (size_t)(n0 + n) * K + k0 + kc;
  *(short8*)(dp) = a;
  *(short8*)(dp + 8) = b;
}

// ---------- OLD GEMM (fallback when workspace too small for bf16 pool) ----------
__global__ __launch_bounds__(256, 2)
void gemm_bt(const void* __restrict__ A, int a_row0,
             const void* __restrict__ B, const void* __restrict__ bias,
             void* __restrict__ C, int c_row0, int N, int K,
             const int* __restrict__ dflag, int aIn, int cOut) {
  __shared__ short As[128 * 32];
  __shared__ short Bs[128 * 32];
  const bool f32 = (*dflag != 0);
  const bool a32 = aIn && f32;
  const bool c32 = cOut && f32;
  const int tid = threadIdx.x;
  const int lane = tid & 63, w = tid >> 6;
  const int wm = w & 1, wn = w >> 1;
  const int qg = lane >> 4, l16 = lane & 15;
  const int m0 = blockIdx.y << 7, n0 = blockIdx.x << 7;

  const int arow = tid >> 2, ak = (tid & 3) << 3;
  const int brow = tid >> 4, bc = (tid & 15) << 3;
  const int rot = tid & 15;

  floatx4 acc[4][4];
#pragma unroll
  for (int i = 0; i < 4; ++i)
#pragma unroll
    for (int j = 0; j < 4; ++j) acc[i][j] = (floatx4){0.f, 0.f, 0.f, 0.f};

  for (int k0 = 0; k0 < K; k0 += 32) {
    __syncthreads();
#pragma unroll
    for (int j = 0; j < 2; ++j) {
      short8 av = load8(A, (size_t)(a_row0 + m0 + j * 64 + arow) * K + (k0 + ak), a32);
      *(short8*)(As + (j * 64 + arow) * 32 + ak) = av;
      int kr = j * 16 + brow;
      short8 bv = load8(B, (size_t)(k0 + kr) * N + (n0 + bc), f32);
      int kq = kr >> 3, kj = kr & 7;
#pragma unroll
      for (int s = 0; s < 8; ++s) {
        int u = (s + rot) & 7;
        int n = bc + u;
        Bs[(n << 5) + ((kq ^ (n & 3)) << 3) + kj] = bv[u];
      }
    }
    __syncthreads();
    short8 a[4];
#pragma unroll
    for (int mi = 0; mi < 4; ++mi)
      a[mi] = *(const short8*)(As + (wm * 64 + mi * 16 + l16) * 32 + qg * 8);
#pragma unroll
    for (int ni = 0; ni < 4; ++ni) {
      int n = wn * 64 + ni * 16 + l16;
      short8 b = *(const short8*)(Bs + (n << 5) + ((qg ^ (n & 3)) << 3));
#pragma unroll
      for (int mi = 0; mi < 4; ++mi)
        acc[mi][ni] = __builtin_amdgcn_mfma_f32_16x16x32_bf16(a[mi], b, acc[mi][ni], 0, 0, 0);
    }
  }
#pragma unroll
  for (int ni = 0; ni < 4; ++ni) {
    int col = n0 + wn * 64 + ni * 16 + l16;
    float bv = bias ? loadf(bias, col, f32) : 0.0f;
#pragma unroll
    for (int mi = 0; mi < 4; ++mi) {
      int row = m0 + wm * 64 + mi * 16 + qg * 4;
#pragma unroll
      for (int r = 0; r < 4; ++r) {
        size_t idx = (size_t)(c_row0 + row + r) * N + col;
        float val = acc[mi][ni][r] + bv;
        if (c32) ((float*)C)[idx] = val;
        else     ((short*)C)[idx] = f2b(val);
      }
    }
  }
}

// ---------- GEMM v6 (unchanged from R9): depth-2 pipelined, counted vmcnt.
__global__ __launch_bounds__(256, 3)
void gemm_bf2(const short* __restrict__ A, int a_row0,
              const short* __restrict__ BT, const void* __restrict__ bias,
              void* __restrict__ C, int c_row0, int N, int K,
              const int* __restrict__ dflag, int cOut) {
  __shared__ short As[3][128 * 32];
  __shared__ short Bs[3][128 * 32];
  const bool f32 = (*dflag != 0);
  const bool c32 = cOut && f32;
  const int tid = threadIdx.x;
  const int lane = tid & 63, w = tid >> 6;
  const int wm = w & 1, wn = w >> 1;
  const int qg = lane >> 4, l16 = lane & 15;
  const int m0 = blockIdx.y << 7, n0 = blockIdx.x << 7;
  const int garow = lane >> 2;
  const int gcir = lane & 3;
  const int nk = K >> 5;
  const int swz = (gcir ^ (garow & 3) ^ (garow >> 2)) << 3;
  const short* Abase = A + (size_t)(a_row0 + m0 + w * 32 + garow) * K + swz;
  const short* Bbase = BT + (size_t)(n0 + w * 32 + garow) * K + swz;
  const int rswz = (l16 & 3) ^ (l16 >> 2);

  floatx4 acc[4][4];
#pragma unroll
  for (int i = 0; i < 4; ++i)
#pragma unroll
    for (int j = 0; j < 4; ++j) acc[i][j] = (floatx4){0.f, 0.f, 0.f, 0.f};

  auto STAGE = [&](int buf, int k0) {
#pragma unroll
    for (int j = 0; j < 2; ++j) {
      gload16(Abase + (size_t)j * 16 * K + k0, &As[buf][(w * 2 + j) << 9]);
      gload16(Bbase + (size_t)j * 16 * K + k0, &Bs[buf][(w * 2 + j) << 9]);
    }
  };

  STAGE(0, 0);
  if (nk > 1) STAGE(1, 32);

  int cb = 0;
  for (int t = 0; t < nk; ++t) {
    if (t + 2 < nk) {
      int sb = (cb == 0) ? 2 : cb - 1;
      STAGE(sb, (t + 2) << 5);
      asm volatile("s_waitcnt vmcnt(8)" ::: "memory");
    } else if (t + 1 < nk) {
      asm volatile("s_waitcnt vmcnt(4)" ::: "memory");
    } else {
      asm volatile("s_waitcnt vmcnt(0)" ::: "memory");
    }
    __builtin_amdgcn_s_barrier();
    short8 a[4], b[4];
#pragma unroll
    for (int mi = 0; mi < 4; ++mi) {
      int ra = wm * 64 + mi * 16 + l16;
      a[mi] = *(const short8*)(&As[cb][(ra << 5) + ((qg ^ rswz) << 3)]);
    }
#pragma unroll
    for (int ni = 0; ni < 4; ++ni) {
      int n = wn * 64 + ni * 16 + l16;
      b[ni] = *(const short8*)(&Bs[cb][(n << 5) + ((qg ^ rswz) << 3)]);
    }
    __builtin_amdgcn_s_setprio(1);
#pragma unroll
    for (int ni = 0; ni < 4; ++ni)
#pragma unroll
      for (int mi = 0; mi < 4; ++mi)
        acc[mi][ni] = __builtin_amdgcn_mfma_f32_16x16x32_bf16(a[mi], b[ni], acc[mi][ni], 0, 0, 0);
    __builtin_amdgcn_s_setprio(0);
    asm volatile("s_waitcnt lgkmcnt(0)" ::: "memory");
    __builtin_amdgcn_s_barrier();
    cb = (cb == 2) ? 0 : cb + 1;
  }
#pragma unroll
  for (int ni = 0; ni < 4; ++ni) {
    int col = n0 + wn * 64 + ni * 16 + l16;
    float bvv = bias ? loadf(bias, col, f32) : 0.0f;
#pragma unroll
    for (int mi = 0; mi < 4; ++mi) {
      int row = m0 + wm * 64 + mi * 16 + qg * 4;
#pragma unroll
      for (int r = 0; r < 4; ++r) {
        size_t idx = (size_t)(c_row0 + row + r) * N + col;
        float val = acc[mi][ni][r] + bvv;
        if (c32) ((float*)C)[idx] = val;
        else     ((short*)C)[idx] = f2b(val);
      }
    }
  }
}

// ---------- RMSNorm + RoPE: one wave per head. q additionally scaled by
// log2(e) so attention softmax runs in the exp2 domain (exact same P values).
__global__ __launch_bounds__(512)
void norm_rope(short* __restrict__ qkv, const int* __restrict__ ids,
               const void* __restrict__ nqw, const void* __restrict__ nkw,
               const void* __restrict__ naqw, const void* __restrict__ nakw,
               const int* __restrict__ dflag) {
  const bool f32 = (*dflag != 0);
  const int t = blockIdx.x, wv = threadIdx.x >> 6, lane = threadIdx.x & 63;
  const bool txt = t < 512;
  int p = lane, axis; float expo;
  if (p < 8)       { axis = 0; expo = (float)(2 * p) * (1.0f / 16.0f); }
  else if (p < 36) { axis = 1; expo = (float)(2 * (p - 8)) * (1.0f / 56.0f); }
  else             { axis = 2; expo = (float)(2 * (p - 36)) * (1.0f / 56.0f); }
  float freq = __expf(-expo * 9.210340371976184f);  // 10000^-expo
  float ang = (float)ids[t * 3 + axis] * freq;
  float s, c; sincosf(ang, &s, &c);
  const void* qw = txt ? naqw : nqw;
  const void* kw = txt ? nakw : nkw;
  float w0q = loadf(qw, 2 * lane, f32), w1q = loadf(qw, 2 * lane + 1, f32);
  float w0k = loadf(kw, 2 * lane, f32), w1k = loadf(kw, 2 * lane + 1, f32);
  const float QS = 0.08838834764831845f * 1.4426950408889634f;  // rsqrt(128)*log2(e)
#pragma unroll
  for (int i = 0; i < 3; ++i) {
    int h = wv + 8 * i;
    short* qp = qkv + (size_t)t * 9216 + h * 128 + 2 * lane;
    short* kp = qp + 3072;
    union { unsigned u; short sh[2]; } qv, kv;
    qv.u = *(const unsigned*)qp;
    kv.u = *(const unsigned*)kp;
    float q0 = b2f(qv.sh[0]), q1 = b2f(qv.sh[1]);
    float k0 = b2f(kv.sh[0]), k1 = b2f(kv.sh[1]);
    float sq = q0 * q0 + q1 * q1, sk = k0 * k0 + k1 * k1;
#pragma unroll
    for (int o = 1; o < 64; o <<= 1) { sq += __shfl_xor(sq, o); sk += __shfl_xor(sk, o); }
    float rq = rsqrtf(sq * (1.0f / 128.0f) + 1e-5f);
    float rk = rsqrtf(sk * (1.0f / 128.0f) + 1e-5f);
    float qn0 = q0 * rq * w0q, qn1 = q1 * rq * w1q;
    float kn0 = k0 * rk * w0k, kn1 = k1 * rk * w1k;
    float qo0 = qn0 * c - qn1 * s, qo1 = qn1 * c + qn0 * s;
    float ko0 = kn0 * c - kn1 * s, ko1 = kn1 * c + kn0 * s;
    union { unsigned u; short sh[2]; } qo, ko;
    qo.sh[0] = f2b(qo0 * QS);
    qo.sh[1] = f2b(qo1 * QS);
    ko.sh[0] = f2b(ko0); ko.sh[1] = f2b(ko1);
    *(unsigned*)qp = qo.u;
    *(unsigned*)kp = ko.u;
  }
}

// ---------- flash attention v7 (= v6 + exp2-domain softmax + cvt_pk P-pack).
__global__ __launch_bounds__(512, 2)
void attn_fa(const short* __restrict__ qkv, short* __restrict__ attn) {
  __shared__ short QPs[256 * 128];      // 64 KB
  __shared__ short KVs[2][128 * 128];   // 2 x 32 KB
  const int wgid = blockIdx.x;
  const int xcd = wgid & 7, slot = wgid >> 3;   // 30 slots/XCD
  const int h = xcd * 3 + slot / 10;            // 3 heads per XCD (L2-resident K/V)
  const int qt = slot % 10;
  const int tid = threadIdx.x, lane = tid & 63, w = tid >> 6;  // 8 waves
  const int qg = lane >> 4, l16 = lane & 15;
  const int lr = lane >> 4, lc = lane & 15;
  const int q0 = qt << 8;
  const int sc = tid & 15;
  const int srow5 = (tid >> 4) & 15, half = tid >> 8;

  const short* Qg  = qkv + (size_t)q0 * 9216 + h * 128;
  const short* Kg0 = qkv + 3072 + h * 128;
  const short* Vg0 = qkv + 6144 + h * 128;

  short8 vr[4];
#pragma unroll
  for (int j = 0; j < 8; ++j) {
    int row = j * 32 + w * 4 + lr;
    gload16(Qg + (size_t)row * 9216 + ((lc ^ (row & 7)) << 3),
            QPs + (j * 32 + w * 4) * 128);
  }
#pragma unroll
  for (int j = 0; j < 4; ++j) {
    int row = j * 32 + w * 4 + lr;
    gload16(Kg0 + (size_t)row * 9216 + ((lc ^ (row & 7)) << 3),
            &KVs[0][(j * 32 + w * 4) * 128]);
  }
#pragma unroll
  for (int j = 0; j < 4; ++j) {
    int row = half * 64 + j * 16 + srow5;
    vr[j] = *(const short8*)(Vg0 + (size_t)row * 9216 + sc * 8);
  }
  asm volatile("s_waitcnt vmcnt(8) lgkmcnt(0)" ::: "memory");
  __builtin_amdgcn_s_barrier();
  short8 aq[2][4];
#pragma unroll
  for (int mi = 0; mi < 2; ++mi)
#pragma unroll
    for (int kc = 0; kc < 4; ++kc) {
      int row = w * 32 + mi * 16 + l16;
      aq[mi][kc] = *(const short8*)(QPs + row * 128 + (((kc * 4 + qg) ^ (row & 7)) << 3));
    }

  floatx4 acc_o[2][8];
#pragma unroll
  for (int mi = 0; mi < 2; ++mi)
#pragma unroll
    for (int nd = 0; nd < 8; ++nd) acc_o[mi][nd] = (floatx4){0.f, 0.f, 0.f, 0.f};
  float m_i[2][4], l_i[2][4];
#pragma unroll
  for (int mi = 0; mi < 2; ++mi)
#pragma unroll
    for (int r = 0; r < 4; ++r) { m_i[mi][r] = -1e30f; l_i[mi][r] = 0.0f; }

  for (int kt = 0; kt < 20; ++kt) {
    const int c = kt & 1;
    asm volatile("s_waitcnt vmcnt(4) lgkmcnt(0)" ::: "memory");
    __builtin_amdgcn_s_barrier();
    if (kt < 19) {
      const short* Kg = qkv + ((size_t)(kt + 1) * 128) * 9216 + 3072 + h * 128;
#pragma unroll
      for (int j = 0; j < 4; ++j) {
        int row = j * 32 + w * 4 + lr;
        gload16(Kg + (size_t)row * 9216 + ((lc ^ (row & 7)) << 3),
                &KVs[1 - c][(j * 32 + w * 4) * 128]);
      }
    }
    // ---- QK^T from KVs[c] (scores already in log2 domain via q-scale)
    floatx4 acc_s[2][8];
#pragma unroll
    for (int mi = 0; mi < 2; ++mi)
#pragma unroll
      for (int ni = 0; ni < 8; ++ni) acc_s[mi][ni] = (floatx4){0.f, 0.f, 0.f, 0.f};
    __builtin_amdgcn_s_setprio(1);
#pragma unroll
    for (int kc = 0; kc < 4; ++kc) {
#pragma unroll
      for (int ni = 0; ni < 8; ++ni) {
        int row = ni * 16 + l16;
        short8 b = *(const short8*)(&KVs[c][row * 128 + (((kc * 4 + qg) ^ (row & 7)) << 3)]);
        acc_s[0][ni] = __builtin_amdgcn_mfma_f32_16x16x32_bf16(aq[0][kc], b, acc_s[0][ni], 0, 0, 0);
        acc_s[1][ni] = __builtin_amdgcn_mfma_f32_16x16x32_bf16(aq[1][kc], b, acc_s[1][ni], 0, 0, 0);
      }
    }
    __builtin_amdgcn_s_setprio(0);
    // ---- online softmax (wave-private rows), exp2 domain
    float alpha[2][4];
#pragma unroll
    for (int mi = 0; mi < 2; ++mi) {
#pragma unroll
      for (int r = 0; r < 4; ++r) {
        float mx = acc_s[mi][0][r];
#pragma unroll
        for (int ni = 1; ni < 8; ++ni) mx = fmaxf(mx, acc_s[mi][ni][r]);
        mx = fmaxf(mx, __shfl_xor(mx, 1));
        mx = fmaxf(mx, __shfl_xor(mx, 2));
        mx = fmaxf(mx, __shfl_xor(mx, 4));
        mx = fmaxf(mx, __shfl_xor(mx, 8));
        float mn = fmaxf(m_i[mi][r], mx);
        alpha[mi][r] = __builtin_amdgcn_exp2f(m_i[mi][r] - mn);
        m_i[mi][r] = mn;
      }
    }
#pragma unroll
    for (int mi = 0; mi < 2; ++mi) {
      float rs[4] = {0.f, 0.f, 0.f, 0.f};
#pragma unroll
      for (int r = 0; r < 4; ++r) {
        float pv[8];
#pragma unroll
        for (int ni = 0; ni < 8; ++ni) {
          pv[ni] = __builtin_amdgcn_exp2f(acc_s[mi][ni][r] - m_i[mi][r]);
          rs[r] += pv[ni];
        }
        unsigned u0 = cvtpk(pv[0], pv[1]);
        unsigned u1 = cvtpk(pv[2], pv[3]);
        unsigned u2 = cvtpk(pv[4], pv[5]);
        unsigned u3 = cvtpk(pv[6], pv[7]);
        int row = w * 32 + mi * 16 + qg * 4 + r;  // wave-private P row
        uint4 uu; uu.x = u0; uu.y = u1; uu.z = u2; uu.w = u3;
        *(uint4*)(QPs + row * 128 + ((l16 ^ (row & 15)) << 3)) = uu;
      }
#pragma unroll
      for (int r = 0; r < 4; ++r) {
        float t = rs[r];
        t += __shfl_xor(t, 1); t += __shfl_xor(t, 2);
        t += __shfl_xor(t, 4); t += __shfl_xor(t, 8);
        l_i[mi][r] = alpha[mi][r] * l_i[mi][r] + t;
      }
#pragma unroll
      for (int nd = 0; nd < 8; ++nd)
#pragma unroll
        for (int r = 0; r < 4; ++r) acc_o[mi][nd][r] *= alpha[mi][r];
    }
    asm volatile("s_waitcnt lgkmcnt(0)" ::: "memory");
    __builtin_amdgcn_s_barrier();
    // ---- commit V^T(kt) into KVs[c]: token r -> col t' = 8*(r&15) + (r>>4).
#pragma unroll
    for (int u = 0; u < 8; ++u) {
      int d = sc * 8 + u;
      short4v pk = { vr[0][u], vr[1][u], vr[2][u], vr[3][u] };
      *(short4v*)(&KVs[c][d * 128 + (((srow5 ^ u ^ (sc & 7))) << 3) + half * 4]) = pk;
    }
    if (kt < 19) {
      const short* Vg = qkv + ((size_t)(kt + 1) * 128) * 9216 + 6144 + h * 128;
#pragma unroll
      for (int j = 0; j < 4; ++j) {
        int row = half * 64 + j * 16 + srow5;
        vr[j] = *(const short8*)(Vg + (size_t)row * 9216 + sc * 8);
      }
    }
    asm volatile("s_waitcnt lgkmcnt(0)" ::: "memory");
    __builtin_amdgcn_s_barrier();
    // ---- PV
    __builtin_amdgcn_s_setprio(1);
#pragma unroll
    for (int kc = 0; kc < 4; ++kc) {
      int prow0 = w * 32 + l16;
      short8 ap0 = *(const short8*)(QPs + prow0 * 128 + (((kc * 4 + qg) ^ (prow0 & 15)) << 3));
      int prow1 = prow0 + 16;
      short8 ap1 = *(const short8*)(QPs + prow1 * 128 + (((kc * 4 + qg) ^ (prow1 & 15)) << 3));
#pragma unroll
      for (int nd = 0; nd < 8; ++nd) {
        int row = nd * 16 + l16;
        int chn = (kc * 4 + qg) ^ (row & 7) ^ ((row >> 3) & 7);
        short8 b = *(const short8*)(&KVs[c][row * 128 + (chn << 3)]);
        acc_o[0][nd] = __builtin_amdgcn_mfma_f32_16x16x32_bf16(ap0, b, acc_o[0][nd], 0, 0, 0);
        acc_o[1][nd] = __builtin_amdgcn_mfma_f32_16x16x32_bf16(ap1, b, acc_o[1][nd], 0, 0, 0);
      }
    }
    __builtin_amdgcn_s_setprio(0);
  }
  // ---- epilogue: normalize, transpose through QPs, coalesced b128 stores
#pragma unroll
  for (int mi = 0; mi < 2; ++mi) {
    float inv[4];
#pragma unroll
    for (int r = 0; r < 4; ++r) inv[r] = 1.0f / l_i[mi][r];
#pragma unroll
    for (int nd = 0; nd < 8; ++nd) {
#pragma unroll
      for (int r = 0; r < 4; ++r) {
        int row = w * 32 + mi * 16 + qg * 4 + r;
        QPs[row * 128 + nd * 16 + l16] = f2b(acc_o[mi][nd][r] * inv[r]);
      }
    }
  }
  asm volatile("s_waitcnt lgkmcnt(0)" ::: "memory");
#pragma unroll
  for (int j = 0; j < 8; ++j) {
    int rrow = w * 32 + j * 4 + qg;   // 4 rows x 16 col-chunks per iteration
    short8 vv = *(const short8*)(QPs + rrow * 128 + l16 * 8);
    *(short8*)(attn + (size_t)(q0 + rrow) * 3072 + h * 128 + l16 * 8) = vv;
  }
}

extern "C" void kernel_launch(void* const* d_in, const int* in_sizes, int n_in,
                              void* d_out, int out_size, void* d_ws, size_t ws_size,
                              hipStream_t stream) {
  (void)in_sizes; (void)n_in; (void)out_size;
  const void* hidden    = d_in[0];
  const void* enc       = d_in[1];
  const int*  ids       = (const int*)d_in[2];
  const void* w_qkv     = d_in[3];
  const void* w_add_qkv = d_in[4];
  const void* b_add_qkv = d_in[5];
  const void* w_out     = d_in[6];
  const void* b_out     = d_in[7];
  const void* w_add_out = d_in[8];
  const void* b_add_out = d_in[9];
  const void* nqw  = d_in[10];
  const void* nkw  = d_in[11];
  const void* naqw = d_in[12];
  const void* nakw = d_in[13];

  int*   dflag = (int*)d_ws;
  short* qkv   = (short*)((char*)d_ws + 256);   // [2560][9216] bf16
  short* attnB = qkv + (size_t)2560 * 9216;     // [2560][3072] bf16

  // bf16 pool: hidden, enc (row-major) + w_qkv^T, w_add_qkv^T, w_out^T, w_add_out^T
  short* pool  = attnB + (size_t)2560 * 3072;
  const long n_hid  = 2048L * 3072;
  const long n_enc  = 512L * 3072;
  const long n_wqkv = 3072L * 9216;
  const long n_wout = 3072L * 3072;
  short* hb   = pool;
  short* eb   = hb + n_hid;
  short* wqb  = eb + n_enc;        // w_qkv^T    [9216][3072]
  short* waqb = wqb + n_wqkv;      // w_add_qkv^T[9216][3072]
  short* wob  = waqb + n_wqkv;     // w_out^T    [3072][3072]
  short* waob = wob + n_wout;      // w_add_out^T[3072][3072]
  const size_t REQ = 256 + 2 * ((size_t)2560 * 9216 + (size_t)2560 * 3072 +
                                n_hid + n_enc + 2 * n_wqkv + 2 * n_wout);

  detect_dtype<<<1, 256, 0, stream>>>((const unsigned short*)w_qkv, dflag);

  if (ws_size >= REQ) {
    cvt_bf16<<<1024, 256, 0, stream>>>(hidden, hb, n_hid / 8, dflag);
    cvt_bf16<<<256, 256, 0, stream>>>(enc, eb, n_enc / 8, dflag);
    cvt_t<<<dim3(144, 48), 256, 0, stream>>>(w_qkv,     wqb,  3072, 9216, dflag);
    cvt_t<<<dim3(144, 48), 256, 0, stream>>>(w_add_qkv, waqb, 3072, 9216, dflag);
    cvt_t<<<dim3(48, 48), 256, 0, stream>>>(w_out,     wob,  3072, 3072, dflag);
    cvt_t<<<dim3(48, 48), 256, 0, stream>>>(w_add_out, waob, 3072, 3072, dflag);

    gemm_bf2<<<dim3(72, 4), 256, 0, stream>>>(eb, 0, waqb, b_add_qkv, qkv, 0, 9216, 3072, dflag, 0);
    gemm_bf2<<<dim3(72, 16), 256, 0, stream>>>(hb, 0, wqb, nullptr, qkv, 512, 9216, 3072, dflag, 0);
    norm_rope<<<dim3(2560), 512, 0, stream>>>(qkv, ids, nqw, nkw, naqw, nakw, dflag);
    attn_fa<<<dim3(240), 512, 0, stream>>>(qkv, attnB);
    gemm_bf2<<<dim3(24, 16), 256, 0, stream>>>(attnB, 512, wob, b_out, d_out, 0, 3072, 3072, dflag, 1);
    gemm_bf2<<<dim3(24, 4), 256, 0, stream>>>(attnB, 0, waob, b_add_out, d_out, 2048, 3072, 3072, dflag, 1);
  } else {
    gemm_bt<<<dim3(72, 4), 256, 0, stream>>>(enc, 0, w_add_qkv, b_add_qkv, qkv, 0, 9216, 3072, dflag, 1, 0);
    gemm_bt<<<dim3(72, 16), 256, 0, stream>>>(hidden, 0, w_qkv, nullptr, qkv, 512, 9216, 3072, dflag, 1, 0);
    norm_rope<<<dim3(2560), 512, 0, stream>>>(qkv, ids, nqw, nkw, naqw, nakw, dflag);
    attn_fa<<<dim3(240), 512, 0, stream>>>(qkv, attnB);
    gemm_bt<<<dim3(24, 16), 256, 0, stream>>>(attnB, 512, w_out, b_out, d_out, 0, 3072, 3072, dflag, 0, 1);
    gemm_bt<<<dim3(24, 4), 256, 0, stream>>>(attnB, 0, w_add_out, b_add_out, d_out, 2048, 3072, 3072, dflag, 0, 1);
  }
}

// Round 11
// 876.832 us; speedup vs baseline: 1.1817x; 1.1243x over previous
//
#include <hip/hip_runtime.h>

typedef __attribute__((ext_vector_type(8))) short short8;
typedef __attribute__((ext_vector_type(4))) short short4v;
typedef __attribute__((ext_vector_type(4))) float floatx4;

__device__ __forceinline__ float b2f(short b) {
  union { unsigned u; float f; } v; v.u = ((unsigned)(unsigned short)b) << 16; return v.f;
}
__device__ __forceinline__ short f2b(float f) {
  union { float f; unsigned u; } v; v.f = f;
  return (short)((v.u + 0x7fffu + ((v.u >> 16) & 1u)) >> 16);
}
// packed f32x2 -> bf16x2 (RNE), single VOP3 instr
__device__ __forceinline__ unsigned cvtpk(float lo, float hi) {
  unsigned r;
  asm("v_cvt_pk_bf16_f32 %0, %1, %2" : "=v"(r) : "v"(lo), "v"(hi));
  return r;
}
__device__ __forceinline__ float loadf(const void* p, size_t i, bool f32) {
  return f32 ? ((const float*)p)[i] : b2f(((const short*)p)[i]);
}
__device__ __forceinline__ short8 load8(const void* p, size_t i, bool f32) {
  if (f32) {
    const float* fp = (const float*)p + i;
    float4 a = *(const float4*)fp;
    float4 b = *(const float4*)(fp + 4);
    short8 r;
    r[0] = f2b(a.x); r[1] = f2b(a.y); r[2] = f2b(a.z); r[3] = f2b(a.w);
    r[4] = f2b(b.x); r[5] = f2b(b.y); r[6] = f2b(b.z); r[7] = f2b(b.w);
    return r;
  }
  return *(const short8*)((const short*)p + i);
}

// async global->LDS, 16B per lane. LDS dest = wave-uniform base + lane*16.
__device__ __forceinline__ void gload16(const short* g, short* l) {
  __builtin_amdgcn_global_load_lds(
      (const __attribute__((address_space(1))) unsigned int*)g,
      (__attribute__((address_space(3))) unsigned int*)l, 16, 0, 0);
}

// ---------- dtype detector
__global__ void detect_dtype(const unsigned short* __restrict__ w, int* __restrict__ flag) {
  __shared__ int cnt;
  if (threadIdx.x == 0) cnt = 0;
  __syncthreads();
  int bad = 0;
  for (int i = threadIdx.x; i < 4096; i += 256) {
    int e = (w[i] >> 7) & 0xFF;
    if (e >= 0xC8) bad++;
  }
  atomicAdd(&cnt, bad);
  __syncthreads();
  if (threadIdx.x == 0) *flag = (cnt > 64) ? 1 : 0;
}

// ---------- one-time dtype normalization: src -> bf16
__global__ __launch_bounds__(256)
void cvt_bf16(const void* __restrict__ src, short* __restrict__ dst, long n8,
              const int* __restrict__ dflag) {
  const bool f32 = (*dflag != 0);
  long stride = (long)gridDim.x * 256;
  for (long i = (long)blockIdx.x * 256 + threadIdx.x; i < n8; i += stride) {
    long e = i * 8;
    if (f32) {
      const float* fp = (const float*)src + e;
      float4 a = *(const float4*)fp;
      float4 b = *(const float4*)(fp + 4);
      short8 r;
      r[0] = f2b(a.x); r[1] = f2b(a.y); r[2] = f2b(a.z); r[3] = f2b(a.w);
      r[4] = f2b(b.x); r[5] = f2b(b.y); r[6] = f2b(b.z); r[7] = f2b(b.w);
      *(short8*)(dst + e) = r;
    } else {
      *(short8*)(dst + e) = *(const short8*)((const short*)src + e);
    }
  }
}

// ---------- cvt_t v2: src [K][N] -> dst [N][K] bf16 (vectorized both sides).
__global__ __launch_bounds__(256)
void cvt_t(const void* __restrict__ src, short* __restrict__ dst,
           int K, int N, const int* __restrict__ dflag) {
  __shared__ short st[64][72];
  const bool f32 = (*dflag != 0);
  const int n0 = blockIdx.x << 6, k0 = blockIdx.y << 6;
  const int c4 = threadIdx.x & 15;
  const int rq = threadIdx.x >> 4;
#pragma unroll
  for (int r = 0; r < 4; ++r) {
    int k = r * 16 + rq;
    int n = c4 * 4;
    short v0, v1, v2, v3;
    if (f32) {
      const float* sp = (const float*)src + (size_t)(k0 + k) * N + n0 + n;
      float4 f = *(const float4*)sp;
      v0 = f2b(f.x); v1 = f2b(f.y); v2 = f2b(f.z); v3 = f2b(f.w);
    } else {
      const short* sp = (const short*)src + (size_t)(k0 + k) * N + n0 + n;
      short4v s = *(const short4v*)sp;
      v0 = s[0]; v1 = s[1]; v2 = s[2]; v3 = s[3];
    }
    st[n + 0][k] = v0; st[n + 1][k] = v1; st[n + 2][k] = v2; st[n + 3][k] = v3;
  }
  __syncthreads();
  const int n = threadIdx.x >> 2;
  const int kc = (threadIdx.x & 3) << 4;
  short8 a = *(const short8*)(&st[n][kc]);
  short8 b = *(const short8*)(&st[n][kc + 8]);
  short* dp = dst + (size_t)(n0 + n) * K + k0 + kc;
  *(short8*)(dp) = a;
  *(short8*)(dp + 8) = b;
}

// ---------- OLD GEMM (fallback) ----------
__global__ __launch_bounds__(256, 2)
void gemm_bt(const void* __restrict__ A, int a_row0,
             const void* __restrict__ B, const void* __restrict__ bias,
             void* __restrict__ C, int c_row0, int N, int K,
             const int* __restrict__ dflag, int aIn, int cOut) {
  __shared__ short As[128 * 32];
  __shared__ short Bs[128 * 32];
  const bool f32 = (*dflag != 0);
  const bool a32 = aIn && f32;
  const bool c32 = cOut && f32;
  const int tid = threadIdx.x;
  const int lane = tid & 63, w = tid >> 6;
  const int wm = w & 1, wn = w >> 1;
  const int qg = lane >> 4, l16 = lane & 15;
  const int m0 = blockIdx.y << 7, n0 = blockIdx.x << 7;

  const int arow = tid >> 2, ak = (tid & 3) << 3;
  const int brow = tid >> 4, bc = (tid & 15) << 3;
  const int rot = tid & 15;

  floatx4 acc[4][4];
#pragma unroll
  for (int i = 0; i < 4; ++i)
#pragma unroll
    for (int j = 0; j < 4; ++j) acc[i][j] = (floatx4){0.f, 0.f, 0.f, 0.f};

  for (int k0 = 0; k0 < K; k0 += 32) {
    __syncthreads();
#pragma unroll
    for (int j = 0; j < 2; ++j) {
      short8 av = load8(A, (size_t)(a_row0 + m0 + j * 64 + arow) * K + (k0 + ak), a32);
      *(short8*)(As + (j * 64 + arow) * 32 + ak) = av;
      int kr = j * 16 + brow;
      short8 bv = load8(B, (size_t)(k0 + kr) * N + (n0 + bc), f32);
      int kq = kr >> 3, kj = kr & 7;
#pragma unroll
      for (int s = 0; s < 8; ++s) {
        int u = (s + rot) & 7;
        int n = bc + u;
        Bs[(n << 5) + ((kq ^ (n & 3)) << 3) + kj] = bv[u];
      }
    }
    __syncthreads();
    short8 a[4];
#pragma unroll
    for (int mi = 0; mi < 4; ++mi)
      a[mi] = *(const short8*)(As + (wm * 64 + mi * 16 + l16) * 32 + qg * 8);
#pragma unroll
    for (int ni = 0; ni < 4; ++ni) {
      int n = wn * 64 + ni * 16 + l16;
      short8 b = *(const short8*)(Bs + (n << 5) + ((qg ^ (n & 3)) << 3));
#pragma unroll
      for (int mi = 0; mi < 4; ++mi)
        acc[mi][ni] = __builtin_amdgcn_mfma_f32_16x16x32_bf16(a[mi], b, acc[mi][ni], 0, 0, 0);
    }
  }
#pragma unroll
  for (int ni = 0; ni < 4; ++ni) {
    int col = n0 + wn * 64 + ni * 16 + l16;
    float bv = bias ? loadf(bias, col, f32) : 0.0f;
#pragma unroll
    for (int mi = 0; mi < 4; ++mi) {
      int row = m0 + wm * 64 + mi * 16 + qg * 4;
#pragma unroll
      for (int r = 0; r < 4; ++r) {
        size_t idx = (size_t)(c_row0 + row + r) * N + col;
        float val = acc[mi][ni][r] + bv;
        if (c32) ((float*)C)[idx] = val;
        else     ((short*)C)[idx] = f2b(val);
      }
    }
  }
}

// ---------- GEMM v7: depth-2 pipelined (R9-proven) + per-block param select
// so two logical GEMMs (different B/bias/row-mapping) fuse into ONE launch:
// blockIdx.y < nYa -> set A (BTa,biasa,a0a,c0a), else set B with my=y-nYa.
__global__ __launch_bounds__(256, 3)
void gemm_bf2(const short* __restrict__ A,
              const short* __restrict__ BTa, const void* __restrict__ biasa,
              int a0a, int c0a, int nYa,
              const short* __restrict__ BTb, const void* __restrict__ biasb,
              int a0b, int c0b,
              void* __restrict__ C, int N, int K,
              const int* __restrict__ dflag, int cOut) {
  __shared__ short As[3][128 * 32];
  __shared__ short Bs[3][128 * 32];
  const bool f32 = (*dflag != 0);
  const bool c32 = cOut && f32;
  const int y = blockIdx.y;
  const short* BT; const void* bias; int arow0, crow0;
  if (y < nYa) { BT = BTa; bias = biasa; arow0 = a0a + (y << 7); crow0 = c0a + (y << 7); }
  else { int my = y - nYa; BT = BTb; bias = biasb; arow0 = a0b + (my << 7); crow0 = c0b + (my << 7); }
  const int tid = threadIdx.x;
  const int lane = tid & 63, w = tid >> 6;
  const int wm = w & 1, wn = w >> 1;
  const int qg = lane >> 4, l16 = lane & 15;
  const int n0 = blockIdx.x << 7;
  const int garow = lane >> 2;
  const int gcir = lane & 3;
  const int nk = K >> 5;
  const int swz = (gcir ^ (garow & 3) ^ (garow >> 2)) << 3;
  const short* Abase = A + (size_t)(arow0 + w * 32 + garow) * K + swz;
  const short* Bbase = BT + (size_t)(n0 + w * 32 + garow) * K + swz;
  const int rswz = (l16 & 3) ^ (l16 >> 2);

  floatx4 acc[4][4];
#pragma unroll
  for (int i = 0; i < 4; ++i)
#pragma unroll
    for (int j = 0; j < 4; ++j) acc[i][j] = (floatx4){0.f, 0.f, 0.f, 0.f};

  auto STAGE = [&](int buf, int k0) {
#pragma unroll
    for (int j = 0; j < 2; ++j) {
      gload16(Abase + (size_t)j * 16 * K + k0, &As[buf][(w * 2 + j) << 9]);
      gload16(Bbase + (size_t)j * 16 * K + k0, &Bs[buf][(w * 2 + j) << 9]);
    }
  };

  STAGE(0, 0);
  if (nk > 1) STAGE(1, 32);

  int cb = 0;
  for (int t = 0; t < nk; ++t) {
    if (t + 2 < nk) {
      int sb = (cb == 0) ? 2 : cb - 1;
      STAGE(sb, (t + 2) << 5);
      asm volatile("s_waitcnt vmcnt(8)" ::: "memory");
    } else if (t + 1 < nk) {
      asm volatile("s_waitcnt vmcnt(4)" ::: "memory");
    } else {
      asm volatile("s_waitcnt vmcnt(0)" ::: "memory");
    }
    __builtin_amdgcn_s_barrier();
    short8 a[4], b[4];
#pragma unroll
    for (int mi = 0; mi < 4; ++mi) {
      int ra = wm * 64 + mi * 16 + l16;
      a[mi] = *(const short8*)(&As[cb][(ra << 5) + ((qg ^ rswz) << 3)]);
    }
#pragma unroll
    for (int ni = 0; ni < 4; ++ni) {
      int n = wn * 64 + ni * 16 + l16;
      b[ni] = *(const short8*)(&Bs[cb][(n << 5) + ((qg ^ rswz) << 3)]);
    }
    __builtin_amdgcn_s_setprio(1);
#pragma unroll
    for (int ni = 0; ni < 4; ++ni)
#pragma unroll
      for (int mi = 0; mi < 4; ++mi)
        acc[mi][ni] = __builtin_amdgcn_mfma_f32_16x16x32_bf16(a[mi], b[ni], acc[mi][ni], 0, 0, 0);
    __builtin_amdgcn_s_setprio(0);
    asm volatile("s_waitcnt lgkmcnt(0)" ::: "memory");
    __builtin_amdgcn_s_barrier();
    cb = (cb == 2) ? 0 : cb + 1;
  }
#pragma unroll
  for (int ni = 0; ni < 4; ++ni) {
    int col = n0 + wn * 64 + ni * 16 + l16;
    float bvv = bias ? loadf(bias, col, f32) : 0.0f;
#pragma unroll
    for (int mi = 0; mi < 4; ++mi) {
      int row = wm * 64 + mi * 16 + qg * 4;
#pragma unroll
      for (int r = 0; r < 4; ++r) {
        size_t idx = (size_t)(crow0 + row + r) * N + col;
        float val = acc[mi][ni][r] + bvv;
        if (c32) ((float*)C)[idx] = val;
        else     ((short*)C)[idx] = f2b(val);
      }
    }
  }
}

// ---------- RMSNorm + RoPE (unchanged): q scaled by rsqrt(128)*log2(e).
__global__ __launch_bounds__(512)
void norm_rope(short* __restrict__ qkv, const int* __restrict__ ids,
               const void* __restrict__ nqw, const void* __restrict__ nkw,
               const void* __restrict__ naqw, const void* __restrict__ nakw,
               const int* __restrict__ dflag) {
  const bool f32 = (*dflag != 0);
  const int t = blockIdx.x, wv = threadIdx.x >> 6, lane = threadIdx.x & 63;
  const bool txt = t < 512;
  int p = lane, axis; float expo;
  if (p < 8)       { axis = 0; expo = (float)(2 * p) * (1.0f / 16.0f); }
  else if (p < 36) { axis = 1; expo = (float)(2 * (p - 8)) * (1.0f / 56.0f); }
  else             { axis = 2; expo = (float)(2 * (p - 36)) * (1.0f / 56.0f); }
  float freq = __expf(-expo * 9.210340371976184f);
  float ang = (float)ids[t * 3 + axis] * freq;
  float s, c; sincosf(ang, &s, &c);
  const void* qw = txt ? naqw : nqw;
  const void* kw = txt ? nakw : nkw;
  float w0q = loadf(qw, 2 * lane, f32), w1q = loadf(qw, 2 * lane + 1, f32);
  float w0k = loadf(kw, 2 * lane, f32), w1k = loadf(kw, 2 * lane + 1, f32);
  const float QS = 0.08838834764831845f * 1.4426950408889634f;
#pragma unroll
  for (int i = 0; i < 3; ++i) {
    int h = wv + 8 * i;
    short* qp = qkv + (size_t)t * 9216 + h * 128 + 2 * lane;
    short* kp = qp + 3072;
    union { unsigned u; short sh[2]; } qv, kv;
    qv.u = *(const unsigned*)qp;
    kv.u = *(const unsigned*)kp;
    float q0 = b2f(qv.sh[0]), q1 = b2f(qv.sh[1]);
    float k0 = b2f(kv.sh[0]), k1 = b2f(kv.sh[1]);
    float sq = q0 * q0 + q1 * q1, sk = k0 * k0 + k1 * k1;
#pragma unroll
    for (int o = 1; o < 64; o <<= 1) { sq += __shfl_xor(sq, o); sk += __shfl_xor(sk, o); }
    float rq = rsqrtf(sq * (1.0f / 128.0f) + 1e-5f);
    float rk = rsqrtf(sk * (1.0f / 128.0f) + 1e-5f);
    float qn0 = q0 * rq * w0q, qn1 = q1 * rq * w1q;
    float kn0 = k0 * rk * w0k, kn1 = k1 * rk * w1k;
    float qo0 = qn0 * c - qn1 * s, qo1 = qn1 * c + qn0 * s;
    float ko0 = kn0 * c - kn1 * s, ko1 = kn1 * c + kn0 * s;
    union { unsigned u; short sh[2]; } qo, ko;
    qo.sh[0] = f2b(qo0 * QS);
    qo.sh[1] = f2b(qo1 * QS);
    ko.sh[0] = f2b(ko0); ko.sh[1] = f2b(ko1);
    *(unsigned*)qp = qo.u;
    *(unsigned*)kp = ko.u;
  }
}

// ---------- flash attention v8: restructured for 2 blocks/CU.
// Q-tile 128 (8 waves x 16 q-rows), key-block 64, Q direct-to-register.
// LDS: Ps 128x64 (16 KB) + Ks dbuf 2x(64x128) (32 KB) = 48 KB; VGPR ~110
// with __launch_bounds__(512,4) -> 2 blocks/CU (R10 evidence: per-iter cost
// 24K cyc has been constant since R3 because phases serialize in the single
// resident block; LDS stream per wave is invariant, so overlap is the lever).
// k-order perm for KB=64: t' = 4*(t&15) + (t>>4) for P pack AND V^T commit.
// V^T chunk swizzle ^(d&7)^((d>>3)&7); K/P chunk swizzle ^(row&7).
__global__ __launch_bounds__(512, 4)
void attn_fa(const short* __restrict__ qkv, short* __restrict__ attn) {
  __shared__ short Ps[128 * 64];      // 16 KB: P rows(128) x 64 permuted keys
  __shared__ short Ks[2][64 * 128];   // 32 KB: K tiles (V^T overwrites in-place)
  const int wgid = blockIdx.x;
  const int xcd = wgid & 7, slot = wgid >> 3;   // 60 slots/XCD
  const int h = xcd * 3 + slot / 20;            // 3 heads per XCD
  const int qt = slot % 20;
  const int tid = threadIdx.x, lane = tid & 63, w = tid >> 6;  // 8 waves
  const int qg = lane >> 4, l16 = lane & 15;
  const int lr = lane >> 4, lc = lane & 15;
  const int q0 = qt << 7;
  const int sc = tid & 15;              // V chunk
  const int s = (tid >> 4) & 15;        // V token-sub
  const int half = tid >> 8;            // V token-half

  const short* Qg = qkv + (size_t)q0 * 9216 + h * 128;
  const short* KgB = qkv + 3072 + h * 128;
  const short* VgB = qkv + 6144 + h * 128;

  // ---- prologue: K(0) glds, aq direct loads, V(0) reg loads
#pragma unroll
  for (int j = 0; j < 2; ++j) {
    int row = j * 32 + w * 4 + lr;
    gload16(KgB + (size_t)row * 9216 + ((lc ^ (row & 7)) << 3),
            &Ks[0][(j * 32 + w * 4) * 128]);
  }
  short8 aq[4];
#pragma unroll
  for (int kc = 0; kc < 4; ++kc)
    aq[kc] = *(const short8*)(Qg + (size_t)(w * 16 + l16) * 9216 + kc * 32 + qg * 8);
  short8 vr[2];
#pragma unroll
  for (int jj = 0; jj < 2; ++jj) {
    int row = (2 * half + jj) * 16 + s;
    vr[jj] = *(const short8*)(VgB + (size_t)row * 9216 + sc * 8);
  }

  floatx4 acc_o[8];
#pragma unroll
  for (int nd = 0; nd < 8; ++nd) acc_o[nd] = (floatx4){0.f, 0.f, 0.f, 0.f};
  float m_i[4], l_i[4];
#pragma unroll
  for (int r = 0; r < 4; ++r) { m_i[r] = -1e30f; l_i[r] = 0.0f; }

  for (int kt = 0; kt < 40; ++kt) {
    const int cb = kt & 1;
    // K(kt) done (2 oldest); V(kt) may stay in flight. PV(kt-1) LDS reads drained.
    asm volatile("s_waitcnt vmcnt(2) lgkmcnt(0)" ::: "memory");
    __builtin_amdgcn_s_barrier();
    if (kt < 39) {   // issue K(kt+1) -> other buffer (freed by the barrier above)
      const short* Kg = KgB + (size_t)(kt + 1) * 64 * 9216;
#pragma unroll
      for (int j = 0; j < 2; ++j) {
        int row = j * 32 + w * 4 + lr;
        gload16(Kg + (size_t)row * 9216 + ((lc ^ (row & 7)) << 3),
                &Ks[1 - cb][(j * 32 + w * 4) * 128]);
      }
    }
    // ---- QK^T: 16 q-rows x 64 keys
    floatx4 acc_s[4];
#pragma unroll
    for (int ni = 0; ni < 4; ++ni) acc_s[ni] = (floatx4){0.f, 0.f, 0.f, 0.f};
    __builtin_amdgcn_s_setprio(1);
#pragma unroll
    for (int kc = 0; kc < 4; ++kc) {
#pragma unroll
      for (int ni = 0; ni < 4; ++ni) {
        int row = ni * 16 + l16;
        short8 b = *(const short8*)(&Ks[cb][row * 128 + (((kc * 4 + qg) ^ (row & 7)) << 3)]);
        acc_s[ni] = __builtin_amdgcn_mfma_f32_16x16x32_bf16(aq[kc], b, acc_s[ni], 0, 0, 0);
      }
    }
    __builtin_amdgcn_s_setprio(0);
    // ---- online softmax (exp2 domain; scores pre-scaled by log2e)
    float alpha[4];
#pragma unroll
    for (int r = 0; r < 4; ++r) {
      float mx = acc_s[0][r];
#pragma unroll
      for (int ni = 1; ni < 4; ++ni) mx = fmaxf(mx, acc_s[ni][r]);
      mx = fmaxf(mx, __shfl_xor(mx, 1));
      mx = fmaxf(mx, __shfl_xor(mx, 2));
      mx = fmaxf(mx, __shfl_xor(mx, 4));
      mx = fmaxf(mx, __shfl_xor(mx, 8));
      float mn = fmaxf(m_i[r], mx);
      alpha[r] = __builtin_amdgcn_exp2f(m_i[r] - mn);
      m_i[r] = mn;
    }
    float rs[4];
#pragma unroll
    for (int r = 0; r < 4; ++r) {
      float p0 = __builtin_amdgcn_exp2f(acc_s[0][r] - m_i[r]);
      float p1 = __builtin_amdgcn_exp2f(acc_s[1][r] - m_i[r]);
      float p2 = __builtin_amdgcn_exp2f(acc_s[2][r] - m_i[r]);
      float p3 = __builtin_amdgcn_exp2f(acc_s[3][r] - m_i[r]);
      rs[r] = (p0 + p1) + (p2 + p3);
      // P pack: key t = ni*16+l16 -> t' = 4*l16 + ni  (b64 per row)
      unsigned u0 = cvtpk(p0, p1);
      unsigned u1 = cvtpk(p2, p3);
      int row = w * 16 + qg * 4 + r;  // wave-private
      uint2 uu; uu.x = u0; uu.y = u1;
      *(uint2*)(Ps + row * 64 + ((((l16 >> 1) ^ (row & 7)) << 3) + ((l16 & 1) << 2))) = uu;
    }
#pragma unroll
    for (int r = 0; r < 4; ++r) {
      float t = rs[r];
      t += __shfl_xor(t, 1); t += __shfl_xor(t, 2);
      t += __shfl_xor(t, 4); t += __shfl_xor(t, 8);
      l_i[r] = alpha[r] * l_i[r] + t;
    }
#pragma unroll
    for (int nd = 0; nd < 8; ++nd)
#pragma unroll
      for (int r = 0; r < 4; ++r) acc_o[nd][r] *= alpha[r];
    asm volatile("s_waitcnt lgkmcnt(0)" ::: "memory");
    __builtin_amdgcn_s_barrier();
    // ---- commit V^T(kt) into Ks[cb] (overwrite K): token t -> t'=4*(t&15)+(t>>4)
    // thread holds tokens (2*half+jj)*16+s -> t' = 4s+2half+jj (b32 pair).
#pragma unroll
    for (int u = 0; u < 8; ++u) {
      int d = sc * 8 + u;
      int cc = (s >> 1) ^ u ^ (sc & 7);   // (d&7)=u, (d>>3)&7=sc&7
      union { unsigned uu; short sh[2]; } pk;
      pk.sh[0] = vr[0][u]; pk.sh[1] = vr[1][u];
      *(unsigned*)(&Ks[cb][d * 64 + (cc << 3) + ((s & 1) << 2) + (half << 1)]) = pk.uu;
    }
    if (kt < 39) {   // V(kt+1) reg loads (in flight across PV + next QK^T)
      const short* Vg = VgB + (size_t)(kt + 1) * 64 * 9216;
#pragma unroll
      for (int jj = 0; jj < 2; ++jj) {
        int row = (2 * half + jj) * 16 + s;
        vr[jj] = *(const short8*)(Vg + (size_t)row * 9216 + sc * 8);
      }
    }
    asm volatile("s_waitcnt lgkmcnt(0)" ::: "memory");
    __builtin_amdgcn_s_barrier();
    // ---- PV: A = P (wave-private rows), B = V^T in Ks[cb]
    __builtin_amdgcn_s_setprio(1);
#pragma unroll
    for (int kc = 0; kc < 2; ++kc) {
      int prow = w * 16 + l16;
      short8 ap = *(const short8*)(Ps + prow * 64 + (((kc * 4 + qg) ^ (prow & 7)) << 3));
#pragma unroll
      for (int nd = 0; nd < 8; ++nd) {
        int d = nd * 16 + l16;
        int cc = (kc * 4 + qg) ^ (d & 7) ^ ((d >> 3) & 7);
        short8 b = *(const short8*)(&Ks[cb][d * 64 + (cc << 3)]);
        acc_o[nd] = __builtin_amdgcn_mfma_f32_16x16x32_bf16(ap, b, acc_o[nd], 0, 0, 0);
      }
    }
    __builtin_amdgcn_s_setprio(0);
  }
  // ---- epilogue: normalize, transpose through Ks (flat 128x128, freed), store
  asm volatile("s_waitcnt lgkmcnt(0)" ::: "memory");
  __builtin_amdgcn_s_barrier();   // all waves done with PV reads of Ks
  short* Es = &Ks[0][0];          // 128 rows x 128 shorts
  float inv[4];
#pragma unroll
  for (int r = 0; r < 4; ++r) inv[r] = 1.0f / l_i[r];
#pragma unroll
  for (int nd = 0; nd < 8; ++nd) {
#pragma unroll
    for (int r = 0; r < 4; ++r) {
      int row = w * 16 + qg * 4 + r;
      int col = nd * 16 + l16;
      Es[row * 128 + ((col + 8 * row) & 127)] = f2b(acc_o[nd][r] * inv[r]);
    }
  }
  asm volatile("s_waitcnt lgkmcnt(0)" ::: "memory");   // wave-private rows: no barrier
#pragma unroll
  for (int j = 0; j < 4; ++j) {
    int rrow = w * 16 + j * 4 + (lane >> 4);
    int c8 = lane & 15;
    short8 vv = *(const short8*)(Es + rrow * 128 + 8 * ((c8 + rrow) & 15));
    *(short8*)(attn + (size_t)(q0 + rrow) * 3072 + h * 128 + c8 * 8) = vv;
  }
}

extern "C" void kernel_launch(void* const* d_in, const int* in_sizes, int n_in,
                              void* d_out, int out_size, void* d_ws, size_t ws_size,
                              hipStream_t stream) {
  (void)in_sizes; (void)n_in; (void)out_size;
  const void* hidden    = d_in[0];
  const void* enc       = d_in[1];
  const int*  ids       = (const int*)d_in[2];
  const void* w_qkv     = d_in[3];
  const void* w_add_qkv = d_in[4];
  const void* b_add_qkv = d_in[5];
  const void* w_out     = d_in[6];
  const void* b_out     = d_in[7];
  const void* w_add_out = d_in[8];
  const void* b_add_out = d_in[9];
  const void* nqw  = d_in[10];
  const void* nkw  = d_in[11];
  const void* naqw = d_in[12];
  const void* nakw = d_in[13];

  int*   dflag = (int*)d_ws;
  short* qkv   = (short*)((char*)d_ws + 256);   // [2560][9216] bf16
  short* attnB = qkv + (size_t)2560 * 9216;     // [2560][3072] bf16

  // bf16 pool: xb = concat(enc rows 0..512, hidden rows 512..2560) + weightsT
  short* pool  = attnB + (size_t)2560 * 3072;
  const long n_hid  = 2048L * 3072;
  const long n_enc  = 512L * 3072;
  const long n_wqkv = 3072L * 9216;
  const long n_wout = 3072L * 3072;
  short* xb   = pool;                    // [2560][3072]
  short* wqb  = xb + n_enc + n_hid;      // w_qkv^T    [9216][3072]
  short* waqb = wqb + n_wqkv;            // w_add_qkv^T[9216][3072]
  short* wob  = waqb + n_wqkv;           // w_out^T    [3072][3072]
  short* waob = wob + n_wout;            // w_add_out^T[3072][3072]
  const size_t REQ = 256 + 2 * ((size_t)2560 * 9216 + (size_t)2560 * 3072 +
                                n_hid + n_enc + 2 * n_wqkv + 2 * n_wout);

  detect_dtype<<<1, 256, 0, stream>>>((const unsigned short*)w_qkv, dflag);

  if (ws_size >= REQ) {
    cvt_bf16<<<256, 256, 0, stream>>>(enc, xb, n_enc / 8, dflag);
    cvt_bf16<<<1024, 256, 0, stream>>>(hidden, xb + n_enc, n_hid / 8, dflag);
    cvt_t<<<dim3(144, 48), 256, 0, stream>>>(w_qkv,     wqb,  3072, 9216, dflag);
    cvt_t<<<dim3(144, 48), 256, 0, stream>>>(w_add_qkv, waqb, 3072, 9216, dflag);
    cvt_t<<<dim3(48, 48), 256, 0, stream>>>(w_out,     wob,  3072, 3072, dflag);
    cvt_t<<<dim3(48, 48), 256, 0, stream>>>(w_add_out, waob, 3072, 3072, dflag);

    // merged QKV projection: y<4 -> enc rows w/ w_add_qkv + bias; y>=4 -> hidden
    gemm_bf2<<<dim3(72, 20), 256, 0, stream>>>(
        xb, waqb, b_add_qkv, 0, 0, 4, wqb, nullptr, 512, 512,
        qkv, 9216, 3072, dflag, 0);
    norm_rope<<<dim3(2560), 512, 0, stream>>>(qkv, ids, nqw, nkw, naqw, nakw, dflag);
    attn_fa<<<dim3(480), 512, 0, stream>>>(qkv, attnB);
    // merged out-proj: y<16 -> img (attnB rows 512.., w_out, C rows 0..);
    //                  y>=16 -> enc (attnB rows 0.., w_add_out, C rows 2048..)
    gemm_bf2<<<dim3(24, 20), 256, 0, stream>>>(
        attnB, wob, b_out, 512, 0, 16, waob, b_add_out, 0, 2048,
        d_out, 3072, 3072, dflag, 1);
  } else {
    gemm_bt<<<dim3(72, 4), 256, 0, stream>>>(enc, 0, w_add_qkv, b_add_qkv, qkv, 0, 9216, 3072, dflag, 1, 0);
    gemm_bt<<<dim3(72, 16), 256, 0, stream>>>(hidden, 0, w_qkv, nullptr, qkv, 512, 9216, 3072, dflag, 1, 0);
    norm_rope<<<dim3(2560), 512, 0, stream>>>(qkv, ids, nqw, nkw, naqw, nakw, dflag);
    attn_fa<<<dim3(480), 512, 0, stream>>>(qkv, attnB);
    gemm_bt<<<dim3(24, 16), 256, 0, stream>>>(attnB, 512, w_out, b_out, d_out, 0, 3072, 3072, dflag, 0, 1);
    gemm_bt<<<dim3(24, 4), 256, 0, stream>>>(attnB, 0, w_add_out, b_add_out, d_out, 2048, 3072, 3072, dflag, 0, 1);
  }
}

// Round 12
// 842.403 us; speedup vs baseline: 1.2300x; 1.0409x over previous
//
#include <hip/hip_runtime.h>

typedef __attribute__((ext_vector_type(8))) short short8;
typedef __attribute__((ext_vector_type(4))) short short4v;
typedef __attribute__((ext_vector_type(4))) float floatx4;

__device__ __forceinline__ float b2f(short b) {
  union { unsigned u; float f; } v; v.u = ((unsigned)(unsigned short)b) << 16; return v.f;
}
__device__ __forceinline__ short f2b(float f) {
  union { float f; unsigned u; } v; v.f = f;
  return (short)((v.u + 0x7fffu + ((v.u >> 16) & 1u)) >> 16);
}
// packed f32x2 -> bf16x2 (RNE), single VOP3 instr
__device__ __forceinline__ unsigned cvtpk(float lo, float hi) {
  unsigned r;
  asm("v_cvt_pk_bf16_f32 %0, %1, %2" : "=v"(r) : "v"(lo), "v"(hi));
  return r;
}
__device__ __forceinline__ float loadf(const void* p, size_t i, bool f32) {
  return f32 ? ((const float*)p)[i] : b2f(((const short*)p)[i]);
}
__device__ __forceinline__ short8 load8(const void* p, size_t i, bool f32) {
  if (f32) {
    const float* fp = (const float*)p + i;
    float4 a = *(const float4*)fp;
    float4 b = *(const float4*)(fp + 4);
    short8 r;
    r[0] = f2b(a.x); r[1] = f2b(a.y); r[2] = f2b(a.z); r[3] = f2b(a.w);
    r[4] = f2b(b.x); r[5] = f2b(b.y); r[6] = f2b(b.z); r[7] = f2b(b.w);
    return r;
  }
  return *(const short8*)((const short*)p + i);
}

// async global->LDS, 16B per lane. LDS dest = wave-uniform base + lane*16.
__device__ __forceinline__ void gload16(const short* g, short* l) {
  __builtin_amdgcn_global_load_lds(
      (const __attribute__((address_space(1))) unsigned int*)g,
      (__attribute__((address_space(3))) unsigned int*)l, 16, 0, 0);
}

// ---------- dtype detector
__global__ void detect_dtype(const unsigned short* __restrict__ w, int* __restrict__ flag) {
  __shared__ int cnt;
  if (threadIdx.x == 0) cnt = 0;
  __syncthreads();
  int bad = 0;
  for (int i = threadIdx.x; i < 4096; i += 256) {
    int e = (w[i] >> 7) & 0xFF;
    if (e >= 0xC8) bad++;
  }
  atomicAdd(&cnt, bad);
  __syncthreads();
  if (threadIdx.x == 0) *flag = (cnt > 64) ? 1 : 0;
}

// ---------- one-time dtype normalization: src -> bf16
__global__ __launch_bounds__(256)
void cvt_bf16(const void* __restrict__ src, short* __restrict__ dst, long n8,
              const int* __restrict__ dflag) {
  const bool f32 = (*dflag != 0);
  long stride = (long)gridDim.x * 256;
  for (long i = (long)blockIdx.x * 256 + threadIdx.x; i < n8; i += stride) {
    long e = i * 8;
    if (f32) {
      const float* fp = (const float*)src + e;
      float4 a = *(const float4*)fp;
      float4 b = *(const float4*)(fp + 4);
      short8 r;
      r[0] = f2b(a.x); r[1] = f2b(a.y); r[2] = f2b(a.z); r[3] = f2b(a.w);
      r[4] = f2b(b.x); r[5] = f2b(b.y); r[6] = f2b(b.z); r[7] = f2b(b.w);
      *(short8*)(dst + e) = r;
    } else {
      *(short8*)(dst + e) = *(const short8*)((const short*)src + e);
    }
  }
}

// ---------- cvt_t v2: src [K][N] -> dst [N][K] bf16 (vectorized both sides).
__global__ __launch_bounds__(256)
void cvt_t(const void* __restrict__ src, short* __restrict__ dst,
           int K, int N, const int* __restrict__ dflag) {
  __shared__ short st[64][72];
  const bool f32 = (*dflag != 0);
  const int n0 = blockIdx.x << 6, k0 = blockIdx.y << 6;
  const int c4 = threadIdx.x & 15;
  const int rq = threadIdx.x >> 4;
#pragma unroll
  for (int r = 0; r < 4; ++r) {
    int k = r * 16 + rq;
    int n = c4 * 4;
    short v0, v1, v2, v3;
    if (f32) {
      const float* sp = (const float*)src + (size_t)(k0 + k) * N + n0 + n;
      float4 f = *(const float4*)sp;
      v0 = f2b(f.x); v1 = f2b(f.y); v2 = f2b(f.z); v3 = f2b(f.w);
    } else {
      const short* sp = (const short*)src + (size_t)(k0 + k) * N + n0 + n;
      short4v s = *(const short4v*)sp;
      v0 = s[0]; v1 = s[1]; v2 = s[2]; v3 = s[3];
    }
    st[n + 0][k] = v0; st[n + 1][k] = v1; st[n + 2][k] = v2; st[n + 3][k] = v3;
  }
  __syncthreads();
  const int n = threadIdx.x >> 2;
  const int kc = (threadIdx.x & 3) << 4;
  short8 a = *(const short8*)(&st[n][kc]);
  short8 b = *(const short8*)(&st[n][kc + 8]);
  short* dp = dst + (size_t)(n0 + n) * K + k0 + kc;
  *(short8*)(dp) = a;
  *(short8*)(dp + 8) = b;
}

// ---------- OLD GEMM (fallback) ----------
__global__ __launch_bounds__(256, 2)
void gemm_bt(const void* __restrict__ A, int a_row0,
             const void* __restrict__ B, const void* __restrict__ bias,
             void* __restrict__ C, int c_row0, int N, int K,
             const int* __restrict__ dflag, int aIn, int cOut) {
  __shared__ short As[128 * 32];
  __shared__ short Bs[128 * 32];
  const bool f32 = (*dflag != 0);
  const bool a32 = aIn && f32;
  const bool c32 = cOut && f32;
  const int tid = threadIdx.x;
  const int lane = tid & 63, w = tid >> 6;
  const int wm = w & 1, wn = w >> 1;
  const int qg = lane >> 4, l16 = lane & 15;
  const int m0 = blockIdx.y << 7, n0 = blockIdx.x << 7;

  const int arow = tid >> 2, ak = (tid & 3) << 3;
  const int brow = tid >> 4, bc = (tid & 15) << 3;
  const int rot = tid & 15;

  floatx4 acc[4][4];
#pragma unroll
  for (int i = 0; i < 4; ++i)
#pragma unroll
    for (int j = 0; j < 4; ++j) acc[i][j] = (floatx4){0.f, 0.f, 0.f, 0.f};

  for (int k0 = 0; k0 < K; k0 += 32) {
    __syncthreads();
#pragma unroll
    for (int j = 0; j < 2; ++j) {
      short8 av = load8(A, (size_t)(a_row0 + m0 + j * 64 + arow) * K + (k0 + ak), a32);
      *(short8*)(As + (j * 64 + arow) * 32 + ak) = av;
      int kr = j * 16 + brow;
      short8 bv = load8(B, (size_t)(k0 + kr) * N + (n0 + bc), f32);
      int kq = kr >> 3, kj = kr & 7;
#pragma unroll
      for (int s = 0; s < 8; ++s) {
        int u = (s + rot) & 7;
        int n = bc + u;
        Bs[(n << 5) + ((kq ^ (n & 3)) << 3) + kj] = bv[u];
      }
    }
    __syncthreads();
    short8 a[4];
#pragma unroll
    for (int mi = 0; mi < 4; ++mi)
      a[mi] = *(const short8*)(As + (wm * 64 + mi * 16 + l16) * 32 + qg * 8);
#pragma unroll
    for (int ni = 0; ni < 4; ++ni) {
      int n = wn * 64 + ni * 16 + l16;
      short8 b = *(const short8*)(Bs + (n << 5) + ((qg ^ (n & 3)) << 3));
#pragma unroll
      for (int mi = 0; mi < 4; ++mi)
        acc[mi][ni] = __builtin_amdgcn_mfma_f32_16x16x32_bf16(a[mi], b, acc[mi][ni], 0, 0, 0);
    }
  }
#pragma unroll
  for (int ni = 0; ni < 4; ++ni) {
    int col = n0 + wn * 64 + ni * 16 + l16;
    float bv = bias ? loadf(bias, col, f32) : 0.0f;
#pragma unroll
    for (int mi = 0; mi < 4; ++mi) {
      int row = m0 + wm * 64 + mi * 16 + qg * 4;
#pragma unroll
      for (int r = 0; r < 4; ++r) {
        size_t idx = (size_t)(c_row0 + row + r) * N + col;
        float val = acc[mi][ni][r] + bv;
        if (c32) ((float*)C)[idx] = val;
        else     ((short*)C)[idx] = f2b(val);
      }
    }
  }
}

// ---------- GEMM v7: depth-2 pipelined + per-block param select (merged launches).
__global__ __launch_bounds__(256, 3)
void gemm_bf2(const short* __restrict__ A,
              const short* __restrict__ BTa, const void* __restrict__ biasa,
              int a0a, int c0a, int nYa,
              const short* __restrict__ BTb, const void* __restrict__ biasb,
              int a0b, int c0b,
              void* __restrict__ C, int N, int K,
              const int* __restrict__ dflag, int cOut) {
  __shared__ short As[3][128 * 32];
  __shared__ short Bs[3][128 * 32];
  const bool f32 = (*dflag != 0);
  const bool c32 = cOut && f32;
  const int y = blockIdx.y;
  const short* BT; const void* bias; int arow0, crow0;
  if (y < nYa) { BT = BTa; bias = biasa; arow0 = a0a + (y << 7); crow0 = c0a + (y << 7); }
  else { int my = y - nYa; BT = BTb; bias = biasb; arow0 = a0b + (my << 7); crow0 = c0b + (my << 7); }
  const int tid = threadIdx.x;
  const int lane = tid & 63, w = tid >> 6;
  const int wm = w & 1, wn = w >> 1;
  const int qg = lane >> 4, l16 = lane & 15;
  const int n0 = blockIdx.x << 7;
  const int garow = lane >> 2;
  const int gcir = lane & 3;
  const int nk = K >> 5;
  const int swz = (gcir ^ (garow & 3) ^ (garow >> 2)) << 3;
  const short* Abase = A + (size_t)(arow0 + w * 32 + garow) * K + swz;
  const short* Bbase = BT + (size_t)(n0 + w * 32 + garow) * K + swz;
  const int rswz = (l16 & 3) ^ (l16 >> 2);

  floatx4 acc[4][4];
#pragma unroll
  for (int i = 0; i < 4; ++i)
#pragma unroll
    for (int j = 0; j < 4; ++j) acc[i][j] = (floatx4){0.f, 0.f, 0.f, 0.f};

  auto STAGE = [&](int buf, int k0) {
#pragma unroll
    for (int j = 0; j < 2; ++j) {
      gload16(Abase + (size_t)j * 16 * K + k0, &As[buf][(w * 2 + j) << 9]);
      gload16(Bbase + (size_t)j * 16 * K + k0, &Bs[buf][(w * 2 + j) << 9]);
    }
  };

  STAGE(0, 0);
  if (nk > 1) STAGE(1, 32);

  int cb = 0;
  for (int t = 0; t < nk; ++t) {
    if (t + 2 < nk) {
      int sb = (cb == 0) ? 2 : cb - 1;
      STAGE(sb, (t + 2) << 5);
      asm volatile("s_waitcnt vmcnt(8)" ::: "memory");
    } else if (t + 1 < nk) {
      asm volatile("s_waitcnt vmcnt(4)" ::: "memory");
    } else {
      asm volatile("s_waitcnt vmcnt(0)" ::: "memory");
    }
    __builtin_amdgcn_s_barrier();
    short8 a[4], b[4];
#pragma unroll
    for (int mi = 0; mi < 4; ++mi) {
      int ra = wm * 64 + mi * 16 + l16;
      a[mi] = *(const short8*)(&As[cb][(ra << 5) + ((qg ^ rswz) << 3)]);
    }
#pragma unroll
    for (int ni = 0; ni < 4; ++ni) {
      int n = wn * 64 + ni * 16 + l16;
      b[ni] = *(const short8*)(&Bs[cb][(n << 5) + ((qg ^ rswz) << 3)]);
    }
    __builtin_amdgcn_s_setprio(1);
#pragma unroll
    for (int ni = 0; ni < 4; ++ni)
#pragma unroll
      for (int mi = 0; mi < 4; ++mi)
        acc[mi][ni] = __builtin_amdgcn_mfma_f32_16x16x32_bf16(a[mi], b[ni], acc[mi][ni], 0, 0, 0);
    __builtin_amdgcn_s_setprio(0);
    asm volatile("s_waitcnt lgkmcnt(0)" ::: "memory");
    __builtin_amdgcn_s_barrier();
    cb = (cb == 2) ? 0 : cb + 1;
  }
#pragma unroll
  for (int ni = 0; ni < 4; ++ni) {
    int col = n0 + wn * 64 + ni * 16 + l16;
    float bvv = bias ? loadf(bias, col, f32) : 0.0f;
#pragma unroll
    for (int mi = 0; mi < 4; ++mi) {
      int row = wm * 64 + mi * 16 + qg * 4;
#pragma unroll
      for (int r = 0; r < 4; ++r) {
        size_t idx = (size_t)(crow0 + row + r) * N + col;
        float val = acc[mi][ni][r] + bvv;
        if (c32) ((float*)C)[idx] = val;
        else     ((short*)C)[idx] = f2b(val);
      }
    }
  }
}

// ---------- RMSNorm + RoPE: one wave per head; q scaled by rsqrt(128)*log2(e).
__global__ __launch_bounds__(512)
void norm_rope(short* __restrict__ qkv, const int* __restrict__ ids,
               const void* __restrict__ nqw, const void* __restrict__ nkw,
               const void* __restrict__ naqw, const void* __restrict__ nakw,
               const int* __restrict__ dflag) {
  const bool f32 = (*dflag != 0);
  const int t = blockIdx.x, wv = threadIdx.x >> 6, lane = threadIdx.x & 63;
  const bool txt = t < 512;
  int p = lane, axis; float expo;
  if (p < 8)       { axis = 0; expo = (float)(2 * p) * (1.0f / 16.0f); }
  else if (p < 36) { axis = 1; expo = (float)(2 * (p - 8)) * (1.0f / 56.0f); }
  else             { axis = 2; expo = (float)(2 * (p - 36)) * (1.0f / 56.0f); }
  float freq = __expf(-expo * 9.210340371976184f);
  float ang = (float)ids[t * 3 + axis] * freq;
  float s, c; sincosf(ang, &s, &c);
  const void* qw = txt ? naqw : nqw;
  const void* kw = txt ? nakw : nkw;
  float w0q = loadf(qw, 2 * lane, f32), w1q = loadf(qw, 2 * lane + 1, f32);
  float w0k = loadf(kw, 2 * lane, f32), w1k = loadf(kw, 2 * lane + 1, f32);
  const float QS = 0.08838834764831845f * 1.4426950408889634f;
#pragma unroll
  for (int i = 0; i < 3; ++i) {
    int h = wv + 8 * i;
    short* qp = qkv + (size_t)t * 9216 + h * 128 + 2 * lane;
    short* kp = qp + 3072;
    union { unsigned u; short sh[2]; } qv, kv;
    qv.u = *(const unsigned*)qp;
    kv.u = *(const unsigned*)kp;
    float q0 = b2f(qv.sh[0]), q1 = b2f(qv.sh[1]);
    float k0 = b2f(kv.sh[0]), k1 = b2f(kv.sh[1]);
    float sq = q0 * q0 + q1 * q1, sk = k0 * k0 + k1 * k1;
#pragma unroll
    for (int o = 1; o < 64; o <<= 1) { sq += __shfl_xor(sq, o); sk += __shfl_xor(sk, o); }
    float rq = rsqrtf(sq * (1.0f / 128.0f) + 1e-5f);
    float rk = rsqrtf(sk * (1.0f / 128.0f) + 1e-5f);
    float qn0 = q0 * rq * w0q, qn1 = q1 * rq * w1q;
    float kn0 = k0 * rk * w0k, kn1 = k1 * rk * w1k;
    float qo0 = qn0 * c - qn1 * s, qo1 = qn1 * c + qn0 * s;
    float ko0 = kn0 * c - kn1 * s, ko1 = kn1 * c + kn0 * s;
    union { unsigned u; short sh[2]; } qo, ko;
    qo.sh[0] = f2b(qo0 * QS);
    qo.sh[1] = f2b(qo1 * QS);
    ko.sh[0] = f2b(ko0); ko.sh[1] = f2b(ko1);
    *(unsigned*)qp = qo.u;
    *(unsigned*)kp = ko.u;
  }
}

// ---------- flash attention v7 (REVERTED from v8 — R11 post-mortem: Q128/KB64
// cost +18%/unit-work from 2x softmax frequency + doubled bank conflicts; the
// 1.875-blocks/CU occupancy gain didn't cover it. This is the proven 194-202us
// config: Q-tile 256, KB=128, grid 240, exp2-domain softmax + cvt_pk P-pack,
// packed b64 V^T commit, coalesced epilogue).
__global__ __launch_bounds__(512, 2)
void attn_fa(const short* __restrict__ qkv, short* __restrict__ attn) {
  __shared__ short QPs[256 * 128];      // 64 KB
  __shared__ short KVs[2][128 * 128];   // 2 x 32 KB
  const int wgid = blockIdx.x;
  const int xcd = wgid & 7, slot = wgid >> 3;   // 30 slots/XCD
  const int h = xcd * 3 + slot / 10;            // 3 heads per XCD (L2-resident K/V)
  const int qt = slot % 10;
  const int tid = threadIdx.x, lane = tid & 63, w = tid >> 6;  // 8 waves
  const int qg = lane >> 4, l16 = lane & 15;
  const int lr = lane >> 4, lc = lane & 15;
  const int q0 = qt << 8;
  const int sc = tid & 15;
  const int srow5 = (tid >> 4) & 15, half = tid >> 8;

  const short* Qg  = qkv + (size_t)q0 * 9216 + h * 128;
  const short* Kg0 = qkv + 3072 + h * 128;
  const short* Vg0 = qkv + 6144 + h * 128;

  short8 vr[4];
#pragma unroll
  for (int j = 0; j < 8; ++j) {
    int row = j * 32 + w * 4 + lr;
    gload16(Qg + (size_t)row * 9216 + ((lc ^ (row & 7)) << 3),
            QPs + (j * 32 + w * 4) * 128);
  }
#pragma unroll
  for (int j = 0; j < 4; ++j) {
    int row = j * 32 + w * 4 + lr;
    gload16(Kg0 + (size_t)row * 9216 + ((lc ^ (row & 7)) << 3),
            &KVs[0][(j * 32 + w * 4) * 128]);
  }
#pragma unroll
  for (int j = 0; j < 4; ++j) {
    int row = half * 64 + j * 16 + srow5;
    vr[j] = *(const short8*)(Vg0 + (size_t)row * 9216 + sc * 8);
  }
  asm volatile("s_waitcnt vmcnt(8) lgkmcnt(0)" ::: "memory");
  __builtin_amdgcn_s_barrier();
  short8 aq[2][4];
#pragma unroll
  for (int mi = 0; mi < 2; ++mi)
#pragma unroll
    for (int kc = 0; kc < 4; ++kc) {
      int row = w * 32 + mi * 16 + l16;
      aq[mi][kc] = *(const short8*)(QPs + row * 128 + (((kc * 4 + qg) ^ (row & 7)) << 3));
    }

  floatx4 acc_o[2][8];
#pragma unroll
  for (int mi = 0; mi < 2; ++mi)
#pragma unroll
    for (int nd = 0; nd < 8; ++nd) acc_o[mi][nd] = (floatx4){0.f, 0.f, 0.f, 0.f};
  float m_i[2][4], l_i[2][4];
#pragma unroll
  for (int mi = 0; mi < 2; ++mi)
#pragma unroll
    for (int r = 0; r < 4; ++r) { m_i[mi][r] = -1e30f; l_i[mi][r] = 0.0f; }

  for (int kt = 0; kt < 20; ++kt) {
    const int c = kt & 1;
    asm volatile("s_waitcnt vmcnt(4) lgkmcnt(0)" ::: "memory");
    __builtin_amdgcn_s_barrier();
    if (kt < 19) {
      const short* Kg = qkv + ((size_t)(kt + 1) * 128) * 9216 + 3072 + h * 128;
#pragma unroll
      for (int j = 0; j < 4; ++j) {
        int row = j * 32 + w * 4 + lr;
        gload16(Kg + (size_t)row * 9216 + ((lc ^ (row & 7)) << 3),
                &KVs[1 - c][(j * 32 + w * 4) * 128]);
      }
    }
    // ---- QK^T from KVs[c] (scores already in log2 domain via q-scale)
    floatx4 acc_s[2][8];
#pragma unroll
    for (int mi = 0; mi < 2; ++mi)
#pragma unroll
      for (int ni = 0; ni < 8; ++ni) acc_s[mi][ni] = (floatx4){0.f, 0.f, 0.f, 0.f};
    __builtin_amdgcn_s_setprio(1);
#pragma unroll
    for (int kc = 0; kc < 4; ++kc) {
#pragma unroll
      for (int ni = 0; ni < 8; ++ni) {
        int row = ni * 16 + l16;
        short8 b = *(const short8*)(&KVs[c][row * 128 + (((kc * 4 + qg) ^ (row & 7)) << 3)]);
        acc_s[0][ni] = __builtin_amdgcn_mfma_f32_16x16x32_bf16(aq[0][kc], b, acc_s[0][ni], 0, 0, 0);
        acc_s[1][ni] = __builtin_amdgcn_mfma_f32_16x16x32_bf16(aq[1][kc], b, acc_s[1][ni], 0, 0, 0);
      }
    }
    __builtin_amdgcn_s_setprio(0);
    // ---- online softmax (wave-private rows), exp2 domain
    float alpha[2][4];
#pragma unroll
    for (int mi = 0; mi < 2; ++mi) {
#pragma unroll
      for (int r = 0; r < 4; ++r) {
        float mx = acc_s[mi][0][r];
#pragma unroll
        for (int ni = 1; ni < 8; ++ni) mx = fmaxf(mx, acc_s[mi][ni][r]);
        mx = fmaxf(mx, __shfl_xor(mx, 1));
        mx = fmaxf(mx, __shfl_xor(mx, 2));
        mx = fmaxf(mx, __shfl_xor(mx, 4));
        mx = fmaxf(mx, __shfl_xor(mx, 8));
        float mn = fmaxf(m_i[mi][r], mx);
        alpha[mi][r] = __builtin_amdgcn_exp2f(m_i[mi][r] - mn);
        m_i[mi][r] = mn;
      }
    }
#pragma unroll
    for (int mi = 0; mi < 2; ++mi) {
      float rs[4] = {0.f, 0.f, 0.f, 0.f};
#pragma unroll
      for (int r = 0; r < 4; ++r) {
        float pv[8];
#pragma unroll
        for (int ni = 0; ni < 8; ++ni) {
          pv[ni] = __builtin_amdgcn_exp2f(acc_s[mi][ni][r] - m_i[mi][r]);
          rs[r] += pv[ni];
        }
        unsigned u0 = cvtpk(pv[0], pv[1]);
        unsigned u1 = cvtpk(pv[2], pv[3]);
        unsigned u2 = cvtpk(pv[4], pv[5]);
        unsigned u3 = cvtpk(pv[6], pv[7]);
        int row = w * 32 + mi * 16 + qg * 4 + r;  // wave-private P row
        uint4 uu; uu.x = u0; uu.y = u1; uu.z = u2; uu.w = u3;
        *(uint4*)(QPs + row * 128 + ((l16 ^ (row & 15)) << 3)) = uu;
      }
#pragma unroll
      for (int r = 0; r < 4; ++r) {
        float t = rs[r];
        t += __shfl_xor(t, 1); t += __shfl_xor(t, 2);
        t += __shfl_xor(t, 4); t += __shfl_xor(t, 8);
        l_i[mi][r] = alpha[mi][r] * l_i[mi][r] + t;
      }
#pragma unroll
      for (int nd = 0; nd < 8; ++nd)
#pragma unroll
        for (int r = 0; r < 4; ++r) acc_o[mi][nd][r] *= alpha[mi][r];
    }
    asm volatile("s_waitcnt lgkmcnt(0)" ::: "memory");
    __builtin_amdgcn_s_barrier();
    // ---- commit V^T(kt) into KVs[c]: token r -> col t' = 8*(r&15) + (r>>4).
#pragma unroll
    for (int u = 0; u < 8; ++u) {
      int d = sc * 8 + u;
      short4v pk = { vr[0][u], vr[1][u], vr[2][u], vr[3][u] };
      *(short4v*)(&KVs[c][d * 128 + (((srow5 ^ u ^ (sc & 7))) << 3) + half * 4]) = pk;
    }
    if (kt < 19) {
      const short* Vg = qkv + ((size_t)(kt + 1) * 128) * 9216 + 6144 + h * 128;
#pragma unroll
      for (int j = 0; j < 4; ++j) {
        int row = half * 64 + j * 16 + srow5;
        vr[j] = *(const short8*)(Vg + (size_t)row * 9216 + sc * 8);
      }
    }
    asm volatile("s_waitcnt lgkmcnt(0)" ::: "memory");
    __builtin_amdgcn_s_barrier();
    // ---- PV
    __builtin_amdgcn_s_setprio(1);
#pragma unroll
    for (int kc = 0; kc < 4; ++kc) {
      int prow0 = w * 32 + l16;
      short8 ap0 = *(const short8*)(QPs + prow0 * 128 + (((kc * 4 + qg) ^ (prow0 & 15)) << 3));
      int prow1 = prow0 + 16;
      short8 ap1 = *(const short8*)(QPs + prow1 * 128 + (((kc * 4 + qg) ^ (prow1 & 15)) << 3));
#pragma unroll
      for (int nd = 0; nd < 8; ++nd) {
        int row = nd * 16 + l16;
        int chn = (kc * 4 + qg) ^ (row & 7) ^ ((row >> 3) & 7);
        short8 b = *(const short8*)(&KVs[c][row * 128 + (chn << 3)]);
        acc_o[0][nd] = __builtin_amdgcn_mfma_f32_16x16x32_bf16(ap0, b, acc_o[0][nd], 0, 0, 0);
        acc_o[1][nd] = __builtin_amdgcn_mfma_f32_16x16x32_bf16(ap1, b, acc_o[1][nd], 0, 0, 0);
      }
    }
    __builtin_amdgcn_s_setprio(0);
  }
  // ---- epilogue: normalize, transpose through QPs, coalesced b128 stores
#pragma unroll
  for (int mi = 0; mi < 2; ++mi) {
    float inv[4];
#pragma unroll
    for (int r = 0; r < 4; ++r) inv[r] = 1.0f / l_i[mi][r];
#pragma unroll
    for (int nd = 0; nd < 8; ++nd) {
#pragma unroll
      for (int r = 0; r < 4; ++r) {
        int row = w * 32 + mi * 16 + qg * 4 + r;
        QPs[row * 128 + nd * 16 + l16] = f2b(acc_o[mi][nd][r] * inv[r]);
      }
    }
  }
  asm volatile("s_waitcnt lgkmcnt(0)" ::: "memory");
#pragma unroll
  for (int j = 0; j < 8; ++j) {
    int rrow = w * 32 + j * 4 + qg;   // 4 rows x 16 col-chunks per iteration
    short8 vv = *(const short8*)(QPs + rrow * 128 + l16 * 8);
    *(short8*)(attn + (size_t)(q0 + rrow) * 3072 + h * 128 + l16 * 8) = vv;
  }
}

extern "C" void kernel_launch(void* const* d_in, const int* in_sizes, int n_in,
                              void* d_out, int out_size, void* d_ws, size_t ws_size,
                              hipStream_t stream) {
  (void)in_sizes; (void)n_in; (void)out_size;
  const void* hidden    = d_in[0];
  const void* enc       = d_in[1];
  const int*  ids       = (const int*)d_in[2];
  const void* w_qkv     = d_in[3];
  const void* w_add_qkv = d_in[4];
  const void* b_add_qkv = d_in[5];
  const void* w_out     = d_in[6];
  const void* b_out     = d_in[7];
  const void* w_add_out = d_in[8];
  const void* b_add_out = d_in[9];
  const void* nqw  = d_in[10];
  const void* nkw  = d_in[11];
  const void* naqw = d_in[12];
  const void* nakw = d_in[13];

  int*   dflag = (int*)d_ws;
  short* qkv   = (short*)((char*)d_ws + 256);   // [2560][9216] bf16
  short* attnB = qkv + (size_t)2560 * 9216;     // [2560][3072] bf16

  // bf16 pool: xb = concat(enc rows 0..512, hidden rows 512..2560) + weightsT
  short* pool  = attnB + (size_t)2560 * 3072;
  const long n_hid  = 2048L * 3072;
  const long n_enc  = 512L * 3072;
  const long n_wqkv = 3072L * 9216;
  const long n_wout = 3072L * 3072;
  short* xb   = pool;                    // [2560][3072]
  short* wqb  = xb + n_enc + n_hid;      // w_qkv^T    [9216][3072]
  short* waqb = wqb + n_wqkv;            // w_add_qkv^T[9216][3072]
  short* wob  = waqb + n_wqkv;           // w_out^T    [3072][3072]
  short* waob = wob + n_wout;            // w_add_out^T[3072][3072]
  const size_t REQ = 256 + 2 * ((size_t)2560 * 9216 + (size_t)2560 * 3072 +
                                n_hid + n_enc + 2 * n_wqkv + 2 * n_wout);

  detect_dtype<<<1, 256, 0, stream>>>((const unsigned short*)w_qkv, dflag);

  if (ws_size >= REQ) {
    cvt_bf16<<<256, 256, 0, stream>>>(enc, xb, n_enc / 8, dflag);
    cvt_bf16<<<1024, 256, 0, stream>>>(hidden, xb + n_enc, n_hid / 8, dflag);
    cvt_t<<<dim3(144, 48), 256, 0, stream>>>(w_qkv,     wqb,  3072, 9216, dflag);
    cvt_t<<<dim3(144, 48), 256, 0, stream>>>(w_add_qkv, waqb, 3072, 9216, dflag);
    cvt_t<<<dim3(48, 48), 256, 0, stream>>>(w_out,     wob,  3072, 3072, dflag);
    cvt_t<<<dim3(48, 48), 256, 0, stream>>>(w_add_out, waob, 3072, 3072, dflag);

    // merged QKV projection: y<4 -> enc rows w/ w_add_qkv + bias; y>=4 -> hidden
    gemm_bf2<<<dim3(72, 20), 256, 0, stream>>>(
        xb, waqb, b_add_qkv, 0, 0, 4, wqb, nullptr, 512, 512,
        qkv, 9216, 3072, dflag, 0);
    norm_rope<<<dim3(2560), 512, 0, stream>>>(qkv, ids, nqw, nkw, naqw, nakw, dflag);
    attn_fa<<<dim3(240), 512, 0, stream>>>(qkv, attnB);
    // merged out-proj: y<16 -> img; y>=16 -> enc
    gemm_bf2<<<dim3(24, 20), 256, 0, stream>>>(
        attnB, wob, b_out, 512, 0, 16, waob, b_add_out, 0, 2048,
        d_out, 3072, 3072, dflag, 1);
  } else {
    gemm_bt<<<dim3(72, 4), 256, 0, stream>>>(enc, 0, w_add_qkv, b_add_qkv, qkv, 0, 9216, 3072, dflag, 1, 0);
    gemm_bt<<<dim3(72, 16), 256, 0, stream>>>(hidden, 0, w_qkv, nullptr, qkv, 512, 9216, 3072, dflag, 1, 0);
    norm_rope<<<dim3(2560), 512, 0, stream>>>(qkv, ids, nqw, nkw, naqw, nakw, dflag);
    attn_fa<<<dim3(240), 512, 0, stream>>>(qkv, attnB);
    gemm_bt<<<dim3(24, 16), 256, 0, stream>>>(attnB, 512, w_out, b_out, d_out, 0, 3072, 3072, dflag, 0, 1);
    gemm_bt<<<dim3(24, 4), 256, 0, stream>>>(attnB, 0, w_add_out, b_add_out, d_out, 2048, 3072, 3072, dflag, 0, 1);
  }
}

// Round 13
// 840.609 us; speedup vs baseline: 1.2326x; 1.0021x over previous
//
#include <hip/hip_runtime.h>

typedef __attribute__((ext_vector_type(8))) short short8;
typedef __attribute__((ext_vector_type(4))) short short4v;
typedef __attribute__((ext_vector_type(4))) float floatx4;

__device__ __forceinline__ float b2f(short b) {
  union { unsigned u; float f; } v; v.u = ((unsigned)(unsigned short)b) << 16; return v.f;
}
__device__ __forceinline__ short f2b(float f) {
  union { float f; unsigned u; } v; v.f = f;
  return (short)((v.u + 0x7fffu + ((v.u >> 16) & 1u)) >> 16);
}
// packed f32x2 -> bf16x2 (RNE), single VOP3 instr
__device__ __forceinline__ unsigned cvtpk(float lo, float hi) {
  unsigned r;
  asm("v_cvt_pk_bf16_f32 %0, %1, %2" : "=v"(r) : "v"(lo), "v"(hi));
  return r;
}
__device__ __forceinline__ float loadf(const void* p, size_t i, bool f32) {
  return f32 ? ((const float*)p)[i] : b2f(((const short*)p)[i]);
}
__device__ __forceinline__ short8 load8(const void* p, size_t i, bool f32) {
  if (f32) {
    const float* fp = (const float*)p + i;
    float4 a = *(const float4*)fp;
    float4 b = *(const float4*)(fp + 4);
    short8 r;
    r[0] = f2b(a.x); r[1] = f2b(a.y); r[2] = f2b(a.z); r[3] = f2b(a.w);
    r[4] = f2b(b.x); r[5] = f2b(b.y); r[6] = f2b(b.z); r[7] = f2b(b.w);
    return r;
  }
  return *(const short8*)((const short*)p + i);
}

// async global->LDS, 16B per lane. LDS dest = wave-uniform base + lane*16.
__device__ __forceinline__ void gload16(const short* g, short* l) {
  __builtin_amdgcn_global_load_lds(
      (const __attribute__((address_space(1))) unsigned int*)g,
      (__attribute__((address_space(3))) unsigned int*)l, 16, 0, 0);
}

// ---------- dtype detector
__global__ void detect_dtype(const unsigned short* __restrict__ w, int* __restrict__ flag) {
  __shared__ int cnt;
  if (threadIdx.x == 0) cnt = 0;
  __syncthreads();
  int bad = 0;
  for (int i = threadIdx.x; i < 4096; i += 256) {
    int e = (w[i] >> 7) & 0xFF;
    if (e >= 0xC8) bad++;
  }
  atomicAdd(&cnt, bad);
  __syncthreads();
  if (threadIdx.x == 0) *flag = (cnt > 64) ? 1 : 0;
}

// ---------- one-time dtype normalization: two sources -> one contiguous dst
__global__ __launch_bounds__(256)
void cvt_bf16_2(const void* __restrict__ srcA, long n8A,
                const void* __restrict__ srcB, long n8B,
                short* __restrict__ dst, const int* __restrict__ dflag) {
  const bool f32 = (*dflag != 0);
  const long n8 = n8A + n8B;
  long stride = (long)gridDim.x * 256;
  for (long i = (long)blockIdx.x * 256 + threadIdx.x; i < n8; i += stride) {
    const void* s; long e;
    if (i < n8A) { s = srcA; e = i * 8; } else { s = srcB; e = (i - n8A) * 8; }
    if (f32) {
      const float* fp = (const float*)s + e;
      float4 a = *(const float4*)fp;
      float4 b = *(const float4*)(fp + 4);
      short8 r;
      r[0] = f2b(a.x); r[1] = f2b(a.y); r[2] = f2b(a.z); r[3] = f2b(a.w);
      r[4] = f2b(b.x); r[5] = f2b(b.y); r[6] = f2b(b.z); r[7] = f2b(b.w);
      *(short8*)(dst + i * 8) = r;
    } else {
      *(short8*)(dst + i * 8) = *(const short8*)((const short*)s + e);
    }
  }
}

// ---------- cvt_t v3: [K][N] -> [N][K] bf16, TWO matrices per launch (blockIdx.z).
__global__ __launch_bounds__(256)
void cvt_t2(const void* __restrict__ src0, short* __restrict__ dst0,
            const void* __restrict__ src1, short* __restrict__ dst1,
            int K, int N, const int* __restrict__ dflag) {
  __shared__ short st[64][72];
  const bool f32 = (*dflag != 0);
  const void* src = blockIdx.z ? src1 : src0;
  short* dst = blockIdx.z ? dst1 : dst0;
  const int n0 = blockIdx.x << 6, k0 = blockIdx.y << 6;
  const int c4 = threadIdx.x & 15;
  const int rq = threadIdx.x >> 4;
#pragma unroll
  for (int r = 0; r < 4; ++r) {
    int k = r * 16 + rq;
    int n = c4 * 4;
    short v0, v1, v2, v3;
    if (f32) {
      const float* sp = (const float*)src + (size_t)(k0 + k) * N + n0 + n;
      float4 f = *(const float4*)sp;
      v0 = f2b(f.x); v1 = f2b(f.y); v2 = f2b(f.z); v3 = f2b(f.w);
    } else {
      const short* sp = (const short*)src + (size_t)(k0 + k) * N + n0 + n;
      short4v s = *(const short4v*)sp;
      v0 = s[0]; v1 = s[1]; v2 = s[2]; v3 = s[3];
    }
    st[n + 0][k] = v0; st[n + 1][k] = v1; st[n + 2][k] = v2; st[n + 3][k] = v3;
  }
  __syncthreads();
  const int n = threadIdx.x >> 2;
  const int kc = (threadIdx.x & 3) << 4;
  short8 a = *(const short8*)(&st[n][kc]);
  short8 b = *(const short8*)(&st[n][kc + 8]);
  short* dp = dst + (size_t)(n0 + n) * K + k0 + kc;
  *(short8*)(dp) = a;
  *(short8*)(dp + 8) = b;
}

// ---------- OLD GEMM (fallback) ----------
__global__ __launch_bounds__(256, 2)
void gemm_bt(const void* __restrict__ A, int a_row0,
             const void* __restrict__ B, const void* __restrict__ bias,
             void* __restrict__ C, int c_row0, int N, int K,
             const int* __restrict__ dflag, int aIn, int cOut) {
  __shared__ short As[128 * 32];
  __shared__ short Bs[128 * 32];
  const bool f32 = (*dflag != 0);
  const bool a32 = aIn && f32;
  const bool c32 = cOut && f32;
  const int tid = threadIdx.x;
  const int lane = tid & 63, w = tid >> 6;
  const int wm = w & 1, wn = w >> 1;
  const int qg = lane >> 4, l16 = lane & 15;
  const int m0 = blockIdx.y << 7, n0 = blockIdx.x << 7;

  const int arow = tid >> 2, ak = (tid & 3) << 3;
  const int brow = tid >> 4, bc = (tid & 15) << 3;
  const int rot = tid & 15;

  floatx4 acc[4][4];
#pragma unroll
  for (int i = 0; i < 4; ++i)
#pragma unroll
    for (int j = 0; j < 4; ++j) acc[i][j] = (floatx4){0.f, 0.f, 0.f, 0.f};

  for (int k0 = 0; k0 < K; k0 += 32) {
    __syncthreads();
#pragma unroll
    for (int j = 0; j < 2; ++j) {
      short8 av = load8(A, (size_t)(a_row0 + m0 + j * 64 + arow) * K + (k0 + ak), a32);
      *(short8*)(As + (j * 64 + arow) * 32 + ak) = av;
      int kr = j * 16 + brow;
      short8 bv = load8(B, (size_t)(k0 + kr) * N + (n0 + bc), f32);
      int kq = kr >> 3, kj = kr & 7;
#pragma unroll
      for (int s = 0; s < 8; ++s) {
        int u = (s + rot) & 7;
        int n = bc + u;
        Bs[(n << 5) + ((kq ^ (n & 3)) << 3) + kj] = bv[u];
      }
    }
    __syncthreads();
    short8 a[4];
#pragma unroll
    for (int mi = 0; mi < 4; ++mi)
      a[mi] = *(const short8*)(As + (wm * 64 + mi * 16 + l16) * 32 + qg * 8);
#pragma unroll
    for (int ni = 0; ni < 4; ++ni) {
      int n = wn * 64 + ni * 16 + l16;
      short8 b = *(const short8*)(Bs + (n << 5) + ((qg ^ (n & 3)) << 3));
#pragma unroll
      for (int mi = 0; mi < 4; ++mi)
        acc[mi][ni] = __builtin_amdgcn_mfma_f32_16x16x32_bf16(a[mi], b, acc[mi][ni], 0, 0, 0);
    }
  }
#pragma unroll
  for (int ni = 0; ni < 4; ++ni) {
    int col = n0 + wn * 64 + ni * 16 + l16;
    float bv = bias ? loadf(bias, col, f32) : 0.0f;
#pragma unroll
    for (int mi = 0; mi < 4; ++mi) {
      int row = m0 + wm * 64 + mi * 16 + qg * 4;
#pragma unroll
      for (int r = 0; r < 4; ++r) {
        size_t idx = (size_t)(c_row0 + row + r) * N + col;
        float val = acc[mi][ni][r] + bv;
        if (c32) ((float*)C)[idx] = val;
        else     ((short*)C)[idx] = f2b(val);
      }
    }
  }
}

// ---------- GEMM v8: depth-2 pipelined, SINGLE barrier per K-step.
// Per iter t: wait {vmcnt(4): tile t landed (t+1 stays in flight), lgkmcnt(0):
// my ds_reads of t-1 done} -> barrier (all waves' t-1 reads done + tile t valid)
// -> STAGE(t+2) into buf(t-1) (safe) -> ds_read(t) + MFMA. One barrier/iter
// (was 2) and one joint waitcnt (was separate lgkm & vmcnt waits).
__global__ __launch_bounds__(256, 3)
void gemm_bf2(const short* __restrict__ A,
              const short* __restrict__ BTa, const void* __restrict__ biasa,
              int a0a, int c0a, int nYa,
              const short* __restrict__ BTb, const void* __restrict__ biasb,
              int a0b, int c0b,
              void* __restrict__ C, int N, int K,
              const int* __restrict__ dflag, int cOut) {
  __shared__ short As[3][128 * 32];
  __shared__ short Bs[3][128 * 32];
  const bool f32 = (*dflag != 0);
  const bool c32 = cOut && f32;
  const int y = blockIdx.y;
  const short* BT; const void* bias; int arow0, crow0;
  if (y < nYa) { BT = BTa; bias = biasa; arow0 = a0a + (y << 7); crow0 = c0a + (y << 7); }
  else { int my = y - nYa; BT = BTb; bias = biasb; arow0 = a0b + (my << 7); crow0 = c0b + (my << 7); }
  const int tid = threadIdx.x;
  const int lane = tid & 63, w = tid >> 6;
  const int wm = w & 1, wn = w >> 1;
  const int qg = lane >> 4, l16 = lane & 15;
  const int n0 = blockIdx.x << 7;
  const int garow = lane >> 2;
  const int gcir = lane & 3;
  const int nk = K >> 5;
  const int swz = (gcir ^ (garow & 3) ^ (garow >> 2)) << 3;
  const short* Abase = A + (size_t)(arow0 + w * 32 + garow) * K + swz;
  const short* Bbase = BT + (size_t)(n0 + w * 32 + garow) * K + swz;
  const int rswz = (l16 & 3) ^ (l16 >> 2);

  floatx4 acc[4][4];
#pragma unroll
  for (int i = 0; i < 4; ++i)
#pragma unroll
    for (int j = 0; j < 4; ++j) acc[i][j] = (floatx4){0.f, 0.f, 0.f, 0.f};

  auto STAGE = [&](int buf, int k0) {
#pragma unroll
    for (int j = 0; j < 2; ++j) {
      gload16(Abase + (size_t)j * 16 * K + k0, &As[buf][(w * 2 + j) << 9]);
      gload16(Bbase + (size_t)j * 16 * K + k0, &Bs[buf][(w * 2 + j) << 9]);
    }
  };

  STAGE(0, 0);
  if (nk > 1) STAGE(1, 32);

  int cb = 0;
  for (int t = 0; t < nk; ++t) {
    if (t + 1 < nk) {
      asm volatile("s_waitcnt vmcnt(4) lgkmcnt(0)" ::: "memory");
    } else {
      asm volatile("s_waitcnt vmcnt(0) lgkmcnt(0)" ::: "memory");
    }
    __builtin_amdgcn_s_barrier();
    if (t + 2 < nk) {
      int sb = (cb == 0) ? 2 : cb - 1;   // (t+2)%3 == (t-1)%3
      STAGE(sb, (t + 2) << 5);
    }
    short8 a[4], b[4];
#pragma unroll
    for (int mi = 0; mi < 4; ++mi) {
      int ra = wm * 64 + mi * 16 + l16;
      a[mi] = *(const short8*)(&As[cb][(ra << 5) + ((qg ^ rswz) << 3)]);
    }
#pragma unroll
    for (int ni = 0; ni < 4; ++ni) {
      int n = wn * 64 + ni * 16 + l16;
      b[ni] = *(const short8*)(&Bs[cb][(n << 5) + ((qg ^ rswz) << 3)]);
    }
    __builtin_amdgcn_s_setprio(1);
#pragma unroll
    for (int ni = 0; ni < 4; ++ni)
#pragma unroll
      for (int mi = 0; mi < 4; ++mi)
        acc[mi][ni] = __builtin_amdgcn_mfma_f32_16x16x32_bf16(a[mi], b[ni], acc[mi][ni], 0, 0, 0);
    __builtin_amdgcn_s_setprio(0);
    cb = (cb == 2) ? 0 : cb + 1;
  }
#pragma unroll
  for (int ni = 0; ni < 4; ++ni) {
    int col = n0 + wn * 64 + ni * 16 + l16;
    float bvv = bias ? loadf(bias, col, f32) : 0.0f;
#pragma unroll
    for (int mi = 0; mi < 4; ++mi) {
      int row = wm * 64 + mi * 16 + qg * 4;
#pragma unroll
      for (int r = 0; r < 4; ++r) {
        size_t idx = (size_t)(crow0 + row + r) * N + col;
        float val = acc[mi][ni][r] + bvv;
        if (c32) ((float*)C)[idx] = val;
        else     ((short*)C)[idx] = f2b(val);
      }
    }
  }
}

// ---------- RMSNorm + RoPE: one wave per head; q scaled by rsqrt(128)*log2(e).
__global__ __launch_bounds__(512)
void norm_rope(short* __restrict__ qkv, const int* __restrict__ ids,
               const void* __restrict__ nqw, const void* __restrict__ nkw,
               const void* __restrict__ naqw, const void* __restrict__ nakw,
               const int* __restrict__ dflag) {
  const bool f32 = (*dflag != 0);
  const int t = blockIdx.x, wv = threadIdx.x >> 6, lane = threadIdx.x & 63;
  const bool txt = t < 512;
  int p = lane, axis; float expo;
  if (p < 8)       { axis = 0; expo = (float)(2 * p) * (1.0f / 16.0f); }
  else if (p < 36) { axis = 1; expo = (float)(2 * (p - 8)) * (1.0f / 56.0f); }
  else             { axis = 2; expo = (float)(2 * (p - 36)) * (1.0f / 56.0f); }
  float freq = __expf(-expo * 9.210340371976184f);
  float ang = (float)ids[t * 3 + axis] * freq;
  float s, c; sincosf(ang, &s, &c);
  const void* qw = txt ? naqw : nqw;
  const void* kw = txt ? nakw : nkw;
  float w0q = loadf(qw, 2 * lane, f32), w1q = loadf(qw, 2 * lane + 1, f32);
  float w0k = loadf(kw, 2 * lane, f32), w1k = loadf(kw, 2 * lane + 1, f32);
  const float QS = 0.08838834764831845f * 1.4426950408889634f;
#pragma unroll
  for (int i = 0; i < 3; ++i) {
    int h = wv + 8 * i;
    short* qp = qkv + (size_t)t * 9216 + h * 128 + 2 * lane;
    short* kp = qp + 3072;
    union { unsigned u; short sh[2]; } qv, kv;
    qv.u = *(const unsigned*)qp;
    kv.u = *(const unsigned*)kp;
    float q0 = b2f(qv.sh[0]), q1 = b2f(qv.sh[1]);
    float k0 = b2f(kv.sh[0]), k1 = b2f(kv.sh[1]);
    float sq = q0 * q0 + q1 * q1, sk = k0 * k0 + k1 * k1;
#pragma unroll
    for (int o = 1; o < 64; o <<= 1) { sq += __shfl_xor(sq, o); sk += __shfl_xor(sk, o); }
    float rq = rsqrtf(sq * (1.0f / 128.0f) + 1e-5f);
    float rk = rsqrtf(sk * (1.0f / 128.0f) + 1e-5f);
    float qn0 = q0 * rq * w0q, qn1 = q1 * rq * w1q;
    float kn0 = k0 * rk * w0k, kn1 = k1 * rk * w1k;
    float qo0 = qn0 * c - qn1 * s, qo1 = qn1 * c + qn0 * s;
    float ko0 = kn0 * c - kn1 * s, ko1 = kn1 * c + kn0 * s;
    union { unsigned u; short sh[2]; } qo, ko;
    qo.sh[0] = f2b(qo0 * QS);
    qo.sh[1] = f2b(qo1 * QS);
    ko.sh[0] = f2b(ko0); ko.sh[1] = f2b(ko1);
    *(unsigned*)qp = qo.u;
    *(unsigned*)kp = ko.u;
  }
}

// ---------- flash attention v9 = v7 + T13 defer-rescale.
// Wave-uniform __ballot skip of the alpha-rescale when no row's tile-max
// exceeds m_old + 8 (exp2 domain => P bounded by 2^8; f32 accum safe; first
// tile forces rescale, alpha = exp2(-1e30) = 0).
__global__ __launch_bounds__(512, 2)
void attn_fa(const short* __restrict__ qkv, short* __restrict__ attn) {
  __shared__ short QPs[256 * 128];      // 64 KB
  __shared__ short KVs[2][128 * 128];   // 2 x 32 KB
  const int wgid = blockIdx.x;
  const int xcd = wgid & 7, slot = wgid >> 3;   // 30 slots/XCD
  const int h = xcd * 3 + slot / 10;            // 3 heads per XCD (L2-resident K/V)
  const int qt = slot % 10;
  const int tid = threadIdx.x, lane = tid & 63, w = tid >> 6;  // 8 waves
  const int qg = lane >> 4, l16 = lane & 15;
  const int lr = lane >> 4, lc = lane & 15;
  const int q0 = qt << 8;
  const int sc = tid & 15;
  const int srow5 = (tid >> 4) & 15, half = tid >> 8;

  const short* Qg  = qkv + (size_t)q0 * 9216 + h * 128;
  const short* Kg0 = qkv + 3072 + h * 128;
  const short* Vg0 = qkv + 6144 + h * 128;

  short8 vr[4];
#pragma unroll
  for (int j = 0; j < 8; ++j) {
    int row = j * 32 + w * 4 + lr;
    gload16(Qg + (size_t)row * 9216 + ((lc ^ (row & 7)) << 3),
            QPs + (j * 32 + w * 4) * 128);
  }
#pragma unroll
  for (int j = 0; j < 4; ++j) {
    int row = j * 32 + w * 4 + lr;
    gload16(Kg0 + (size_t)row * 9216 + ((lc ^ (row & 7)) << 3),
            &KVs[0][(j * 32 + w * 4) * 128]);
  }
#pragma unroll
  for (int j = 0; j < 4; ++j) {
    int row = half * 64 + j * 16 + srow5;
    vr[j] = *(const short8*)(Vg0 + (size_t)row * 9216 + sc * 8);
  }
  asm volatile("s_waitcnt vmcnt(8) lgkmcnt(0)" ::: "memory");
  __builtin_amdgcn_s_barrier();
  short8 aq[2][4];
#pragma unroll
  for (int mi = 0; mi < 2; ++mi)
#pragma unroll
    for (int kc = 0; kc < 4; ++kc) {
      int row = w * 32 + mi * 16 + l16;
      aq[mi][kc] = *(const short8*)(QPs + row * 128 + (((kc * 4 + qg) ^ (row & 7)) << 3));
    }

  floatx4 acc_o[2][8];
#pragma unroll
  for (int mi = 0; mi < 2; ++mi)
#pragma unroll
    for (int nd = 0; nd < 8; ++nd) acc_o[mi][nd] = (floatx4){0.f, 0.f, 0.f, 0.f};
  float m_i[2][4], l_i[2][4];
#pragma unroll
  for (int mi = 0; mi < 2; ++mi)
#pragma unroll
    for (int r = 0; r < 4; ++r) { m_i[mi][r] = -1e30f; l_i[mi][r] = 0.0f; }

  for (int kt = 0; kt < 20; ++kt) {
    const int c = kt & 1;
    asm volatile("s_waitcnt vmcnt(4) lgkmcnt(0)" ::: "memory");
    __builtin_amdgcn_s_barrier();
    if (kt < 19) {
      const short* Kg = qkv + ((size_t)(kt + 1) * 128) * 9216 + 3072 + h * 128;
#pragma unroll
      for (int j = 0; j < 4; ++j) {
        int row = j * 32 + w * 4 + lr;
        gload16(Kg + (size_t)row * 9216 + ((lc ^ (row & 7)) << 3),
                &KVs[1 - c][(j * 32 + w * 4) * 128]);
      }
    }
    // ---- QK^T from KVs[c] (scores already in log2 domain via q-scale)
    floatx4 acc_s[2][8];
#pragma unroll
    for (int mi = 0; mi < 2; ++mi)
#pragma unroll
      for (int ni = 0; ni < 8; ++ni) acc_s[mi][ni] = (floatx4){0.f, 0.f, 0.f, 0.f};
    __builtin_amdgcn_s_setprio(1);
#pragma unroll
    for (int kc = 0; kc < 4; ++kc) {
#pragma unroll
      for (int ni = 0; ni < 8; ++ni) {
        int row = ni * 16 + l16;
        short8 b = *(const short8*)(&KVs[c][row * 128 + (((kc * 4 + qg) ^ (row & 7)) << 3)]);
        acc_s[0][ni] = __builtin_amdgcn_mfma_f32_16x16x32_bf16(aq[0][kc], b, acc_s[0][ni], 0, 0, 0);
        acc_s[1][ni] = __builtin_amdgcn_mfma_f32_16x16x32_bf16(aq[1][kc], b, acc_s[1][ni], 0, 0, 0);
      }
    }
    __builtin_amdgcn_s_setprio(0);
    // ---- online softmax, exp2 domain, defer-rescale (T13)
    float mxv[2][4];
    bool need = false;
#pragma unroll
    for (int mi = 0; mi < 2; ++mi) {
#pragma unroll
      for (int r = 0; r < 4; ++r) {
        float mx = acc_s[mi][0][r];
#pragma unroll
        for (int ni = 1; ni < 8; ++ni) mx = fmaxf(mx, acc_s[mi][ni][r]);
        mx = fmaxf(mx, __shfl_xor(mx, 1));
        mx = fmaxf(mx, __shfl_xor(mx, 2));
        mx = fmaxf(mx, __shfl_xor(mx, 4));
        mx = fmaxf(mx, __shfl_xor(mx, 8));
        mxv[mi][r] = mx;
        need = need || (mx > m_i[mi][r] + 8.0f);
      }
    }
    if (__ballot(need)) {   // wave-uniform: rescale all rows with fresh max
#pragma unroll
      for (int mi = 0; mi < 2; ++mi) {
#pragma unroll
        for (int r = 0; r < 4; ++r) {
          float mn = fmaxf(m_i[mi][r], mxv[mi][r]);
          float al = __builtin_amdgcn_exp2f(m_i[mi][r] - mn);
          m_i[mi][r] = mn;
          l_i[mi][r] *= al;
#pragma unroll
          for (int nd = 0; nd < 8; ++nd) acc_o[mi][nd][r] *= al;
        }
      }
    }
#pragma unroll
    for (int mi = 0; mi < 2; ++mi) {
      float rs[4] = {0.f, 0.f, 0.f, 0.f};
#pragma unroll
      for (int r = 0; r < 4; ++r) {
        float pv[8];
#pragma unroll
        for (int ni = 0; ni < 8; ++ni) {
          pv[ni] = __builtin_amdgcn_exp2f(acc_s[mi][ni][r] - m_i[mi][r]);
          rs[r] += pv[ni];
        }
        unsigned u0 = cvtpk(pv[0], pv[1]);
        unsigned u1 = cvtpk(pv[2], pv[3]);
        unsigned u2 = cvtpk(pv[4], pv[5]);
        unsigned u3 = cvtpk(pv[6], pv[7]);
        int row = w * 32 + mi * 16 + qg * 4 + r;  // wave-private P row
        uint4 uu; uu.x = u0; uu.y = u1; uu.z = u2; uu.w = u3;
        *(uint4*)(QPs + row * 128 + ((l16 ^ (row & 15)) << 3)) = uu;
      }
#pragma unroll
      for (int r = 0; r < 4; ++r) {
        float t = rs[r];
        t += __shfl_xor(t, 1); t += __shfl_xor(t, 2);
        t += __shfl_xor(t, 4); t += __shfl_xor(t, 8);
        l_i[mi][r] += t;   // alpha already applied in the rescale branch
      }
    }
    asm volatile("s_waitcnt lgkmcnt(0)" ::: "memory");
    __builtin_amdgcn_s_barrier();
    // ---- commit V^T(kt) into KVs[c]: token r -> col t' = 8*(r&15) + (r>>4).
#pragma unroll
    for (int u = 0; u < 8; ++u) {
      int d = sc * 8 + u;
      short4v pk = { vr[0][u], vr[1][u], vr[2][u], vr[3][u] };
      *(short4v*)(&KVs[c][d * 128 + (((srow5 ^ u ^ (sc & 7))) << 3) + half * 4]) = pk;
    }
    if (kt < 19) {
      const short* Vg = qkv + ((size_t)(kt + 1) * 128) * 9216 + 6144 + h * 128;
#pragma unroll
      for (int j = 0; j < 4; ++j) {
        int row = half * 64 + j * 16 + srow5;
        vr[j] = *(const short8*)(Vg + (size_t)row * 9216 + sc * 8);
      }
    }
    asm volatile("s_waitcnt lgkmcnt(0)" ::: "memory");
    __builtin_amdgcn_s_barrier();
    // ---- PV
    __builtin_amdgcn_s_setprio(1);
#pragma unroll
    for (int kc = 0; kc < 4; ++kc) {
      int prow0 = w * 32 + l16;
      short8 ap0 = *(const short8*)(QPs + prow0 * 128 + (((kc * 4 + qg) ^ (prow0 & 15)) << 3));
      int prow1 = prow0 + 16;
      short8 ap1 = *(const short8*)(QPs + prow1 * 128 + (((kc * 4 + qg) ^ (prow1 & 15)) << 3));
#pragma unroll
      for (int nd = 0; nd < 8; ++nd) {
        int row = nd * 16 + l16;
        int chn = (kc * 4 + qg) ^ (row & 7) ^ ((row >> 3) & 7);
        short8 b = *(const short8*)(&KVs[c][row * 128 + (chn << 3)]);
        acc_o[0][nd] = __builtin_amdgcn_mfma_f32_16x16x32_bf16(ap0, b, acc_o[0][nd], 0, 0, 0);
        acc_o[1][nd] = __builtin_amdgcn_mfma_f32_16x16x32_bf16(ap1, b, acc_o[1][nd], 0, 0, 0);
      }
    }
    __builtin_amdgcn_s_setprio(0);
  }
  // ---- epilogue: normalize, transpose through QPs, coalesced b128 stores
#pragma unroll
  for (int mi = 0; mi < 2; ++mi) {
    float inv[4];
#pragma unroll
    for (int r = 0; r < 4; ++r) inv[r] = 1.0f / l_i[mi][r];
#pragma unroll
    for (int nd = 0; nd < 8; ++nd) {
#pragma unroll
      for (int r = 0; r < 4; ++r) {
        int row = w * 32 + mi * 16 + qg * 4 + r;
        QPs[row * 128 + nd * 16 + l16] = f2b(acc_o[mi][nd][r] * inv[r]);
      }
    }
  }
  asm volatile("s_waitcnt lgkmcnt(0)" ::: "memory");
#pragma unroll
  for (int j = 0; j < 8; ++j) {
    int rrow = w * 32 + j * 4 + qg;   // 4 rows x 16 col-chunks per iteration
    short8 vv = *(const short8*)(QPs + rrow * 128 + l16 * 8);
    *(short8*)(attn + (size_t)(q0 + rrow) * 3072 + h * 128 + l16 * 8) = vv;
  }
}

extern "C" void kernel_launch(void* const* d_in, const int* in_sizes, int n_in,
                              void* d_out, int out_size, void* d_ws, size_t ws_size,
                              hipStream_t stream) {
  (void)in_sizes; (void)n_in; (void)out_size;
  const void* hidden    = d_in[0];
  const void* enc       = d_in[1];
  const int*  ids       = (const int*)d_in[2];
  const void* w_qkv     = d_in[3];
  const void* w_add_qkv = d_in[4];
  const void* b_add_qkv = d_in[5];
  const void* w_out     = d_in[6];
  const void* b_out     = d_in[7];
  const void* w_add_out = d_in[8];
  const void* b_add_out = d_in[9];
  const void* nqw  = d_in[10];
  const void* nkw  = d_in[11];
  const void* naqw = d_in[12];
  const void* nakw = d_in[13];

  int*   dflag = (int*)d_ws;
  short* qkv   = (short*)((char*)d_ws + 256);   // [2560][9216] bf16
  short* attnB = qkv + (size_t)2560 * 9216;     // [2560][3072] bf16

  // bf16 pool: xb = concat(enc rows 0..512, hidden rows 512..2560) + weightsT
  short* pool  = attnB + (size_t)2560 * 3072;
  const long n_hid  = 2048L * 3072;
  const long n_enc  = 512L * 3072;
  const long n_wqkv = 3072L * 9216;
  const long n_wout = 3072L * 3072;
  short* xb   = pool;                    // [2560][3072]
  short* wqb  = xb + n_enc + n_hid;      // w_qkv^T    [9216][3072]
  short* waqb = wqb + n_wqkv;            // w_add_qkv^T[9216][3072]
  short* wob  = waqb + n_wqkv;           // w_out^T    [3072][3072]
  short* waob = wob + n_wout;            // w_add_out^T[3072][3072]
  const size_t REQ = 256 + 2 * ((size_t)2560 * 9216 + (size_t)2560 * 3072 +
                                n_hid + n_enc + 2 * n_wqkv + 2 * n_wout);

  detect_dtype<<<1, 256, 0, stream>>>((const unsigned short*)w_qkv, dflag);

  if (ws_size >= REQ) {
    cvt_bf16_2<<<1024, 256, 0, stream>>>(enc, n_enc / 8, hidden, n_hid / 8, xb, dflag);
    cvt_t2<<<dim3(144, 48, 2), 256, 0, stream>>>(w_qkv, wqb, w_add_qkv, waqb, 3072, 9216, dflag);
    cvt_t2<<<dim3(48, 48, 2), 256, 0, stream>>>(w_out, wob, w_add_out, waob, 3072, 3072, dflag);

    // merged QKV projection: y<4 -> enc rows w/ w_add_qkv + bias; y>=4 -> hidden
    gemm_bf2<<<dim3(72, 20), 256, 0, stream>>>(
        xb, waqb, b_add_qkv, 0, 0, 4, wqb, nullptr, 512, 512,
        qkv, 9216, 3072, dflag, 0);
    norm_rope<<<dim3(2560), 512, 0, stream>>>(qkv, ids, nqw, nkw, naqw, nakw, dflag);
    attn_fa<<<dim3(240), 512, 0, stream>>>(qkv, attnB);
    // merged out-proj: y<16 -> img; y>=16 -> enc
    gemm_bf2<<<dim3(24, 20), 256, 0, stream>>>(
        attnB, wob, b_out, 512, 0, 16, waob, b_add_out, 0, 2048,
        d_out, 3072, 3072, dflag, 1);
  } else {
    gemm_bt<<<dim3(72, 4), 256, 0, stream>>>(enc, 0, w_add_qkv, b_add_qkv, qkv, 0, 9216, 3072, dflag, 1, 0);
    gemm_bt<<<dim3(72, 16), 256, 0, stream>>>(hidden, 0, w_qkv, nullptr, qkv, 512, 9216, 3072, dflag, 1, 0);
    norm_rope<<<dim3(2560), 512, 0, stream>>>(qkv, ids, nqw, nkw, naqw, nakw, dflag);
    attn_fa<<<dim3(240), 512, 0, stream>>>(qkv, attnB);
    gemm_bt<<<dim3(24, 16), 256, 0, stream>>>(attnB, 512, w_out, b_out, d_out, 0, 3072, 3072, dflag, 0, 1);
    gemm_bt<<<dim3(24, 4), 256, 0, stream>>>(attnB, 0, w_add_out, b_add_out, d_out, 2048, 3072, 3072, dflag, 0, 1);
  }
}

// Round 14
// 823.406 us; speedup vs baseline: 1.2583x; 1.0209x over previous
//
#include <hip/hip_runtime.h>

typedef __attribute__((ext_vector_type(8))) short short8;
typedef __attribute__((ext_vector_type(4))) short short4v;
typedef __attribute__((ext_vector_type(4))) float floatx4;

__device__ __forceinline__ float b2f(short b) {
  union { unsigned u; float f; } v; v.u = ((unsigned)(unsigned short)b) << 16; return v.f;
}
__device__ __forceinline__ short f2b(float f) {
  union { float f; unsigned u; } v; v.f = f;
  return (short)((v.u + 0x7fffu + ((v.u >> 16) & 1u)) >> 16);
}
// packed f32x2 -> bf16x2 (RNE), single VOP3 instr
__device__ __forceinline__ unsigned cvtpk(float lo, float hi) {
  unsigned r;
  asm("v_cvt_pk_bf16_f32 %0, %1, %2" : "=v"(r) : "v"(lo), "v"(hi));
  return r;
}
__device__ __forceinline__ float loadf(const void* p, size_t i, bool f32) {
  return f32 ? ((const float*)p)[i] : b2f(((const short*)p)[i]);
}
__device__ __forceinline__ short8 load8(const void* p, size_t i, bool f32) {
  if (f32) {
    const float* fp = (const float*)p + i;
    float4 a = *(const float4*)fp;
    float4 b = *(const float4*)(fp + 4);
    short8 r;
    r[0] = f2b(a.x); r[1] = f2b(a.y); r[2] = f2b(a.z); r[3] = f2b(a.w);
    r[4] = f2b(b.x); r[5] = f2b(b.y); r[6] = f2b(b.z); r[7] = f2b(b.w);
    return r;
  }
  return *(const short8*)((const short*)p + i);
}

// async global->LDS, 16B per lane. LDS dest = wave-uniform base + lane*16.
__device__ __forceinline__ void gload16(const short* g, short* l) {
  __builtin_amdgcn_global_load_lds(
      (const __attribute__((address_space(1))) unsigned int*)g,
      (__attribute__((address_space(3))) unsigned int*)l, 16, 0, 0);
}

// ---------- dtype detector
__global__ void detect_dtype(const unsigned short* __restrict__ w, int* __restrict__ flag) {
  __shared__ int cnt;
  if (threadIdx.x == 0) cnt = 0;
  __syncthreads();
  int bad = 0;
  for (int i = threadIdx.x; i < 4096; i += 256) {
    int e = (w[i] >> 7) & 0xFF;
    if (e >= 0xC8) bad++;
  }
  atomicAdd(&cnt, bad);
  __syncthreads();
  if (threadIdx.x == 0) *flag = (cnt > 64) ? 1 : 0;
}

// ---------- one-time dtype normalization: two sources -> one contiguous dst
__global__ __launch_bounds__(256)
void cvt_bf16_2(const void* __restrict__ srcA, long n8A,
                const void* __restrict__ srcB, long n8B,
                short* __restrict__ dst, const int* __restrict__ dflag) {
  const bool f32 = (*dflag != 0);
  const long n8 = n8A + n8B;
  long stride = (long)gridDim.x * 256;
  for (long i = (long)blockIdx.x * 256 + threadIdx.x; i < n8; i += stride) {
    const void* s; long e;
    if (i < n8A) { s = srcA; e = i * 8; } else { s = srcB; e = (i - n8A) * 8; }
    if (f32) {
      const float* fp = (const float*)s + e;
      float4 a = *(const float4*)fp;
      float4 b = *(const float4*)(fp + 4);
      short8 r;
      r[0] = f2b(a.x); r[1] = f2b(a.y); r[2] = f2b(a.z); r[3] = f2b(a.w);
      r[4] = f2b(b.x); r[5] = f2b(b.y); r[6] = f2b(b.z); r[7] = f2b(b.w);
      *(short8*)(dst + i * 8) = r;
    } else {
      *(short8*)(dst + i * 8) = *(const short8*)((const short*)s + e);
    }
  }
}

// ---------- cvt_tw: all 4 weight transposes in ONE launch (1-D grid decode).
// tiles: w_qkv/w_add_qkv: 144x48 each (N=9216); w_out/w_add_out: 48x48 (N=3072).
__global__ __launch_bounds__(256)
void cvt_tw(const void* __restrict__ wq, short* __restrict__ wqd,
            const void* __restrict__ waq, short* __restrict__ waqd,
            const void* __restrict__ wo, short* __restrict__ wod,
            const void* __restrict__ wao, short* __restrict__ waod,
            const int* __restrict__ dflag) {
  __shared__ short st[64][72];
  const bool f32 = (*dflag != 0);
  const int K = 3072;
  int b = blockIdx.x;
  const void* src; short* dst; int N, n0, k0;
  if (b < 13824) {               // two big matrices: 2 x (144 x 48)
    src = (b < 6912) ? wq : waq;
    dst = (b < 6912) ? wqd : waqd;
    int rem = b % 6912;
    N = 9216; n0 = (rem % 144) << 6; k0 = (rem / 144) << 6;
  } else {                       // two small: 2 x (48 x 48)
    b -= 13824;
    src = (b < 2304) ? wo : wao;
    dst = (b < 2304) ? wod : waod;
    int rem = b % 2304;
    N = 3072; n0 = (rem % 48) << 6; k0 = (rem / 48) << 6;
  }
  const int c4 = threadIdx.x & 15;
  const int rq = threadIdx.x >> 4;
#pragma unroll
  for (int r = 0; r < 4; ++r) {
    int k = r * 16 + rq;
    int n = c4 * 4;
    short v0, v1, v2, v3;
    if (f32) {
      const float* sp = (const float*)src + (size_t)(k0 + k) * N + n0 + n;
      float4 f = *(const float4*)sp;
      v0 = f2b(f.x); v1 = f2b(f.y); v2 = f2b(f.z); v3 = f2b(f.w);
    } else {
      const short* sp = (const short*)src + (size_t)(k0 + k) * N + n0 + n;
      short4v s = *(const short4v*)sp;
      v0 = s[0]; v1 = s[1]; v2 = s[2]; v3 = s[3];
    }
    st[n + 0][k] = v0; st[n + 1][k] = v1; st[n + 2][k] = v2; st[n + 3][k] = v3;
  }
  __syncthreads();
  const int n = threadIdx.x >> 2;
  const int kc = (threadIdx.x & 3) << 4;
  short8 a = *(const short8*)(&st[n][kc]);
  short8 bb = *(const short8*)(&st[n][kc + 8]);
  short* dp = dst + (size_t)(n0 + n) * K + k0 + kc;
  *(short8*)(dp) = a;
  *(short8*)(dp + 8) = bb;
}

// ---------- OLD GEMM (fallback) ----------
__global__ __launch_bounds__(256, 2)
void gemm_bt(const void* __restrict__ A, int a_row0,
             const void* __restrict__ B, const void* __restrict__ bias,
             void* __restrict__ C, int c_row0, int N, int K,
             const int* __restrict__ dflag, int aIn, int cOut) {
  __shared__ short As[128 * 32];
  __shared__ short Bs[128 * 32];
  const bool f32 = (*dflag != 0);
  const bool a32 = aIn && f32;
  const bool c32 = cOut && f32;
  const int tid = threadIdx.x;
  const int lane = tid & 63, w = tid >> 6;
  const int wm = w & 1, wn = w >> 1;
  const int qg = lane >> 4, l16 = lane & 15;
  const int m0 = blockIdx.y << 7, n0 = blockIdx.x << 7;

  const int arow = tid >> 2, ak = (tid & 3) << 3;
  const int brow = tid >> 4, bc = (tid & 15) << 3;
  const int rot = tid & 15;

  floatx4 acc[4][4];
#pragma unroll
  for (int i = 0; i < 4; ++i)
#pragma unroll
    for (int j = 0; j < 4; ++j) acc[i][j] = (floatx4){0.f, 0.f, 0.f, 0.f};

  for (int k0 = 0; k0 < K; k0 += 32) {
    __syncthreads();
#pragma unroll
    for (int j = 0; j < 2; ++j) {
      short8 av = load8(A, (size_t)(a_row0 + m0 + j * 64 + arow) * K + (k0 + ak), a32);
      *(short8*)(As + (j * 64 + arow) * 32 + ak) = av;
      int kr = j * 16 + brow;
      short8 bv = load8(B, (size_t)(k0 + kr) * N + (n0 + bc), f32);
      int kq = kr >> 3, kj = kr & 7;
#pragma unroll
      for (int s = 0; s < 8; ++s) {
        int u = (s + rot) & 7;
        int n = bc + u;
        Bs[(n << 5) + ((kq ^ (n & 3)) << 3) + kj] = bv[u];
      }
    }
    __syncthreads();
    short8 a[4];
#pragma unroll
    for (int mi = 0; mi < 4; ++mi)
      a[mi] = *(const short8*)(As + (wm * 64 + mi * 16 + l16) * 32 + qg * 8);
#pragma unroll
    for (int ni = 0; ni < 4; ++ni) {
      int n = wn * 64 + ni * 16 + l16;
      short8 b = *(const short8*)(Bs + (n << 5) + ((qg ^ (n & 3)) << 3));
#pragma unroll
      for (int mi = 0; mi < 4; ++mi)
        acc[mi][ni] = __builtin_amdgcn_mfma_f32_16x16x32_bf16(a[mi], b, acc[mi][ni], 0, 0, 0);
    }
  }
#pragma unroll
  for (int ni = 0; ni < 4; ++ni) {
    int col = n0 + wn * 64 + ni * 16 + l16;
    float bv = bias ? loadf(bias, col, f32) : 0.0f;
#pragma unroll
    for (int mi = 0; mi < 4; ++mi) {
      int row = m0 + wm * 64 + mi * 16 + qg * 4;
#pragma unroll
      for (int r = 0; r < 4; ++r) {
        size_t idx = (size_t)(c_row0 + row + r) * N + col;
        float val = acc[mi][ni][r] + bv;
        if (c32) ((float*)C)[idx] = val;
        else     ((short*)C)[idx] = f2b(val);
      }
    }
  }
}

// ---------- GEMM v9: depth-2 pipelined, single barrier per K-step (R13),
// + T1 XCD-chunked block swizzle (contiguous flat range per XCD -> A panels
// L2-resident; shortens the latency chain in this latency-bound regime),
// + coalesced LDS-transposed epilogue (kills the 2B/4B scattered-store RMW:
// R13 counters: WRITE 61MB vs 45 ideal on bf16 C; fp32 C was 4B-per-line).
__global__ __launch_bounds__(256, 3)
void gemm_bf2(const short* __restrict__ A,
              const short* __restrict__ BTa, const void* __restrict__ biasa,
              int a0a, int c0a, int nYa,
              const short* __restrict__ BTb, const void* __restrict__ biasb,
              int a0b, int c0b,
              void* __restrict__ C, int N, int K,
              const int* __restrict__ dflag, int cOut) {
  __shared__ short Ls[6 * 128 * 32];           // 48 KB: 3 A bufs + 3 B bufs
#define ASB(b) (Ls + (b) * 4096)
#define BSB(b) (Ls + (3 + (b)) * 4096)
  const bool f32 = (*dflag != 0);
  const bool c32 = cOut && f32;
  // XCD-chunked swizzle (nwg % 8 == 0 for both launch shapes: 1440, 480)
  const int flat0 = blockIdx.y * gridDim.x + blockIdx.x;
  const int nwg = gridDim.x * gridDim.y;
  const int flat = (flat0 & 7) * (nwg >> 3) + (flat0 >> 3);
  const int bx = flat % gridDim.x;
  const int y = flat / gridDim.x;
  const short* BT; const void* bias; int arow0, crow0;
  if (y < nYa) { BT = BTa; bias = biasa; arow0 = a0a + (y << 7); crow0 = c0a + (y << 7); }
  else { int my = y - nYa; BT = BTb; bias = biasb; arow0 = a0b + (my << 7); crow0 = c0b + (my << 7); }
  const int tid = threadIdx.x;
  const int lane = tid & 63, w = tid >> 6;
  const int wm = w & 1, wn = w >> 1;
  const int qg = lane >> 4, l16 = lane & 15;
  const int n0 = bx << 7;
  const int garow = lane >> 2;
  const int gcir = lane & 3;
  const int nk = K >> 5;
  const int swz = (gcir ^ (garow & 3) ^ (garow >> 2)) << 3;
  const short* Abase = A + (size_t)(arow0 + w * 32 + garow) * K + swz;
  const short* Bbase = BT + (size_t)(n0 + w * 32 + garow) * K + swz;
  const int rswz = (l16 & 3) ^ (l16 >> 2);

  floatx4 acc[4][4];
#pragma unroll
  for (int i = 0; i < 4; ++i)
#pragma unroll
    for (int j = 0; j < 4; ++j) acc[i][j] = (floatx4){0.f, 0.f, 0.f, 0.f};

  auto STAGE = [&](int buf, int k0) {
#pragma unroll
    for (int j = 0; j < 2; ++j) {
      gload16(Abase + (size_t)j * 16 * K + k0, ASB(buf) + ((w * 2 + j) << 9));
      gload16(Bbase + (size_t)j * 16 * K + k0, BSB(buf) + ((w * 2 + j) << 9));
    }
  };

  STAGE(0, 0);
  if (nk > 1) STAGE(1, 32);

  int cb = 0;
  for (int t = 0; t < nk; ++t) {
    if (t + 1 < nk) {
      asm volatile("s_waitcnt vmcnt(4) lgkmcnt(0)" ::: "memory");
    } else {
      asm volatile("s_waitcnt vmcnt(0) lgkmcnt(0)" ::: "memory");
    }
    __builtin_amdgcn_s_barrier();
    if (t + 2 < nk) {
      int sb = (cb == 0) ? 2 : cb - 1;   // (t+2)%3 == (t-1)%3
      STAGE(sb, (t + 2) << 5);
    }
    short8 a[4], b[4];
#pragma unroll
    for (int mi = 0; mi < 4; ++mi) {
      int ra = wm * 64 + mi * 16 + l16;
      a[mi] = *(const short8*)(ASB(cb) + (ra << 5) + ((qg ^ rswz) << 3));
    }
#pragma unroll
    for (int ni = 0; ni < 4; ++ni) {
      int n = wn * 64 + ni * 16 + l16;
      b[ni] = *(const short8*)(BSB(cb) + (n << 5) + ((qg ^ rswz) << 3));
    }
    __builtin_amdgcn_s_setprio(1);
#pragma unroll
    for (int ni = 0; ni < 4; ++ni)
#pragma unroll
      for (int mi = 0; mi < 4; ++mi)
        acc[mi][ni] = __builtin_amdgcn_mfma_f32_16x16x32_bf16(a[mi], b[ni], acc[mi][ni], 0, 0, 0);
    __builtin_amdgcn_s_setprio(0);
    cb = (cb == 2) ? 0 : cb + 1;
  }
  // ---- coalesced epilogue: each wave transposes its 64x64 quadrant through
  // its PRIVATE 8KB LDS slice (no inter-wave sharing), then vector stores.
  __builtin_amdgcn_s_barrier();   // all waves past final MFMA -> all ds_reads retired
  if (!c32) {
    short* wreg = Ls + w * 4096;  // 64x64 shorts
#pragma unroll
    for (int ni = 0; ni < 4; ++ni) {
      float bvv = bias ? loadf(bias, n0 + wn * 64 + ni * 16 + l16, f32) : 0.0f;
#pragma unroll
      for (int mi = 0; mi < 4; ++mi)
#pragma unroll
        for (int r = 0; r < 4; ++r)
          wreg[(mi * 16 + qg * 4 + r) * 64 + ni * 16 + l16] = f2b(acc[mi][ni][r] + bvv);
    }
    asm volatile("s_waitcnt lgkmcnt(0)" ::: "memory");
#pragma unroll
    for (int j = 0; j < 8; ++j) {
      int row = j * 8 + (lane >> 3);
      int col = (lane & 7) * 8;
      short8 v = *(const short8*)(wreg + row * 64 + col);
      *(short8*)((short*)C + (size_t)(crow0 + wm * 64 + row) * N + n0 + wn * 64 + col) = v;
    }
  } else {
    float* wregf = (float*)(Ls) + w * 2048;  // 64x32 floats per half
#pragma unroll
    for (int half = 0; half < 2; ++half) {
#pragma unroll
      for (int nh = 0; nh < 2; ++nh) {
        int ni = half * 2 + nh;
        float bvv = bias ? loadf(bias, n0 + wn * 64 + ni * 16 + l16, f32) : 0.0f;
#pragma unroll
        for (int mi = 0; mi < 4; ++mi)
#pragma unroll
          for (int r = 0; r < 4; ++r)
            wregf[(mi * 16 + qg * 4 + r) * 32 + nh * 16 + l16] = acc[mi][ni][r] + bvv;
      }
      asm volatile("s_waitcnt lgkmcnt(0)" ::: "memory");
#pragma unroll
      for (int j = 0; j < 8; ++j) {
        int row = j * 8 + (lane >> 3);
        int c4 = (lane & 7) * 4;
        float4 v = *(const float4*)(wregf + row * 32 + c4);
        *(float4*)((float*)C + (size_t)(crow0 + wm * 64 + row) * N + n0 + wn * 64 + half * 32 + c4) = v;
      }
      asm volatile("s_waitcnt lgkmcnt(0)" ::: "memory");  // half reads done before overwrite
    }
  }
#undef ASB
#undef BSB
}

// ---------- RMSNorm + RoPE: one wave per head; q scaled by rsqrt(128)*log2(e).
__global__ __launch_bounds__(512)
void norm_rope(short* __restrict__ qkv, const int* __restrict__ ids,
               const void* __restrict__ nqw, const void* __restrict__ nkw,
               const void* __restrict__ naqw, const void* __restrict__ nakw,
               const int* __restrict__ dflag) {
  const bool f32 = (*dflag != 0);
  const int t = blockIdx.x, wv = threadIdx.x >> 6, lane = threadIdx.x & 63;
  const bool txt = t < 512;
  int p = lane, axis; float expo;
  if (p < 8)       { axis = 0; expo = (float)(2 * p) * (1.0f / 16.0f); }
  else if (p < 36) { axis = 1; expo = (float)(2 * (p - 8)) * (1.0f / 56.0f); }
  else             { axis = 2; expo = (float)(2 * (p - 36)) * (1.0f / 56.0f); }
  float freq = __expf(-expo * 9.210340371976184f);
  float ang = (float)ids[t * 3 + axis] * freq;
  float s, c; sincosf(ang, &s, &c);
  const void* qw = txt ? naqw : nqw;
  const void* kw = txt ? nakw : nkw;
  float w0q = loadf(qw, 2 * lane, f32), w1q = loadf(qw, 2 * lane + 1, f32);
  float w0k = loadf(kw, 2 * lane, f32), w1k = loadf(kw, 2 * lane + 1, f32);
  const float QS = 0.08838834764831845f * 1.4426950408889634f;
#pragma unroll
  for (int i = 0; i < 3; ++i) {
    int h = wv + 8 * i;
    short* qp = qkv + (size_t)t * 9216 + h * 128 + 2 * lane;
    short* kp = qp + 3072;
    union { unsigned u; short sh[2]; } qv, kv;
    qv.u = *(const unsigned*)qp;
    kv.u = *(const unsigned*)kp;
    float q0 = b2f(qv.sh[0]), q1 = b2f(qv.sh[1]);
    float k0 = b2f(kv.sh[0]), k1 = b2f(kv.sh[1]);
    float sq = q0 * q0 + q1 * q1, sk = k0 * k0 + k1 * k1;
#pragma unroll
    for (int o = 1; o < 64; o <<= 1) { sq += __shfl_xor(sq, o); sk += __shfl_xor(sk, o); }
    float rq = rsqrtf(sq * (1.0f / 128.0f) + 1e-5f);
    float rk = rsqrtf(sk * (1.0f / 128.0f) + 1e-5f);
    float qn0 = q0 * rq * w0q, qn1 = q1 * rq * w1q;
    float kn0 = k0 * rk * w0k, kn1 = k1 * rk * w1k;
    float qo0 = qn0 * c - qn1 * s, qo1 = qn1 * c + qn0 * s;
    float ko0 = kn0 * c - kn1 * s, ko1 = kn1 * c + kn0 * s;
    union { unsigned u; short sh[2]; } qo, ko;
    qo.sh[0] = f2b(qo0 * QS);
    qo.sh[1] = f2b(qo1 * QS);
    ko.sh[0] = f2b(ko0); ko.sh[1] = f2b(ko1);
    *(unsigned*)qp = qo.u;
    *(unsigned*)kp = ko.u;
  }
}

// ---------- flash attention v9 (unchanged from R13).
__global__ __launch_bounds__(512, 2)
void attn_fa(const short* __restrict__ qkv, short* __restrict__ attn) {
  __shared__ short QPs[256 * 128];      // 64 KB
  __shared__ short KVs[2][128 * 128];   // 2 x 32 KB
  const int wgid = blockIdx.x;
  const int xcd = wgid & 7, slot = wgid >> 3;   // 30 slots/XCD
  const int h = xcd * 3 + slot / 10;            // 3 heads per XCD (L2-resident K/V)
  const int qt = slot % 10;
  const int tid = threadIdx.x, lane = tid & 63, w = tid >> 6;  // 8 waves
  const int qg = lane >> 4, l16 = lane & 15;
  const int lr = lane >> 4, lc = lane & 15;
  const int q0 = qt << 8;
  const int sc = tid & 15;
  const int srow5 = (tid >> 4) & 15, half = tid >> 8;

  const short* Qg  = qkv + (size_t)q0 * 9216 + h * 128;
  const short* Kg0 = qkv + 3072 + h * 128;
  const short* Vg0 = qkv + 6144 + h * 128;

  short8 vr[4];
#pragma unroll
  for (int j = 0; j < 8; ++j) {
    int row = j * 32 + w * 4 + lr;
    gload16(Qg + (size_t)row * 9216 + ((lc ^ (row & 7)) << 3),
            QPs + (j * 32 + w * 4) * 128);
  }
#pragma unroll
  for (int j = 0; j < 4; ++j) {
    int row = j * 32 + w * 4 + lr;
    gload16(Kg0 + (size_t)row * 9216 + ((lc ^ (row & 7)) << 3),
            &KVs[0][(j * 32 + w * 4) * 128]);
  }
#pragma unroll
  for (int j = 0; j < 4; ++j) {
    int row = half * 64 + j * 16 + srow5;
    vr[j] = *(const short8*)(Vg0 + (size_t)row * 9216 + sc * 8);
  }
  asm volatile("s_waitcnt vmcnt(8) lgkmcnt(0)" ::: "memory");
  __builtin_amdgcn_s_barrier();
  short8 aq[2][4];
#pragma unroll
  for (int mi = 0; mi < 2; ++mi)
#pragma unroll
    for (int kc = 0; kc < 4; ++kc) {
      int row = w * 32 + mi * 16 + l16;
      aq[mi][kc] = *(const short8*)(QPs + row * 128 + (((kc * 4 + qg) ^ (row & 7)) << 3));
    }

  floatx4 acc_o[2][8];
#pragma unroll
  for (int mi = 0; mi < 2; ++mi)
#pragma unroll
    for (int nd = 0; nd < 8; ++nd) acc_o[mi][nd] = (floatx4){0.f, 0.f, 0.f, 0.f};
  float m_i[2][4], l_i[2][4];
#pragma unroll
  for (int mi = 0; mi < 2; ++mi)
#pragma unroll
    for (int r = 0; r < 4; ++r) { m_i[mi][r] = -1e30f; l_i[mi][r] = 0.0f; }

  for (int kt = 0; kt < 20; ++kt) {
    const int c = kt & 1;
    asm volatile("s_waitcnt vmcnt(4) lgkmcnt(0)" ::: "memory");
    __builtin_amdgcn_s_barrier();
    if (kt < 19) {
      const short* Kg = qkv + ((size_t)(kt + 1) * 128) * 9216 + 3072 + h * 128;
#pragma unroll
      for (int j = 0; j < 4; ++j) {
        int row = j * 32 + w * 4 + lr;
        gload16(Kg + (size_t)row * 9216 + ((lc ^ (row & 7)) << 3),
                &KVs[1 - c][(j * 32 + w * 4) * 128]);
      }
    }
    // ---- QK^T from KVs[c] (scores already in log2 domain via q-scale)
    floatx4 acc_s[2][8];
#pragma unroll
    for (int mi = 0; mi < 2; ++mi)
#pragma unroll
      for (int ni = 0; ni < 8; ++ni) acc_s[mi][ni] = (floatx4){0.f, 0.f, 0.f, 0.f};
    __builtin_amdgcn_s_setprio(1);
#pragma unroll
    for (int kc = 0; kc < 4; ++kc) {
#pragma unroll
      for (int ni = 0; ni < 8; ++ni) {
        int row = ni * 16 + l16;
        short8 b = *(const short8*)(&KVs[c][row * 128 + (((kc * 4 + qg) ^ (row & 7)) << 3)]);
        acc_s[0][ni] = __builtin_amdgcn_mfma_f32_16x16x32_bf16(aq[0][kc], b, acc_s[0][ni], 0, 0, 0);
        acc_s[1][ni] = __builtin_amdgcn_mfma_f32_16x16x32_bf16(aq[1][kc], b, acc_s[1][ni], 0, 0, 0);
      }
    }
    __builtin_amdgcn_s_setprio(0);
    // ---- online softmax, exp2 domain, defer-rescale (T13)
    float mxv[2][4];
    bool need = false;
#pragma unroll
    for (int mi = 0; mi < 2; ++mi) {
#pragma unroll
      for (int r = 0; r < 4; ++r) {
        float mx = acc_s[mi][0][r];
#pragma unroll
        for (int ni = 1; ni < 8; ++ni) mx = fmaxf(mx, acc_s[mi][ni][r]);
        mx = fmaxf(mx, __shfl_xor(mx, 1));
        mx = fmaxf(mx, __shfl_xor(mx, 2));
        mx = fmaxf(mx, __shfl_xor(mx, 4));
        mx = fmaxf(mx, __shfl_xor(mx, 8));
        mxv[mi][r] = mx;
        need = need || (mx > m_i[mi][r] + 8.0f);
      }
    }
    if (__ballot(need)) {
#pragma unroll
      for (int mi = 0; mi < 2; ++mi) {
#pragma unroll
        for (int r = 0; r < 4; ++r) {
          float mn = fmaxf(m_i[mi][r], mxv[mi][r]);
          float al = __builtin_amdgcn_exp2f(m_i[mi][r] - mn);
          m_i[mi][r] = mn;
          l_i[mi][r] *= al;
#pragma unroll
          for (int nd = 0; nd < 8; ++nd) acc_o[mi][nd][r] *= al;
        }
      }
    }
#pragma unroll
    for (int mi = 0; mi < 2; ++mi) {
      float rs[4] = {0.f, 0.f, 0.f, 0.f};
#pragma unroll
      for (int r = 0; r < 4; ++r) {
        float pv[8];
#pragma unroll
        for (int ni = 0; ni < 8; ++ni) {
          pv[ni] = __builtin_amdgcn_exp2f(acc_s[mi][ni][r] - m_i[mi][r]);
          rs[r] += pv[ni];
        }
        unsigned u0 = cvtpk(pv[0], pv[1]);
        unsigned u1 = cvtpk(pv[2], pv[3]);
        unsigned u2 = cvtpk(pv[4], pv[5]);
        unsigned u3 = cvtpk(pv[6], pv[7]);
        int row = w * 32 + mi * 16 + qg * 4 + r;  // wave-private P row
        uint4 uu; uu.x = u0; uu.y = u1; uu.z = u2; uu.w = u3;
        *(uint4*)(QPs + row * 128 + ((l16 ^ (row & 15)) << 3)) = uu;
      }
#pragma unroll
      for (int r = 0; r < 4; ++r) {
        float t = rs[r];
        t += __shfl_xor(t, 1); t += __shfl_xor(t, 2);
        t += __shfl_xor(t, 4); t += __shfl_xor(t, 8);
        l_i[mi][r] += t;
      }
    }
    asm volatile("s_waitcnt lgkmcnt(0)" ::: "memory");
    __builtin_amdgcn_s_barrier();
    // ---- commit V^T(kt) into KVs[c]: token r -> col t' = 8*(r&15) + (r>>4).
#pragma unroll
    for (int u = 0; u < 8; ++u) {
      int d = sc * 8 + u;
      short4v pk = { vr[0][u], vr[1][u], vr[2][u], vr[3][u] };
      *(short4v*)(&KVs[c][d * 128 + (((srow5 ^ u ^ (sc & 7))) << 3) + half * 4]) = pk;
    }
    if (kt < 19) {
      const short* Vg = qkv + ((size_t)(kt + 1) * 128) * 9216 + 6144 + h * 128;
#pragma unroll
      for (int j = 0; j < 4; ++j) {
        int row = half * 64 + j * 16 + srow5;
        vr[j] = *(const short8*)(Vg + (size_t)row * 9216 + sc * 8);
      }
    }
    asm volatile("s_waitcnt lgkmcnt(0)" ::: "memory");
    __builtin_amdgcn_s_barrier();
    // ---- PV
    __builtin_amdgcn_s_setprio(1);
#pragma unroll
    for (int kc = 0; kc < 4; ++kc) {
      int prow0 = w * 32 + l16;
      short8 ap0 = *(const short8*)(QPs + prow0 * 128 + (((kc * 4 + qg) ^ (prow0 & 15)) << 3));
      int prow1 = prow0 + 16;
      short8 ap1 = *(const short8*)(QPs + prow1 * 128 + (((kc * 4 + qg) ^ (prow1 & 15)) << 3));
#pragma unroll
      for (int nd = 0; nd < 8; ++nd) {
        int row = nd * 16 + l16;
        int chn = (kc * 4 + qg) ^ (row & 7) ^ ((row >> 3) & 7);
        short8 b = *(const short8*)(&KVs[c][row * 128 + (chn << 3)]);
        acc_o[0][nd] = __builtin_amdgcn_mfma_f32_16x16x32_bf16(ap0, b, acc_o[0][nd], 0, 0, 0);
        acc_o[1][nd] = __builtin_amdgcn_mfma_f32_16x16x32_bf16(ap1, b, acc_o[1][nd], 0, 0, 0);
      }
    }
    __builtin_amdgcn_s_setprio(0);
  }
  // ---- epilogue: normalize, transpose through QPs, coalesced b128 stores
#pragma unroll
  for (int mi = 0; mi < 2; ++mi) {
    float inv[4];
#pragma unroll
    for (int r = 0; r < 4; ++r) inv[r] = 1.0f / l_i[mi][r];
#pragma unroll
    for (int nd = 0; nd < 8; ++nd) {
#pragma unroll
      for (int r = 0; r < 4; ++r) {
        int row = w * 32 + mi * 16 + qg * 4 + r;
        QPs[row * 128 + nd * 16 + l16] = f2b(acc_o[mi][nd][r] * inv[r]);
      }
    }
  }
  asm volatile("s_waitcnt lgkmcnt(0)" ::: "memory");
#pragma unroll
  for (int j = 0; j < 8; ++j) {
    int rrow = w * 32 + j * 4 + qg;
    short8 vv = *(const short8*)(QPs + rrow * 128 + l16 * 8);
    *(short8*)(attn + (size_t)(q0 + rrow) * 3072 + h * 128 + l16 * 8) = vv;
  }
}

extern "C" void kernel_launch(void* const* d_in, const int* in_sizes, int n_in,
                              void* d_out, int out_size, void* d_ws, size_t ws_size,
                              hipStream_t stream) {
  (void)in_sizes; (void)n_in; (void)out_size;
  const void* hidden    = d_in[0];
  const void* enc       = d_in[1];
  const int*  ids       = (const int*)d_in[2];
  const void* w_qkv     = d_in[3];
  const void* w_add_qkv = d_in[4];
  const void* b_add_qkv = d_in[5];
  const void* w_out     = d_in[6];
  const void* b_out     = d_in[7];
  const void* w_add_out = d_in[8];
  const void* b_add_out = d_in[9];
  const void* nqw  = d_in[10];
  const void* nkw  = d_in[11];
  const void* naqw = d_in[12];
  const void* nakw = d_in[13];

  int*   dflag = (int*)d_ws;
  short* qkv   = (short*)((char*)d_ws + 256);   // [2560][9216] bf16
  short* attnB = qkv + (size_t)2560 * 9216;     // [2560][3072] bf16

  // bf16 pool: xb = concat(enc rows 0..512, hidden rows 512..2560) + weightsT
  short* pool  = attnB + (size_t)2560 * 3072;
  const long n_hid  = 2048L * 3072;
  const long n_enc  = 512L * 3072;
  const long n_wqkv = 3072L * 9216;
  const long n_wout = 3072L * 3072;
  short* xb   = pool;                    // [2560][3072]
  short* wqb  = xb + n_enc + n_hid;      // w_qkv^T    [9216][3072]
  short* waqb = wqb + n_wqkv;            // w_add_qkv^T[9216][3072]
  short* wob  = waqb + n_wqkv;           // w_out^T    [3072][3072]
  short* waob = wob + n_wout;            // w_add_out^T[3072][3072]
  const size_t REQ = 256 + 2 * ((size_t)2560 * 9216 + (size_t)2560 * 3072 +
                                n_hid + n_enc + 2 * n_wqkv + 2 * n_wout);

  detect_dtype<<<1, 256, 0, stream>>>((const unsigned short*)w_qkv, dflag);

  if (ws_size >= REQ) {
    cvt_bf16_2<<<1024, 256, 0, stream>>>(enc, n_enc / 8, hidden, n_hid / 8, xb, dflag);
    cvt_tw<<<dim3(18432), 256, 0, stream>>>(w_qkv, wqb, w_add_qkv, waqb,
                                            w_out, wob, w_add_out, waob, dflag);

    // merged QKV projection: y<4 -> enc rows w/ w_add_qkv + bias; y>=4 -> hidden
    gemm_bf2<<<dim3(72, 20), 256, 0, stream>>>(
        xb, waqb, b_add_qkv, 0, 0, 4, wqb, nullptr, 512, 512,
        qkv, 9216, 3072, dflag, 0);
    norm_rope<<<dim3(2560), 512, 0, stream>>>(qkv, ids, nqw, nkw, naqw, nakw, dflag);
    attn_fa<<<dim3(240), 512, 0, stream>>>(qkv, attnB);
    // merged out-proj: y<16 -> img; y>=16 -> enc
    gemm_bf2<<<dim3(24, 20), 256, 0, stream>>>(
        attnB, wob, b_out, 512, 0, 16, waob, b_add_out, 0, 2048,
        d_out, 3072, 3072, dflag, 1);
  } else {
    gemm_bt<<<dim3(72, 4), 256, 0, stream>>>(enc, 0, w_add_qkv, b_add_qkv, qkv, 0, 9216, 3072, dflag, 1, 0);
    gemm_bt<<<dim3(72, 16), 256, 0, stream>>>(hidden, 0, w_qkv, nullptr, qkv, 512, 9216, 3072, dflag, 1, 0);
    norm_rope<<<dim3(2560), 512, 0, stream>>>(qkv, ids, nqw, nkw, naqw, nakw, dflag);
    attn_fa<<<dim3(240), 512, 0, stream>>>(qkv, attnB);
    gemm_bt<<<dim3(24, 16), 256, 0, stream>>>(attnB, 512, w_out, b_out, d_out, 0, 3072, 3072, dflag, 0, 1);
    gemm_bt<<<dim3(24, 4), 256, 0, stream>>>(attnB, 0, w_add_out, b_add_out, d_out, 2048, 3072, 3072, dflag, 0, 1);
  }
}

// Round 15
// 792.425 us; speedup vs baseline: 1.3075x; 1.0391x over previous
//
#include <hip/hip_runtime.h>

typedef __attribute__((ext_vector_type(8))) short short8;
typedef __attribute__((ext_vector_type(4))) short short4v;
typedef __attribute__((ext_vector_type(4))) float floatx4;

__device__ __forceinline__ float b2f(short b) {
  union { unsigned u; float f; } v; v.u = ((unsigned)(unsigned short)b) << 16; return v.f;
}
__device__ __forceinline__ short f2b(float f) {
  union { float f; unsigned u; } v; v.f = f;
  return (short)((v.u + 0x7fffu + ((v.u >> 16) & 1u)) >> 16);
}
// packed f32x2 -> bf16x2 (RNE), single VOP3 instr
__device__ __forceinline__ unsigned cvtpk(float lo, float hi) {
  unsigned r;
  asm("v_cvt_pk_bf16_f32 %0, %1, %2" : "=v"(r) : "v"(lo), "v"(hi));
  return r;
}
__device__ __forceinline__ float loadf(const void* p, size_t i, bool f32) {
  return f32 ? ((const float*)p)[i] : b2f(((const short*)p)[i]);
}
__device__ __forceinline__ short8 load8(const void* p, size_t i, bool f32) {
  if (f32) {
    const float* fp = (const float*)p + i;
    float4 a = *(const float4*)fp;
    float4 b = *(const float4*)(fp + 4);
    short8 r;
    r[0] = f2b(a.x); r[1] = f2b(a.y); r[2] = f2b(a.z); r[3] = f2b(a.w);
    r[4] = f2b(b.x); r[5] = f2b(b.y); r[6] = f2b(b.z); r[7] = f2b(b.w);
    return r;
  }
  return *(const short8*)((const short*)p + i);
}

// async global->LDS, 16B per lane. LDS dest = wave-uniform base + lane*16.
__device__ __forceinline__ void gload16(const short* g, short* l) {
  __builtin_amdgcn_global_load_lds(
      (const __attribute__((address_space(1))) unsigned int*)g,
      (__attribute__((address_space(3))) unsigned int*)l, 16, 0, 0);
}

// ---------- dtype detector
__global__ void detect_dtype(const unsigned short* __restrict__ w, int* __restrict__ flag) {
  __shared__ int cnt;
  if (threadIdx.x == 0) cnt = 0;
  __syncthreads();
  int bad = 0;
  for (int i = threadIdx.x; i < 4096; i += 256) {
    int e = (w[i] >> 7) & 0xFF;
    if (e >= 0xC8) bad++;
  }
  atomicAdd(&cnt, bad);
  __syncthreads();
  if (threadIdx.x == 0) *flag = (cnt > 64) ? 1 : 0;
}

// ---------- one-time dtype normalization: two sources -> one contiguous dst
__global__ __launch_bounds__(256)
void cvt_bf16_2(const void* __restrict__ srcA, long n8A,
                const void* __restrict__ srcB, long n8B,
                short* __restrict__ dst, const int* __restrict__ dflag) {
  const bool f32 = (*dflag != 0);
  const long n8 = n8A + n8B;
  long stride = (long)gridDim.x * 256;
  for (long i = (long)blockIdx.x * 256 + threadIdx.x; i < n8; i += stride) {
    const void* s; long e;
    if (i < n8A) { s = srcA; e = i * 8; } else { s = srcB; e = (i - n8A) * 8; }
    if (f32) {
      const float* fp = (const float*)s + e;
      float4 a = *(const float4*)fp;
      float4 b = *(const float4*)(fp + 4);
      short8 r;
      r[0] = f2b(a.x); r[1] = f2b(a.y); r[2] = f2b(a.z); r[3] = f2b(a.w);
      r[4] = f2b(b.x); r[5] = f2b(b.y); r[6] = f2b(b.z); r[7] = f2b(b.w);
      *(short8*)(dst + i * 8) = r;
    } else {
      *(short8*)(dst + i * 8) = *(const short8*)((const short*)s + e);
    }
  }
}

// ---------- cvt_tw: all 4 weight transposes in ONE launch (1-D grid decode).
__global__ __launch_bounds__(256)
void cvt_tw(const void* __restrict__ wq, short* __restrict__ wqd,
            const void* __restrict__ waq, short* __restrict__ waqd,
            const void* __restrict__ wo, short* __restrict__ wod,
            const void* __restrict__ wao, short* __restrict__ waod,
            const int* __restrict__ dflag) {
  __shared__ short st[64][72];
  const bool f32 = (*dflag != 0);
  const int K = 3072;
  int b = blockIdx.x;
  const void* src; short* dst; int N, n0, k0;
  if (b < 13824) {               // two big matrices: 2 x (144 x 48)
    src = (b < 6912) ? wq : waq;
    dst = (b < 6912) ? wqd : waqd;
    int rem = b % 6912;
    N = 9216; n0 = (rem % 144) << 6; k0 = (rem / 144) << 6;
  } else {                       // two small: 2 x (48 x 48)
    b -= 13824;
    src = (b < 2304) ? wo : wao;
    dst = (b < 2304) ? wod : waod;
    int rem = b % 2304;
    N = 3072; n0 = (rem % 48) << 6; k0 = (rem / 48) << 6;
  }
  const int c4 = threadIdx.x & 15;
  const int rq = threadIdx.x >> 4;
#pragma unroll
  for (int r = 0; r < 4; ++r) {
    int k = r * 16 + rq;
    int n = c4 * 4;
    short v0, v1, v2, v3;
    if (f32) {
      const float* sp = (const float*)src + (size_t)(k0 + k) * N + n0 + n;
      float4 f = *(const float4*)sp;
      v0 = f2b(f.x); v1 = f2b(f.y); v2 = f2b(f.z); v3 = f2b(f.w);
    } else {
      const short* sp = (const short*)src + (size_t)(k0 + k) * N + n0 + n;
      short4v s = *(const short4v*)sp;
      v0 = s[0]; v1 = s[1]; v2 = s[2]; v3 = s[3];
    }
    st[n + 0][k] = v0; st[n + 1][k] = v1; st[n + 2][k] = v2; st[n + 3][k] = v3;
  }
  __syncthreads();
  const int n = threadIdx.x >> 2;
  const int kc = (threadIdx.x & 3) << 4;
  short8 a = *(const short8*)(&st[n][kc]);
  short8 bb = *(const short8*)(&st[n][kc + 8]);
  short* dp = dst + (size_t)(n0 + n) * K + k0 + kc;
  *(short8*)(dp) = a;
  *(short8*)(dp + 8) = bb;
}

// ---------- OLD GEMM (fallback) ----------
__global__ __launch_bounds__(256, 2)
void gemm_bt(const void* __restrict__ A, int a_row0,
             const void* __restrict__ B, const void* __restrict__ bias,
             void* __restrict__ C, int c_row0, int N, int K,
             const int* __restrict__ dflag, int aIn, int cOut) {
  __shared__ short As[128 * 32];
  __shared__ short Bs[128 * 32];
  const bool f32 = (*dflag != 0);
  const bool a32 = aIn && f32;
  const bool c32 = cOut && f32;
  const int tid = threadIdx.x;
  const int lane = tid & 63, w = tid >> 6;
  const int wm = w & 1, wn = w >> 1;
  const int qg = lane >> 4, l16 = lane & 15;
  const int m0 = blockIdx.y << 7, n0 = blockIdx.x << 7;

  const int arow = tid >> 2, ak = (tid & 3) << 3;
  const int brow = tid >> 4, bc = (tid & 15) << 3;
  const int rot = tid & 15;

  floatx4 acc[4][4];
#pragma unroll
  for (int i = 0; i < 4; ++i)
#pragma unroll
    for (int j = 0; j < 4; ++j) acc[i][j] = (floatx4){0.f, 0.f, 0.f, 0.f};

  for (int k0 = 0; k0 < K; k0 += 32) {
    __syncthreads();
#pragma unroll
    for (int j = 0; j < 2; ++j) {
      short8 av = load8(A, (size_t)(a_row0 + m0 + j * 64 + arow) * K + (k0 + ak), a32);
      *(short8*)(As + (j * 64 + arow) * 32 + ak) = av;
      int kr = j * 16 + brow;
      short8 bv = load8(B, (size_t)(k0 + kr) * N + (n0 + bc), f32);
      int kq = kr >> 3, kj = kr & 7;
#pragma unroll
      for (int s = 0; s < 8; ++s) {
        int u = (s + rot) & 7;
        int n = bc + u;
        Bs[(n << 5) + ((kq ^ (n & 3)) << 3) + kj] = bv[u];
      }
    }
    __syncthreads();
    short8 a[4];
#pragma unroll
    for (int mi = 0; mi < 4; ++mi)
      a[mi] = *(const short8*)(As + (wm * 64 + mi * 16 + l16) * 32 + qg * 8);
#pragma unroll
    for (int ni = 0; ni < 4; ++ni) {
      int n = wn * 64 + ni * 16 + l16;
      short8 b = *(const short8*)(Bs + (n << 5) + ((qg ^ (n & 3)) << 3));
#pragma unroll
      for (int mi = 0; mi < 4; ++mi)
        acc[mi][ni] = __builtin_amdgcn_mfma_f32_16x16x32_bf16(a[mi], b, acc[mi][ni], 0, 0, 0);
    }
  }
#pragma unroll
  for (int ni = 0; ni < 4; ++ni) {
    int col = n0 + wn * 64 + ni * 16 + l16;
    float bv = bias ? loadf(bias, col, f32) : 0.0f;
#pragma unroll
    for (int mi = 0; mi < 4; ++mi) {
      int row = m0 + wm * 64 + mi * 16 + qg * 4;
#pragma unroll
      for (int r = 0; r < 4; ++r) {
        size_t idx = (size_t)(c_row0 + row + r) * N + col;
        float val = acc[mi][ni][r] + bv;
        if (c32) ((float*)C)[idx] = val;
        else     ((short*)C)[idx] = f2b(val);
      }
    }
  }
}

// ---------- GEMM v10: depth-2 pipelined, single barrier per K-step,
// NATURAL block mapping (R14: XCD-chunked swizzle made each XCD stream the
// whole B matrix -> FETCH 147->582 MB; natural round-robin temporally aligns
// same-bx blocks so B panels hit L2. Reverted),
// + coalesced LDS-transposed epilogue (kept: WRITE 61->46 MB, RMW gone).
__global__ __launch_bounds__(256, 3)
void gemm_bf2(const short* __restrict__ A,
              const short* __restrict__ BTa, const void* __restrict__ biasa,
              int a0a, int c0a, int nYa,
              const short* __restrict__ BTb, const void* __restrict__ biasb,
              int a0b, int c0b,
              void* __restrict__ C, int N, int K,
              const int* __restrict__ dflag, int cOut) {
  __shared__ short Ls[6 * 128 * 32];           // 48 KB: 3 A bufs + 3 B bufs
#define ASB(b) (Ls + (b) * 4096)
#define BSB(b) (Ls + (3 + (b)) * 4096)
  const bool f32 = (*dflag != 0);
  const bool c32 = cOut && f32;
  const int bx = blockIdx.x;
  const int y = blockIdx.y;
  const short* BT; const void* bias; int arow0, crow0;
  if (y < nYa) { BT = BTa; bias = biasa; arow0 = a0a + (y << 7); crow0 = c0a + (y << 7); }
  else { int my = y - nYa; BT = BTb; bias = biasb; arow0 = a0b + (my << 7); crow0 = c0b + (my << 7); }
  const int tid = threadIdx.x;
  const int lane = tid & 63, w = tid >> 6;
  const int wm = w & 1, wn = w >> 1;
  const int qg = lane >> 4, l16 = lane & 15;
  const int n0 = bx << 7;
  const int garow = lane >> 2;
  const int gcir = lane & 3;
  const int nk = K >> 5;
  const int swz = (gcir ^ (garow & 3) ^ (garow >> 2)) << 3;
  const short* Abase = A + (size_t)(arow0 + w * 32 + garow) * K + swz;
  const short* Bbase = BT + (size_t)(n0 + w * 32 + garow) * K + swz;
  const int rswz = (l16 & 3) ^ (l16 >> 2);

  floatx4 acc[4][4];
#pragma unroll
  for (int i = 0; i < 4; ++i)
#pragma unroll
    for (int j = 0; j < 4; ++j) acc[i][j] = (floatx4){0.f, 0.f, 0.f, 0.f};

  auto STAGE = [&](int buf, int k0) {
#pragma unroll
    for (int j = 0; j < 2; ++j) {
      gload16(Abase + (size_t)j * 16 * K + k0, ASB(buf) + ((w * 2 + j) << 9));
      gload16(Bbase + (size_t)j * 16 * K + k0, BSB(buf) + ((w * 2 + j) << 9));
    }
  };

  STAGE(0, 0);
  if (nk > 1) STAGE(1, 32);

  int cb = 0;
  for (int t = 0; t < nk; ++t) {
    if (t + 1 < nk) {
      asm volatile("s_waitcnt vmcnt(4) lgkmcnt(0)" ::: "memory");
    } else {
      asm volatile("s_waitcnt vmcnt(0) lgkmcnt(0)" ::: "memory");
    }
    __builtin_amdgcn_s_barrier();
    if (t + 2 < nk) {
      int sb = (cb == 0) ? 2 : cb - 1;   // (t+2)%3 == (t-1)%3
      STAGE(sb, (t + 2) << 5);
    }
    short8 a[4], b[4];
#pragma unroll
    for (int mi = 0; mi < 4; ++mi) {
      int ra = wm * 64 + mi * 16 + l16;
      a[mi] = *(const short8*)(ASB(cb) + (ra << 5) + ((qg ^ rswz) << 3));
    }
#pragma unroll
    for (int ni = 0; ni < 4; ++ni) {
      int n = wn * 64 + ni * 16 + l16;
      b[ni] = *(const short8*)(BSB(cb) + (n << 5) + ((qg ^ rswz) << 3));
    }
    __builtin_amdgcn_s_setprio(1);
#pragma unroll
    for (int ni = 0; ni < 4; ++ni)
#pragma unroll
      for (int mi = 0; mi < 4; ++mi)
        acc[mi][ni] = __builtin_amdgcn_mfma_f32_16x16x32_bf16(a[mi], b[ni], acc[mi][ni], 0, 0, 0);
    __builtin_amdgcn_s_setprio(0);
    cb = (cb == 2) ? 0 : cb + 1;
  }
  // ---- coalesced epilogue: each wave transposes its 64x64 quadrant through
  // its PRIVATE 8KB LDS slice, then vector stores.
  __builtin_amdgcn_s_barrier();   // all waves past final MFMA -> ds_reads retired
  if (!c32) {
    short* wreg = Ls + w * 4096;  // 64x64 shorts
#pragma unroll
    for (int ni = 0; ni < 4; ++ni) {
      float bvv = bias ? loadf(bias, n0 + wn * 64 + ni * 16 + l16, f32) : 0.0f;
#pragma unroll
      for (int mi = 0; mi < 4; ++mi)
#pragma unroll
        for (int r = 0; r < 4; ++r)
          wreg[(mi * 16 + qg * 4 + r) * 64 + ni * 16 + l16] = f2b(acc[mi][ni][r] + bvv);
    }
    asm volatile("s_waitcnt lgkmcnt(0)" ::: "memory");
#pragma unroll
    for (int j = 0; j < 8; ++j) {
      int row = j * 8 + (lane >> 3);
      int col = (lane & 7) * 8;
      short8 v = *(const short8*)(wreg + row * 64 + col);
      *(short8*)((short*)C + (size_t)(crow0 + wm * 64 + row) * N + n0 + wn * 64 + col) = v;
    }
  } else {
    float* wregf = (float*)(Ls) + w * 2048;  // 64x32 floats per half
#pragma unroll
    for (int half = 0; half < 2; ++half) {
#pragma unroll
      for (int nh = 0; nh < 2; ++nh) {
        int ni = half * 2 + nh;
        float bvv = bias ? loadf(bias, n0 + wn * 64 + ni * 16 + l16, f32) : 0.0f;
#pragma unroll
        for (int mi = 0; mi < 4; ++mi)
#pragma unroll
          for (int r = 0; r < 4; ++r)
            wregf[(mi * 16 + qg * 4 + r) * 32 + nh * 16 + l16] = acc[mi][ni][r] + bvv;
      }
      asm volatile("s_waitcnt lgkmcnt(0)" ::: "memory");
#pragma unroll
      for (int j = 0; j < 8; ++j) {
        int row = j * 8 + (lane >> 3);
        int c4 = (lane & 7) * 4;
        float4 v = *(const float4*)(wregf + row * 32 + c4);
        *(float4*)((float*)C + (size_t)(crow0 + wm * 64 + row) * N + n0 + wn * 64 + half * 32 + c4) = v;
      }
      asm volatile("s_waitcnt lgkmcnt(0)" ::: "memory");  // half reads done before overwrite
    }
  }
#undef ASB
#undef BSB
}

// ---------- RMSNorm + RoPE: one wave per head; q scaled by rsqrt(128)*log2(e).
__global__ __launch_bounds__(512)
void norm_rope(short* __restrict__ qkv, const int* __restrict__ ids,
               const void* __restrict__ nqw, const void* __restrict__ nkw,
               const void* __restrict__ naqw, const void* __restrict__ nakw,
               const int* __restrict__ dflag) {
  const bool f32 = (*dflag != 0);
  const int t = blockIdx.x, wv = threadIdx.x >> 6, lane = threadIdx.x & 63;
  const bool txt = t < 512;
  int p = lane, axis; float expo;
  if (p < 8)       { axis = 0; expo = (float)(2 * p) * (1.0f / 16.0f); }
  else if (p < 36) { axis = 1; expo = (float)(2 * (p - 8)) * (1.0f / 56.0f); }
  else             { axis = 2; expo = (float)(2 * (p - 36)) * (1.0f / 56.0f); }
  float freq = __expf(-expo * 9.210340371976184f);
  float ang = (float)ids[t * 3 + axis] * freq;
  float s, c; sincosf(ang, &s, &c);
  const void* qw = txt ? naqw : nqw;
  const void* kw = txt ? nakw : nkw;
  float w0q = loadf(qw, 2 * lane, f32), w1q = loadf(qw, 2 * lane + 1, f32);
  float w0k = loadf(kw, 2 * lane, f32), w1k = loadf(kw, 2 * lane + 1, f32);
  const float QS = 0.08838834764831845f * 1.4426950408889634f;
#pragma unroll
  for (int i = 0; i < 3; ++i) {
    int h = wv + 8 * i;
    short* qp = qkv + (size_t)t * 9216 + h * 128 + 2 * lane;
    short* kp = qp + 3072;
    union { unsigned u; short sh[2]; } qv, kv;
    qv.u = *(const unsigned*)qp;
    kv.u = *(const unsigned*)kp;
    float q0 = b2f(qv.sh[0]), q1 = b2f(qv.sh[1]);
    float k0 = b2f(kv.sh[0]), k1 = b2f(kv.sh[1]);
    float sq = q0 * q0 + q1 * q1, sk = k0 * k0 + k1 * k1;
#pragma unroll
    for (int o = 1; o < 64; o <<= 1) { sq += __shfl_xor(sq, o); sk += __shfl_xor(sk, o); }
    float rq = rsqrtf(sq * (1.0f / 128.0f) + 1e-5f);
    float rk = rsqrtf(sk * (1.0f / 128.0f) + 1e-5f);
    float qn0 = q0 * rq * w0q, qn1 = q1 * rq * w1q;
    float kn0 = k0 * rk * w0k, kn1 = k1 * rk * w1k;
    float qo0 = qn0 * c - qn1 * s, qo1 = qn1 * c + qn0 * s;
    float ko0 = kn0 * c - kn1 * s, ko1 = kn1 * c + kn0 * s;
    union { unsigned u; short sh[2]; } qo, ko;
    qo.sh[0] = f2b(qo0 * QS);
    qo.sh[1] = f2b(qo1 * QS);
    ko.sh[0] = f2b(ko0); ko.sh[1] = f2b(ko1);
    *(unsigned*)qp = qo.u;
    *(unsigned*)kp = ko.u;
  }
}

// ---------- flash attention v9 (unchanged).
__global__ __launch_bounds__(512, 2)
void attn_fa(const short* __restrict__ qkv, short* __restrict__ attn) {
  __shared__ short QPs[256 * 128];      // 64 KB
  __shared__ short KVs[2][128 * 128];   // 2 x 32 KB
  const int wgid = blockIdx.x;
  const int xcd = wgid & 7, slot = wgid >> 3;   // 30 slots/XCD
  const int h = xcd * 3 + slot / 10;            // 3 heads per XCD (L2-resident K/V)
  const int qt = slot % 10;
  const int tid = threadIdx.x, lane = tid & 63, w = tid >> 6;  // 8 waves
  const int qg = lane >> 4, l16 = lane & 15;
  const int lr = lane >> 4, lc = lane & 15;
  const int q0 = qt << 8;
  const int sc = tid & 15;
  const int srow5 = (tid >> 4) & 15, half = tid >> 8;

  const short* Qg  = qkv + (size_t)q0 * 9216 + h * 128;
  const short* Kg0 = qkv + 3072 + h * 128;
  const short* Vg0 = qkv + 6144 + h * 128;

  short8 vr[4];
#pragma unroll
  for (int j = 0; j < 8; ++j) {
    int row = j * 32 + w * 4 + lr;
    gload16(Qg + (size_t)row * 9216 + ((lc ^ (row & 7)) << 3),
            QPs + (j * 32 + w * 4) * 128);
  }
#pragma unroll
  for (int j = 0; j < 4; ++j) {
    int row = j * 32 + w * 4 + lr;
    gload16(Kg0 + (size_t)row * 9216 + ((lc ^ (row & 7)) << 3),
            &KVs[0][(j * 32 + w * 4) * 128]);
  }
#pragma unroll
  for (int j = 0; j < 4; ++j) {
    int row = half * 64 + j * 16 + srow5;
    vr[j] = *(const short8*)(Vg0 + (size_t)row * 9216 + sc * 8);
  }
  asm volatile("s_waitcnt vmcnt(8) lgkmcnt(0)" ::: "memory");
  __builtin_amdgcn_s_barrier();
  short8 aq[2][4];
#pragma unroll
  for (int mi = 0; mi < 2; ++mi)
#pragma unroll
    for (int kc = 0; kc < 4; ++kc) {
      int row = w * 32 + mi * 16 + l16;
      aq[mi][kc] = *(const short8*)(QPs + row * 128 + (((kc * 4 + qg) ^ (row & 7)) << 3));
    }

  floatx4 acc_o[2][8];
#pragma unroll
  for (int mi = 0; mi < 2; ++mi)
#pragma unroll
    for (int nd = 0; nd < 8; ++nd) acc_o[mi][nd] = (floatx4){0.f, 0.f, 0.f, 0.f};
  float m_i[2][4], l_i[2][4];
#pragma unroll
  for (int mi = 0; mi < 2; ++mi)
#pragma unroll
    for (int r = 0; r < 4; ++r) { m_i[mi][r] = -1e30f; l_i[mi][r] = 0.0f; }

  for (int kt = 0; kt < 20; ++kt) {
    const int c = kt & 1;
    asm volatile("s_waitcnt vmcnt(4) lgkmcnt(0)" ::: "memory");
    __builtin_amdgcn_s_barrier();
    if (kt < 19) {
      const short* Kg = qkv + ((size_t)(kt + 1) * 128) * 9216 + 3072 + h * 128;
#pragma unroll
      for (int j = 0; j < 4; ++j) {
        int row = j * 32 + w * 4 + lr;
        gload16(Kg + (size_t)row * 9216 + ((lc ^ (row & 7)) << 3),
                &KVs[1 - c][(j * 32 + w * 4) * 128]);
      }
    }
    floatx4 acc_s[2][8];
#pragma unroll
    for (int mi = 0; mi < 2; ++mi)
#pragma unroll
      for (int ni = 0; ni < 8; ++ni) acc_s[mi][ni] = (floatx4){0.f, 0.f, 0.f, 0.f};
    __builtin_amdgcn_s_setprio(1);
#pragma unroll
    for (int kc = 0; kc < 4; ++kc) {
#pragma unroll
      for (int ni = 0; ni < 8; ++ni) {
        int row = ni * 16 + l16;
        short8 b = *(const short8*)(&KVs[c][row * 128 + (((kc * 4 + qg) ^ (row & 7)) << 3)]);
        acc_s[0][ni] = __builtin_amdgcn_mfma_f32_16x16x32_bf16(aq[0][kc], b, acc_s[0][ni], 0, 0, 0);
        acc_s[1][ni] = __builtin_amdgcn_mfma_f32_16x16x32_bf16(aq[1][kc], b, acc_s[1][ni], 0, 0, 0);
      }
    }
    __builtin_amdgcn_s_setprio(0);
    float mxv[2][4];
    bool need = false;
#pragma unroll
    for (int mi = 0; mi < 2; ++mi) {
#pragma unroll
      for (int r = 0; r < 4; ++r) {
        float mx = acc_s[mi][0][r];
#pragma unroll
        for (int ni = 1; ni < 8; ++ni) mx = fmaxf(mx, acc_s[mi][ni][r]);
        mx = fmaxf(mx, __shfl_xor(mx, 1));
        mx = fmaxf(mx, __shfl_xor(mx, 2));
        mx = fmaxf(mx, __shfl_xor(mx, 4));
        mx = fmaxf(mx, __shfl_xor(mx, 8));
        mxv[mi][r] = mx;
        need = need || (mx > m_i[mi][r] + 8.0f);
      }
    }
    if (__ballot(need)) {
#pragma unroll
      for (int mi = 0; mi < 2; ++mi) {
#pragma unroll
        for (int r = 0; r < 4; ++r) {
          float mn = fmaxf(m_i[mi][r], mxv[mi][r]);
          float al = __builtin_amdgcn_exp2f(m_i[mi][r] - mn);
          m_i[mi][r] = mn;
          l_i[mi][r] *= al;
#pragma unroll
          for (int nd = 0; nd < 8; ++nd) acc_o[mi][nd][r] *= al;
        }
      }
    }
#pragma unroll
    for (int mi = 0; mi < 2; ++mi) {
      float rs[4] = {0.f, 0.f, 0.f, 0.f};
#pragma unroll
      for (int r = 0; r < 4; ++r) {
        float pv[8];
#pragma unroll
        for (int ni = 0; ni < 8; ++ni) {
          pv[ni] = __builtin_amdgcn_exp2f(acc_s[mi][ni][r] - m_i[mi][r]);
          rs[r] += pv[ni];
        }
        unsigned u0 = cvtpk(pv[0], pv[1]);
        unsigned u1 = cvtpk(pv[2], pv[3]);
        unsigned u2 = cvtpk(pv[4], pv[5]);
        unsigned u3 = cvtpk(pv[6], pv[7]);
        int row = w * 32 + mi * 16 + qg * 4 + r;
        uint4 uu; uu.x = u0; uu.y = u1; uu.z = u2; uu.w = u3;
        *(uint4*)(QPs + row * 128 + ((l16 ^ (row & 15)) << 3)) = uu;
      }
#pragma unroll
      for (int r = 0; r < 4; ++r) {
        float t = rs[r];
        t += __shfl_xor(t, 1); t += __shfl_xor(t, 2);
        t += __shfl_xor(t, 4); t += __shfl_xor(t, 8);
        l_i[mi][r] += t;
      }
    }
    asm volatile("s_waitcnt lgkmcnt(0)" ::: "memory");
    __builtin_amdgcn_s_barrier();
#pragma unroll
    for (int u = 0; u < 8; ++u) {
      int d = sc * 8 + u;
      short4v pk = { vr[0][u], vr[1][u], vr[2][u], vr[3][u] };
      *(short4v*)(&KVs[c][d * 128 + (((srow5 ^ u ^ (sc & 7))) << 3) + half * 4]) = pk;
    }
    if (kt < 19) {
      const short* Vg = qkv + ((size_t)(kt + 1) * 128) * 9216 + 6144 + h * 128;
#pragma unroll
      for (int j = 0; j < 4; ++j) {
        int row = half * 64 + j * 16 + srow5;
        vr[j] = *(const short8*)(Vg + (size_t)row * 9216 + sc * 8);
      }
    }
    asm volatile("s_waitcnt lgkmcnt(0)" ::: "memory");
    __builtin_amdgcn_s_barrier();
    __builtin_amdgcn_s_setprio(1);
#pragma unroll
    for (int kc = 0; kc < 4; ++kc) {
      int prow0 = w * 32 + l16;
      short8 ap0 = *(const short8*)(QPs + prow0 * 128 + (((kc * 4 + qg) ^ (prow0 & 15)) << 3));
      int prow1 = prow0 + 16;
      short8 ap1 = *(const short8*)(QPs + prow1 * 128 + (((kc * 4 + qg) ^ (prow1 & 15)) << 3));
#pragma unroll
      for (int nd = 0; nd < 8; ++nd) {
        int row = nd * 16 + l16;
        int chn = (kc * 4 + qg) ^ (row & 7) ^ ((row >> 3) & 7);
        short8 b = *(const short8*)(&KVs[c][row * 128 + (chn << 3)]);
        acc_o[0][nd] = __builtin_amdgcn_mfma_f32_16x16x32_bf16(ap0, b, acc_o[0][nd], 0, 0, 0);
        acc_o[1][nd] = __builtin_amdgcn_mfma_f32_16x16x32_bf16(ap1, b, acc_o[1][nd], 0, 0, 0);
      }
    }
    __builtin_amdgcn_s_setprio(0);
  }
#pragma unroll
  for (int mi = 0; mi < 2; ++mi) {
    float inv[4];
#pragma unroll
    for (int r = 0; r < 4; ++r) inv[r] = 1.0f / l_i[mi][r];
#pragma unroll
    for (int nd = 0; nd < 8; ++nd) {
#pragma unroll
      for (int r = 0; r < 4; ++r) {
        int row = w * 32 + mi * 16 + qg * 4 + r;
        QPs[row * 128 + nd * 16 + l16] = f2b(acc_o[mi][nd][r] * inv[r]);
      }
    }
  }
  asm volatile("s_waitcnt lgkmcnt(0)" ::: "memory");
#pragma unroll
  for (int j = 0; j < 8; ++j) {
    int rrow = w * 32 + j * 4 + qg;
    short8 vv = *(const short8*)(QPs + rrow * 128 + l16 * 8);
    *(short8*)(attn + (size_t)(q0 + rrow) * 3072 + h * 128 + l16 * 8) = vv;
  }
}

extern "C" void kernel_launch(void* const* d_in, const int* in_sizes, int n_in,
                              void* d_out, int out_size, void* d_ws, size_t ws_size,
                              hipStream_t stream) {
  (void)in_sizes; (void)n_in; (void)out_size;
  const void* hidden    = d_in[0];
  const void* enc       = d_in[1];
  const int*  ids       = (const int*)d_in[2];
  const void* w_qkv     = d_in[3];
  const void* w_add_qkv = d_in[4];
  const void* b_add_qkv = d_in[5];
  const void* w_out     = d_in[6];
  const void* b_out     = d_in[7];
  const void* w_add_out = d_in[8];
  const void* b_add_out = d_in[9];
  const void* nqw  = d_in[10];
  const void* nkw  = d_in[11];
  const void* naqw = d_in[12];
  const void* nakw = d_in[13];

  int*   dflag = (int*)d_ws;
  short* qkv   = (short*)((char*)d_ws + 256);   // [2560][9216] bf16
  short* attnB = qkv + (size_t)2560 * 9216;     // [2560][3072] bf16

  short* pool  = attnB + (size_t)2560 * 3072;
  const long n_hid  = 2048L * 3072;
  const long n_enc  = 512L * 3072;
  const long n_wqkv = 3072L * 9216;
  const long n_wout = 3072L * 3072;
  short* xb   = pool;                    // [2560][3072]
  short* wqb  = xb + n_enc + n_hid;      // w_qkv^T    [9216][3072]
  short* waqb = wqb + n_wqkv;            // w_add_qkv^T[9216][3072]
  short* wob  = waqb + n_wqkv;           // w_out^T    [3072][3072]
  short* waob = wob + n_wout;            // w_add_out^T[3072][3072]
  const size_t REQ = 256 + 2 * ((size_t)2560 * 9216 + (size_t)2560 * 3072 +
                                n_hid + n_enc + 2 * n_wqkv + 2 * n_wout);

  detect_dtype<<<1, 256, 0, stream>>>((const unsigned short*)w_qkv, dflag);

  if (ws_size >= REQ) {
    cvt_bf16_2<<<1024, 256, 0, stream>>>(enc, n_enc / 8, hidden, n_hid / 8, xb, dflag);
    cvt_tw<<<dim3(18432), 256, 0, stream>>>(w_qkv, wqb, w_add_qkv, waqb,
                                            w_out, wob, w_add_out, waob, dflag);

    gemm_bf2<<<dim3(72, 20), 256, 0, stream>>>(
        xb, waqb, b_add_qkv, 0, 0, 4, wqb, nullptr, 512, 512,
        qkv, 9216, 3072, dflag, 0);
    norm_rope<<<dim3(2560), 512, 0, stream>>>(qkv, ids, nqw, nkw, naqw, nakw, dflag);
    attn_fa<<<dim3(240), 512, 0, stream>>>(qkv, attnB);
    gemm_bf2<<<dim3(24, 20), 256, 0, stream>>>(
        attnB, wob, b_out, 512, 0, 16, waob, b_add_out, 0, 2048,
        d_out, 3072, 3072, dflag, 1);
  } else {
    gemm_bt<<<dim3(72, 4), 256, 0, stream>>>(enc, 0, w_add_qkv, b_add_qkv, qkv, 0, 9216, 3072, dflag, 1, 0);
    gemm_bt<<<dim3(72, 16), 256, 0, stream>>>(hidden, 0, w_qkv, nullptr, qkv, 512, 9216, 3072, dflag, 1, 0);
    norm_rope<<<dim3(2560), 512, 0, stream>>>(qkv, ids, nqw, nkw, naqw, nakw, dflag);
    attn_fa<<<dim3(240), 512, 0, stream>>>(qkv, attnB);
    gemm_bt<<<dim3(24, 16), 256, 0, stream>>>(attnB, 512, w_out, b_out, d_out, 0, 3072, 3072, dflag, 0, 1);
    gemm_bt<<<dim3(24, 4), 256, 0, stream>>>(attnB, 0, w_add_out, b_add_out, d_out, 2048, 3072, 3072, dflag, 0, 1);
  }
}